// Round 2
// baseline (2167.414 us; speedup 1.0000x reference)
//
#include <hip/hip_runtime.h>
#include <hip/hip_fp16.h>
#include <math.h>

#define B_   2
#define C_   256
#define T_   32
#define HW_  1024
#define THW_ 32768

// ---------------- weight transpose: WT[c][o] = W[o][c] ----------------
__global__ void k_transpose(const float* __restrict__ W, float* __restrict__ WT, int O, int Cin){
  int idx = blockIdx.x * 256 + threadIdx.x;
  if (idx < O * Cin){
    int o = idx / Cin, c = idx % Cin;
    WT[(size_t)c * O + o] = W[idx];
  }
}

// ---------------- rope table: cos/sin(pos * invf[u]), pos<32, u<16 ----------------
__global__ void k_rope_table(float* __restrict__ cosT, float* __restrict__ sinT){
  int tid = threadIdx.x;            // 512 threads, tid = i*16+u
  int i = tid >> 4, u = tid & 15;
  float invf = powf(10000.f, -(2.f * (float)u) / 32.f);
  float s, c;
  sincosf((float)i * invf, &s, &c);
  cosT[tid] = c;
  sinT[tid] = s;
}

// ---------------- qkv GEMM: out[b, oBase+o, s] = sum_c WT[c][o0+oBase+o] * x[b,c,s] ---
// grid (4, 128, 2), block 256. Each thread: 1 s-column, 64 output rows. ldw = 768.
__global__ __launch_bounds__(256) void k_gemm_qkv(
    const float* __restrict__ WT, int o0,
    const float* __restrict__ x, float* __restrict__ out)
{
  const int oBase = blockIdx.x * 64;
  const int s = blockIdx.y * 256 + threadIdx.x;
  const int b = blockIdx.z;
  const float* xp = x + ((size_t)b * C_) * THW_ + s;
  const float* wp = WT + o0 + oBase;
  float acc[64];
  #pragma unroll
  for (int o = 0; o < 64; o++) acc[o] = 0.f;
  #pragma unroll 2
  for (int c = 0; c < C_; c++){
    float xv = xp[(size_t)c * THW_];
    const float* wr = wp + (size_t)c * 768;   // wave-uniform -> scalar loads
    #pragma unroll
    for (int o = 0; o < 64; o++) acc[o] = fmaf(wr[o], xv, acc[o]);
  }
  size_t ob = ((size_t)(b * C_ + oBase)) * THW_ + s;
  #pragma unroll
  for (int o = 0; o < 64; o++) out[ob + (size_t)o * THW_] = acc[o];
}

// ---------------- mean over (H,W): qg[b,c,t] ----------------
__global__ __launch_bounds__(256) void k_mean_hw(const float* __restrict__ q, float* __restrict__ qg){
  int bct = blockIdx.x;                      // (b*256+c)*32 + t
  const float4* p = (const float4*)(q + (size_t)bct * HW_);
  float4 v = p[threadIdx.x];
  float sum = v.x + v.y + v.z + v.w;
  #pragma unroll
  for (int off = 32; off; off >>= 1) sum += __shfl_down(sum, off);
  __shared__ float red[4];
  int lane = threadIdx.x & 63, w = threadIdx.x >> 6;
  if (lane == 0) red[w] = sum;
  __syncthreads();
  if (threadIdx.x == 0) qg[bct] = (red[0] + red[1] + red[2] + red[3]) * (1.f / 1024.f);
}

// ---------------- mix pre: h[b,o,t] = gelu(pre_w @ qg + pre_b) ----------------
__global__ __launch_bounds__(256) void k_mix_pre(const float* __restrict__ preW, const float* __restrict__ preB,
    const float* __restrict__ qg, float* __restrict__ hbuf){
  int b = blockIdx.x >> 5, t = blockIdx.x & 31;
  int o = threadIdx.x;
  __shared__ float qgl[256];
  qgl[o] = qg[((size_t)(b * C_ + o)) * T_ + t];
  __syncthreads();
  float a = preB[o];
  for (int c = 0; c < C_; c++) a = fmaf(preW[o * C_ + c], qgl[c], a);
  float g = 0.5f * a * (1.f + erff(a * 0.70710678118f));
  hbuf[((size_t)(b * C_ + o)) * T_ + t] = g;
}

// ---------------- mix logits + softmax over m: alpha[b,m,t] ----------------
__global__ __launch_bounds__(256) void k_mix_alpha(const float* __restrict__ cw, const float* __restrict__ cb,
    const float* __restrict__ hbuf, float* __restrict__ alpha){
  int b = blockIdx.x >> 5, t = blockIdx.x & 31;
  int c = threadIdx.x;
  float hv[3];
  #pragma unroll
  for (int j = 0; j < 3; j++){
    int tt = t - 2 + j;
    hv[j] = (tt >= 0) ? hbuf[((size_t)(b * C_ + c)) * T_ + tt] : 0.f;
  }
  float p[3];
  #pragma unroll
  for (int m = 0; m < 3; m++){
    const float* w = cw + ((size_t)m * C_ + c) * 3;
    p[m] = w[0] * hv[0] + w[1] * hv[1] + w[2] * hv[2];
  }
  #pragma unroll
  for (int m = 0; m < 3; m++){
    #pragma unroll
    for (int off = 32; off; off >>= 1) p[m] += __shfl_down(p[m], off);
  }
  __shared__ float red[3][4];
  int lane = threadIdx.x & 63, w = threadIdx.x >> 6;
  if (lane == 0){ red[0][w] = p[0]; red[1][w] = p[1]; red[2][w] = p[2]; }
  __syncthreads();
  if (threadIdx.x == 0){
    float lg[3];
    #pragma unroll
    for (int m = 0; m < 3; m++) lg[m] = red[m][0] + red[m][1] + red[m][2] + red[m][3] + cb[m];
    float mx = fmaxf(lg[0], fmaxf(lg[1], lg[2]));
    float e0 = __expf(lg[0] - mx), e1 = __expf(lg[1] - mx), e2 = __expf(lg[2] - mx);
    float r = 1.f / (e0 + e1 + e2);
    alpha[((size_t)(b * 3 + 0)) * T_ + t] = e0 * r;
    alpha[((size_t)(b * 3 + 1)) * T_ + t] = e1 * r;
    alpha[((size_t)(b * 3 + 2)) * T_ + t] = e2 * r;
  }
}

// ---------------- alpha-mixed causal depthwise conv 3x3x3, single tensor ----------------
// grid B*T*C (bi = c + 256*t + 8192*b), block 256.
template<typename OutT>
__global__ __launch_bounds__(256) void k_conv1(
    const float* __restrict__ in_g, const float* __restrict__ bank,
    const float* __restrict__ alpha, OutT* __restrict__ out)
{
  int bi = blockIdx.x;
  int c = bi & 255, t = (bi >> 8) & 31, b = bi >> 13;
  __shared__ float sIn[3 * 34 * 34];
  __shared__ float wmix[27];
  int tid = threadIdx.x;
  if (tid < 27){
    float sum = 0.f;
    #pragma unroll
    for (int m = 0; m < 3; m++)
      sum += alpha[((size_t)(b * 3 + m)) * T_ + t] * bank[((size_t)m * C_ + c) * 27 + tid];
    wmix[tid] = sum;
  }
  size_t cbase = ((size_t)(b * C_ + c)) * T_;
  for (int idx = tid; idx < 3 * 34 * 34; idx += 256){
    int tp = idx / 1156, rem = idx % 1156;
    int yy = rem / 34, xx = rem % 34;
    int tin = t - 2 + tp, y = yy - 1, x = xx - 1;
    bool ok = (tin >= 0) && (y >= 0) && (y < 32) && (x >= 0) && (x < 32);
    size_t g = ok ? ((cbase + tin) * HW_ + (size_t)y * 32 + x) : 0;
    sIn[idx] = ok ? in_g[g] : 0.f;
  }
  __syncthreads();
  int y = tid >> 3, x0 = (tid & 7) * 4;
  float a[4] = {0.f, 0.f, 0.f, 0.f};
  #pragma unroll
  for (int dt = 0; dt < 3; dt++){
    #pragma unroll
    for (int dy = 0; dy < 3; dy++){
      int rb = dt * 1156 + (y + dy) * 34 + x0;
      #pragma unroll
      for (int dx = 0; dx < 3; dx++){
        float wv = wmix[dt * 9 + dy * 3 + dx];
        #pragma unroll
        for (int p2 = 0; p2 < 4; p2++) a[p2] = fmaf(wv, sIn[rb + dx + p2], a[p2]);
      }
    }
  }
  size_t ob = (cbase + t) * HW_ + (size_t)y * 32 + x0;
  if constexpr (sizeof(OutT) == 2){
    __half2 h01 = __halves2half2(__float2half(a[0]), __float2half(a[1]));
    __half2 h23 = __halves2half2(__float2half(a[2]), __float2half(a[3]));
    *reinterpret_cast<__half2*>((__half*)out + ob)     = h01;
    *reinterpret_cast<__half2*>((__half*)out + ob + 2) = h23;
  } else {
    *(float4*)((float*)out + ob) = make_float4(a[0], a[1], a[2], a[3]);
  }
}

// ---------------- axial attention, one 32x32 sequence per wave ----------------
// AXIS: 0=T (causal), 1=H, 2=W. grid 4096 = ggrp(8) x outer(32) x head(8) x b(2), block 256.
// K is f16. ctx may alias vg_ (AXIS=2 in-place) -> no restrict on vg_/ctx.
template<int AXIS, typename CtxT>
__global__ __launch_bounds__(256) void k_attn(
    const float* __restrict__ qg_, const __half* __restrict__ kg_,
    const float* vg_, CtxT* ctx,
    const float* __restrict__ cosT, const float* __restrict__ sinT)
{
  const int SS = (AXIS == 0) ? HW_ : (AXIS == 1) ? 32 : 1;   // stride along sequence
  const int GS = (AXIS == 2) ? 32 : 1;                        // stride along seq-group dim
  const int OS = (AXIS == 0) ? 32 : HW_;                      // stride along outer dim
  int bi = blockIdx.x;
  int ggrp = bi & 7;  bi >>= 3;
  int outer = bi & 31; bi >>= 5;
  int head = bi & 7;
  int b = bi >> 3;
  const size_t base = ((size_t)(b * C_ + head * 32)) * THW_ + (size_t)outer * OS + (size_t)(ggrp * 4) * GS;

  __shared__ float q_l[4 * 32 * 33], k_l[4 * 32 * 33], v_l[4 * 32 * 33];
  const int tid = threadIdx.x;

  for (int idx = tid; idx < 4096; idx += 256){
    int f, i, g;
    if (AXIS == 2){ i = idx & 31; g = (idx >> 5) & 3; f = idx >> 7; }
    else          { g = idx & 3;  i = (idx >> 2) & 31; f = idx >> 7; }
    size_t go = base + (size_t)f * THW_ + (size_t)i * SS + (size_t)g * GS;
    int lo = (g * 32 + i) * 33 + f;
    q_l[lo] = qg_[go];
    k_l[lo] = __half2float(kg_[go]);
    v_l[lo] = vg_[go];
  }
  __syncthreads();

  const int lane = tid & 63;
  const int g = tid >> 6;           // wave id = local sequence
  const int i = lane & 31;          // query position
  const int fh = lane >> 5;         // feature half
  const int qb = (g * 32 + i) * 33 + fh * 16;
  float qr[16];
  #pragma unroll
  for (int u = 0; u < 16; u++) qr[u] = q_l[qb + u];
  #pragma unroll
  for (int u = 0; u < 16; u++){
    float part = __shfl_xor(qr[u], 32);
    float cv = cosT[i * 16 + u], sv = sinT[i * 16 + u];
    qr[u] = fh ? fmaf(qr[u], cv, part * sv) : fmaf(qr[u], cv, -part * sv);
  }
  // RoPE on K in LDS (disjoint pairs per idx -> race-free)
  for (int idx = tid; idx < 2048; idx += 256){
    int u = idx & 15, j = (idx >> 4) & 31, gg = idx >> 9;
    int kb = (gg * 32 + j) * 33;
    float k1 = k_l[kb + u], k2 = k_l[kb + 16 + u];
    float cv = cosT[j * 16 + u], sv = sinT[j * 16 + u];
    k_l[kb + u]      = k1 * cv - k2 * sv;
    k_l[kb + 16 + u] = fmaf(k2, cv, k1 * sv);
  }
  __syncthreads();

  float s_arr[32];
  const int kvb0 = g * 32 * 33 + fh * 16;
  #pragma unroll
  for (int j = 0; j < 32; j++){
    float p = 0.f;
    const float* kr = &k_l[kvb0 + j * 33];
    #pragma unroll
    for (int u = 0; u < 16; u++) p = fmaf(qr[u], kr[u], p);
    p += __shfl_xor(p, 32);
    p *= 0.17677669529663687f;      // 1/sqrt(32)
    if (AXIS == 0 && j > i) p = -1e30f;
    s_arr[j] = p;
  }
  float mx = s_arr[0];
  #pragma unroll
  for (int j = 1; j < 32; j++) mx = fmaxf(mx, s_arr[j]);
  float sum = 0.f;
  #pragma unroll
  for (int j = 0; j < 32; j++){ s_arr[j] = __expf(s_arr[j] - mx); sum += s_arr[j]; }
  float rinv = 1.f / sum;
  float acc[16];
  #pragma unroll
  for (int u = 0; u < 16; u++) acc[u] = 0.f;
  #pragma unroll
  for (int j = 0; j < 32; j++){
    float pv = s_arr[j] * rinv;
    const float* vr = &v_l[kvb0 + j * 33];
    #pragma unroll
    for (int u = 0; u < 16; u++) acc[u] = fmaf(pv, vr[u], acc[u]);
  }
  #pragma unroll
  for (int u = 0; u < 16; u++) q_l[qb + u] = acc[u];
  __syncthreads();
  for (int idx = tid; idx < 4096; idx += 256){
    int f, i2, g2;
    if (AXIS == 2){ i2 = idx & 31; g2 = (idx >> 5) & 3; f = idx >> 7; }
    else          { g2 = idx & 3;  i2 = (idx >> 2) & 31; f = idx >> 7; }
    size_t go = base + (size_t)f * THW_ + (size_t)i2 * SS + (size_t)g2 * GS;
    float val = q_l[(g2 * 32 + i2) * 33 + f];
    if constexpr (sizeof(CtxT) == 2) ctx[go] = __float2half(val);
    else                             ctx[go] = val;
  }
}

// ---------------- gate GEMM + sigmoid + combine: y (+)= sig(Wg[slice]x+b) * ctx --------
// grid (4, 128, 2), block 256. ldw = 768.
template<typename CtxT, bool FIRST>
__global__ __launch_bounds__(256) void k_gate_combine(
    const float* __restrict__ WT, int o0,
    const float* __restrict__ x, const float* __restrict__ gb,
    const CtxT* __restrict__ ctx, float* __restrict__ y)
{
  const int oBase = blockIdx.x * 64;
  const int s = blockIdx.y * 256 + threadIdx.x;
  const int b = blockIdx.z;
  const float* xp = x + ((size_t)b * C_) * THW_ + s;
  const float* wp = WT + o0 + oBase;
  float acc[64];
  #pragma unroll
  for (int o = 0; o < 64; o++) acc[o] = 0.f;
  #pragma unroll 2
  for (int c = 0; c < C_; c++){
    float xv = xp[(size_t)c * THW_];
    const float* wr = wp + (size_t)c * 768;
    #pragma unroll
    for (int o = 0; o < 64; o++) acc[o] = fmaf(wr[o], xv, acc[o]);
  }
  size_t ob = ((size_t)(b * C_ + oBase)) * THW_ + s;
  #pragma unroll
  for (int o = 0; o < 64; o++){
    float gv = 1.f / (1.f + __expf(-(acc[o] + gb[o0 + oBase + o])));
    float cv;
    if constexpr (sizeof(CtxT) == 2) cv = __half2float(ctx[ob + (size_t)o * THW_]);
    else                             cv = ctx[ob + (size_t)o * THW_];
    float val = gv * cv;
    if (FIRST) y[ob + (size_t)o * THW_] = val;
    else       y[ob + (size_t)o * THW_] += val;
  }
}

// ---------------- proj, in-place on d_out via s-column blocking ----------------
// grid (512, 2), block 256, dyn LDS 64KB. Each block owns 64 s-columns (all channels).
__global__ __launch_bounds__(256) void k_proj_inplace(
    const float* __restrict__ WT /* [c][o], ld 256 */, float* y)
{
  extern __shared__ float yt[];            // [256][64]
  const int sBase = blockIdx.x * 64;
  const int b = blockIdx.y;
  const int tid = threadIdx.x;
  for (int idx = tid; idx < 16384; idx += 256){
    int c = idx >> 6, sl = idx & 63;
    yt[idx] = y[((size_t)(b * C_ + c)) * THW_ + sBase + sl];
  }
  __syncthreads();
  const int sl = tid & 63, grp = tid >> 6;  // grp wave-uniform
  float acc[64];
  #pragma unroll
  for (int o = 0; o < 64; o++) acc[o] = 0.f;
  #pragma unroll 2
  for (int c = 0; c < C_; c++){
    float xv = yt[c * 64 + sl];
    const float* wr = WT + c * 256 + grp * 64;  // wave-uniform -> scalar loads
    #pragma unroll
    for (int o = 0; o < 64; o++) acc[o] = fmaf(wr[o], xv, acc[o]);
  }
  #pragma unroll
  for (int o = 0; o < 64; o++)
    y[((size_t)(b * C_ + grp * 64 + o)) * THW_ + sBase + sl] = acc[o];
}

extern "C" void kernel_launch(void* const* d_in, const int* in_sizes, int n_in,
                              void* d_out, int out_size, void* d_ws, size_t ws_size,
                              hipStream_t stream)
{
  (void)in_sizes; (void)n_in; (void)out_size; (void)ws_size;
  const float* x       = (const float*)d_in[0];
  const float* w_qkv   = (const float*)d_in[1];
  const float* wk_bank = (const float*)d_in[2];
  const float* wv_bank = (const float*)d_in[3];
  const float* pre_w   = (const float*)d_in[4];
  const float* pre_b   = (const float*)d_in[5];
  const float* cw      = (const float*)d_in[6];
  const float* cb      = (const float*)d_in[7];
  const float* gate_w  = (const float*)d_in[8];
  const float* gate_b  = (const float*)d_in[9];
  const float* proj_w  = (const float*)d_in[10];

  float* ws = (float*)d_ws;
  const size_t SZ = (size_t)B_ * C_ * THW_;         // 16,777,216 floats (64 MB)
  float*  wsA   = ws;                               // k  -> v_out -> ctx_w (in-place)
  float*  wsB   = ws + SZ;                          // v  -> ctx_t
  __half* koH   = (__half*)(ws + 2 * SZ);           // k_out (f16), SZ halves
  __half* ctxhH = koH + SZ;                         // ctx_h (f16), SZ halves
  float* sm     = ws + 3 * SZ;                      // small region (~0.9 MB)
  float* wt0    = sm;                               // 196608 (wt_qkv -> wt_gate -> wt_proj)
  float* qg     = sm + 196608;                      // 16384
  float* hbuf   = qg + 16384;                       // 16384
  float* alpha  = hbuf + 16384;                     // 192
  float* cosT   = alpha + 192;                      // 512
  float* sinT   = cosT + 512;                       // 512
  float* q = (float*)d_out;                         // q parked in d_out until combine

  k_rope_table<<<1, 512, 0, stream>>>(cosT, sinT);
  k_transpose<<<768, 256, 0, stream>>>(w_qkv, wt0, 768, 256);

  dim3 gq(4, 128, 2);
  k_gemm_qkv<<<gq, 256, 0, stream>>>(wt0, 0,   x, q);     // q -> d_out
  k_gemm_qkv<<<gq, 256, 0, stream>>>(wt0, 256, x, wsA);   // k
  k_gemm_qkv<<<gq, 256, 0, stream>>>(wt0, 512, x, wsB);   // v

  k_mean_hw<<<16384, 256, 0, stream>>>(q, qg);
  k_mix_pre<<<64, 256, 0, stream>>>(pre_w, pre_b, qg, hbuf);
  k_mix_alpha<<<64, 256, 0, stream>>>(cw, cb, hbuf, alpha);

  k_conv1<__half><<<16384, 256, 0, stream>>>(wsA, wk_bank, alpha, koH);  // k_out f16
  k_conv1<float ><<<16384, 256, 0, stream>>>(wsB, wv_bank, alpha, wsA);  // v_out over dead k

  k_attn<0, float ><<<4096, 256, 0, stream>>>(q, koH, wsA, wsB,           cosT, sinT); // ctx_t (v dead)
  k_attn<1, __half><<<4096, 256, 0, stream>>>(q, koH, wsA, ctxhH,         cosT, sinT); // ctx_h f16
  k_attn<2, float ><<<4096, 256, 0, stream>>>(q, koH, wsA, wsA,           cosT, sinT); // ctx_w in-place

  k_transpose<<<768, 256, 0, stream>>>(gate_w, wt0, 768, 256);            // wt_qkv dead
  k_gate_combine<float , true ><<<gq, 256, 0, stream>>>(wt0, 0,   x, gate_b, wsB,   q); // y over dead q
  k_gate_combine<__half, false><<<gq, 256, 0, stream>>>(wt0, 256, x, gate_b, ctxhH, q);
  k_gate_combine<float , false><<<gq, 256, 0, stream>>>(wt0, 512, x, gate_b, wsA,   q);

  k_transpose<<<256, 256, 0, stream>>>(proj_w, wt0, 256, 256);            // wt_gate dead
  k_proj_inplace<<<dim3(512, 2), 256, 65536, stream>>>(wt0, (float*)d_out);
}

// Round 3
// 1201.183 us; speedup vs baseline: 1.8044x; 1.8044x over previous
//
#include <hip/hip_runtime.h>
#include <hip/hip_fp16.h>
#include <math.h>

#define B_   2
#define C_   256
#define T_   32
#define HW_  1024
#define THW_ 32768

using u32 = unsigned int;
typedef __attribute__((ext_vector_type(8))) short bf8_t;   // 8 bf16 in 4 VGPRs
typedef __attribute__((ext_vector_type(4))) float f4_t;

static __device__ __forceinline__ unsigned short f2bf(float x){
  u32 u = __float_as_uint(x);
  u32 r = (u + 0x7FFF + ((u >> 16) & 1)) >> 16;   // RNE
  return (unsigned short)r;
}

// ---------------- rope table ----------------
__global__ void k_rope_table(float* __restrict__ cosT, float* __restrict__ sinT){
  int tid = threadIdx.x;            // 512 threads, tid = i*16+u
  int i = tid >> 4, u = tid & 15;
  float invf = powf(10000.f, -(2.f * (float)u) / 32.f);
  float s, c;
  sincosf((float)i * invf, &s, &c);
  cosT[tid] = c;
  sinT[tid] = s;
}

// ---------------- transpose+cvt: f32 [b][256][THW] -> bf16 [b][THW][256] ----------------
__global__ __launch_bounds__(256) void k_transpose_cvt(
    const float* __restrict__ in, unsigned short* __restrict__ outT)
{
  __shared__ float tile[64][65];
  int s0 = blockIdx.x * 64;     // 512
  int c0 = blockIdx.y * 64;     // 4
  int b  = blockIdx.z;
  int tid = threadIdx.x;
  for (int idx = tid; idx < 4096; idx += 256){
    int c = idx >> 6, s = idx & 63;
    tile[c][s] = in[((size_t)(b * C_ + c0 + c)) * THW_ + s0 + s];
  }
  __syncthreads();
  for (int idx = tid; idx < 4096; idx += 256){
    int s = idx >> 6, c = idx & 63;
    outT[((size_t)b * THW_ + s0 + s) * 256 + c0 + c] = f2bf(tile[c][s]);
  }
}

// ---------------- MFMA GEMM core: acc[4][4] += A[o0..o0+128)x256 (f32) * B^T panel (bf16) ----
// Block 256 thr = 4 waves (2x2 of 64x64). BK=64, 4 K-steps. LDS tiles XOR-swizzled (T2).
static __device__ __forceinline__ void gemm_core(
    const float* __restrict__ A, int o0,
    const unsigned short* __restrict__ BT,   // pre-offset: + (b*THW + s0)*256
    unsigned short* As, unsigned short* Bs, f4_t acc[4][4])
{
  const int tid = threadIdx.x;
  const int lane = tid & 63, wv = tid >> 6;
  const int wm = wv >> 1, wn = wv & 1;
  const int m = lane & 15, kg = lane >> 4;
  const int srow = tid >> 1, ch = (tid & 1) * 32;       // staging: row, 32-elem half
  for (int ks = 0; ks < 4; ks++){
    __syncthreads();                                    // protect prior reads
    {
      const float* ga = A + (size_t)(o0 + srow) * 256 + ks * 64 + ch;
      float f[32];
      #pragma unroll
      for (int q2 = 0; q2 < 8; q2++) *(float4*)(f + q2 * 4) = *(const float4*)(ga + q2 * 4);
      #pragma unroll
      for (int q2 = 0; q2 < 4; q2++){
        bf8_t t;
        #pragma unroll
        for (int j = 0; j < 8; j++) t[j] = (short)f2bf(f[q2 * 8 + j]);
        *(bf8_t*)((char*)As + srow * 128 + ((ch * 2 + q2 * 16) ^ ((srow & 7) << 4))) = t;
      }
      const unsigned short* gbp = BT + (size_t)srow * 256 + ks * 64 + ch;
      #pragma unroll
      for (int q2 = 0; q2 < 4; q2++){
        bf8_t v = *(const bf8_t*)(gbp + q2 * 8);
        *(bf8_t*)((char*)Bs + srow * 128 + ((ch * 2 + q2 * 16) ^ ((srow & 7) << 4))) = v;
      }
    }
    __syncthreads();
    #pragma unroll
    for (int kk = 0; kk < 2; kk++){
      bf8_t af[4], bfr[4];
      #pragma unroll
      for (int mi = 0; mi < 4; mi++){
        int row = wm * 64 + mi * 16 + m;
        af[mi] = *(const bf8_t*)((const char*)As + row * 128 + ((kk * 64 + kg * 16) ^ ((row & 7) << 4)));
      }
      #pragma unroll
      for (int ni = 0; ni < 4; ni++){
        int row = wn * 64 + ni * 16 + m;
        bfr[ni] = *(const bf8_t*)((const char*)Bs + row * 128 + ((kk * 64 + kg * 16) ^ ((row & 7) << 4)));
      }
      #pragma unroll
      for (int mi = 0; mi < 4; mi++)
        #pragma unroll
        for (int ni = 0; ni < 4; ni++)
          acc[mi][ni] = __builtin_amdgcn_mfma_f32_16x16x32_bf16(af[mi], bfr[ni], acc[mi][ni], 0, 0, 0);
    }
  }
}

// ---------------- qkv GEMM: W[768][256] @ x -> q,k,v ----------------
__global__ __launch_bounds__(256) void k_mfma_qkv(
    const float* __restrict__ W, const unsigned short* __restrict__ xT,
    float* __restrict__ q, float* __restrict__ k, float* __restrict__ v)
{
  __shared__ unsigned short As[8192], Bs[8192];
  const int bo = blockIdx.x;                  // 0..5
  const int s0 = blockIdx.y * 128;            // 256
  const int b  = blockIdx.z;
  f4_t acc[4][4];
  #pragma unroll
  for (int mi = 0; mi < 4; mi++)
    #pragma unroll
    for (int ni = 0; ni < 4; ni++) acc[mi][ni] = (f4_t)0.f;
  gemm_core(W, bo * 128, xT + ((size_t)b * THW_ + s0) * 256, As, Bs, acc);
  float* outp = (bo < 2) ? q : (bo < 4) ? k : v;
  const int ro = (bo & 1) * 128;
  const int lane = threadIdx.x & 63, wv = threadIdx.x >> 6;
  const int wm = wv >> 1, wn = wv & 1;
  size_t obase = (size_t)(b * C_) * THW_;
  #pragma unroll
  for (int mi = 0; mi < 4; mi++)
    #pragma unroll
    for (int ni = 0; ni < 4; ni++)
      #pragma unroll
      for (int r = 0; r < 4; r++){
        int o = ro + wm * 64 + mi * 16 + (lane >> 4) * 4 + r;
        int s = s0 + wn * 64 + ni * 16 + (lane & 15);
        outp[obase + (size_t)o * THW_ + s] = acc[mi][ni][r];
      }
}

// ---------------- gate GEMM + sigmoid + combine (3 slices) -> y ----------------
__global__ __launch_bounds__(256) void k_mfma_gate(
    const float* __restrict__ W, const unsigned short* __restrict__ xT,
    const float* __restrict__ gb,
    const float* __restrict__ ctx_t, const __half* __restrict__ ctx_h,
    const float* __restrict__ ctx_w, float* __restrict__ y)
{
  __shared__ unsigned short As[8192], Bs[8192];
  const int bo = blockIdx.x;                  // 0..1
  const int s0 = blockIdx.y * 128;
  const int b  = blockIdx.z;
  const int lane = threadIdx.x & 63, wv = threadIdx.x >> 6;
  const int wm = wv >> 1, wn = wv & 1;
  const size_t obase = (size_t)(b * C_) * THW_;
  f4_t yacc[4][4];
  #pragma unroll
  for (int mi = 0; mi < 4; mi++)
    #pragma unroll
    for (int ni = 0; ni < 4; ni++) yacc[mi][ni] = (f4_t)0.f;
  for (int slice = 0; slice < 3; slice++){
    f4_t acc[4][4];
    #pragma unroll
    for (int mi = 0; mi < 4; mi++)
      #pragma unroll
      for (int ni = 0; ni < 4; ni++) acc[mi][ni] = (f4_t)0.f;
    gemm_core(W, slice * 256 + bo * 128, xT + ((size_t)b * THW_ + s0) * 256, As, Bs, acc);
    #pragma unroll
    for (int mi = 0; mi < 4; mi++)
      #pragma unroll
      for (int ni = 0; ni < 4; ni++)
        #pragma unroll
        for (int r = 0; r < 4; r++){
          int o = bo * 128 + wm * 64 + mi * 16 + (lane >> 4) * 4 + r;
          int s = s0 + wn * 64 + ni * 16 + (lane & 15);
          float lg = acc[mi][ni][r] + gb[slice * 256 + o];
          float g = 1.f / (1.f + __expf(-lg));
          size_t idx = obase + (size_t)o * THW_ + s;
          float cv = (slice == 0) ? ctx_t[idx]
                   : (slice == 1) ? __half2float(ctx_h[idx])
                                  : ctx_w[idx];
          yacc[mi][ni][r] += g * cv;
        }
  }
  #pragma unroll
  for (int mi = 0; mi < 4; mi++)
    #pragma unroll
    for (int ni = 0; ni < 4; ni++)
      #pragma unroll
      for (int r = 0; r < 4; r++){
        int o = bo * 128 + wm * 64 + mi * 16 + (lane >> 4) * 4 + r;
        int s = s0 + wn * 64 + ni * 16 + (lane & 15);
        y[obase + (size_t)o * THW_ + s] = yacc[mi][ni][r];
      }
}

// ---------------- proj GEMM -> d_out ----------------
__global__ __launch_bounds__(256) void k_mfma_proj(
    const float* __restrict__ W, const unsigned short* __restrict__ yT,
    float* __restrict__ out)
{
  __shared__ unsigned short As[8192], Bs[8192];
  const int bo = blockIdx.x;                  // 0..1
  const int s0 = blockIdx.y * 128;
  const int b  = blockIdx.z;
  f4_t acc[4][4];
  #pragma unroll
  for (int mi = 0; mi < 4; mi++)
    #pragma unroll
    for (int ni = 0; ni < 4; ni++) acc[mi][ni] = (f4_t)0.f;
  gemm_core(W, bo * 128, yT + ((size_t)b * THW_ + s0) * 256, As, Bs, acc);
  const int lane = threadIdx.x & 63, wv = threadIdx.x >> 6;
  const int wm = wv >> 1, wn = wv & 1;
  size_t obase = (size_t)(b * C_) * THW_;
  #pragma unroll
  for (int mi = 0; mi < 4; mi++)
    #pragma unroll
    for (int ni = 0; ni < 4; ni++)
      #pragma unroll
      for (int r = 0; r < 4; r++){
        int o = bo * 128 + wm * 64 + mi * 16 + (lane >> 4) * 4 + r;
        int s = s0 + wn * 64 + ni * 16 + (lane & 15);
        out[obase + (size_t)o * THW_ + s] = acc[mi][ni][r];
      }
}

// ---------------- mean over (H,W): qg[b,c,t] ----------------
__global__ __launch_bounds__(256) void k_mean_hw(const float* __restrict__ q, float* __restrict__ qg){
  int bct = blockIdx.x;
  const float4* p = (const float4*)(q + (size_t)bct * HW_);
  float4 v = p[threadIdx.x];
  float sum = v.x + v.y + v.z + v.w;
  #pragma unroll
  for (int off = 32; off; off >>= 1) sum += __shfl_down(sum, off);
  __shared__ float red[4];
  int lane = threadIdx.x & 63, w = threadIdx.x >> 6;
  if (lane == 0) red[w] = sum;
  __syncthreads();
  if (threadIdx.x == 0) qg[bct] = (red[0] + red[1] + red[2] + red[3]) * (1.f / 1024.f);
}

// ---------------- mix pre: h = gelu(pre_w @ qg + pre_b) ----------------
__global__ __launch_bounds__(256) void k_mix_pre(const float* __restrict__ preW, const float* __restrict__ preB,
    const float* __restrict__ qg, float* __restrict__ hbuf){
  int b = blockIdx.x >> 5, t = blockIdx.x & 31;
  int o = threadIdx.x;
  __shared__ float qgl[256];
  qgl[o] = qg[((size_t)(b * C_ + o)) * T_ + t];
  __syncthreads();
  float a = preB[o];
  for (int c = 0; c < C_; c++) a = fmaf(preW[o * C_ + c], qgl[c], a);
  float g = 0.5f * a * (1.f + erff(a * 0.70710678118f));
  hbuf[((size_t)(b * C_ + o)) * T_ + t] = g;
}

// ---------------- mix logits + softmax over m ----------------
__global__ __launch_bounds__(256) void k_mix_alpha(const float* __restrict__ cw, const float* __restrict__ cb,
    const float* __restrict__ hbuf, float* __restrict__ alpha){
  int b = blockIdx.x >> 5, t = blockIdx.x & 31;
  int c = threadIdx.x;
  float hv[3];
  #pragma unroll
  for (int j = 0; j < 3; j++){
    int tt = t - 2 + j;
    hv[j] = (tt >= 0) ? hbuf[((size_t)(b * C_ + c)) * T_ + tt] : 0.f;
  }
  float p[3];
  #pragma unroll
  for (int m = 0; m < 3; m++){
    const float* w = cw + ((size_t)m * C_ + c) * 3;
    p[m] = w[0] * hv[0] + w[1] * hv[1] + w[2] * hv[2];
  }
  #pragma unroll
  for (int m = 0; m < 3; m++){
    #pragma unroll
    for (int off = 32; off; off >>= 1) p[m] += __shfl_down(p[m], off);
  }
  __shared__ float red[3][4];
  int lane = threadIdx.x & 63, w = threadIdx.x >> 6;
  if (lane == 0){ red[0][w] = p[0]; red[1][w] = p[1]; red[2][w] = p[2]; }
  __syncthreads();
  if (threadIdx.x == 0){
    float lg[3];
    #pragma unroll
    for (int m = 0; m < 3; m++) lg[m] = red[m][0] + red[m][1] + red[m][2] + red[m][3] + cb[m];
    float mx = fmaxf(lg[0], fmaxf(lg[1], lg[2]));
    float e0 = __expf(lg[0] - mx), e1 = __expf(lg[1] - mx), e2 = __expf(lg[2] - mx);
    float r = 1.f / (e0 + e1 + e2);
    alpha[((size_t)(b * 3 + 0)) * T_ + t] = e0 * r;
    alpha[((size_t)(b * 3 + 1)) * T_ + t] = e1 * r;
    alpha[((size_t)(b * 3 + 2)) * T_ + t] = e2 * r;
  }
}

// ---------------- alpha-mixed causal depthwise conv 3x3x3 ----------------
template<typename OutT>
__global__ __launch_bounds__(256) void k_conv1(
    const float* __restrict__ in_g, const float* __restrict__ bank,
    const float* __restrict__ alpha, OutT* __restrict__ out)
{
  int bi = blockIdx.x;
  int c = bi & 255, t = (bi >> 8) & 31, b = bi >> 13;
  __shared__ float sIn[3 * 34 * 34];
  __shared__ float wmix[27];
  int tid = threadIdx.x;
  if (tid < 27){
    float sum = 0.f;
    #pragma unroll
    for (int m = 0; m < 3; m++)
      sum += alpha[((size_t)(b * 3 + m)) * T_ + t] * bank[((size_t)m * C_ + c) * 27 + tid];
    wmix[tid] = sum;
  }
  size_t cbase = ((size_t)(b * C_ + c)) * T_;
  for (int idx = tid; idx < 3 * 34 * 34; idx += 256){
    int tp = idx / 1156, rem = idx % 1156;
    int yy = rem / 34, xx = rem % 34;
    int tin = t - 2 + tp, y = yy - 1, x = xx - 1;
    bool ok = (tin >= 0) && (y >= 0) && (y < 32) && (x >= 0) && (x < 32);
    size_t g = ok ? ((cbase + tin) * HW_ + (size_t)y * 32 + x) : 0;
    sIn[idx] = ok ? in_g[g] : 0.f;
  }
  __syncthreads();
  int y = tid >> 3, x0 = (tid & 7) * 4;
  float a[4] = {0.f, 0.f, 0.f, 0.f};
  #pragma unroll
  for (int dt = 0; dt < 3; dt++){
    #pragma unroll
    for (int dy = 0; dy < 3; dy++){
      int rb = dt * 1156 + (y + dy) * 34 + x0;
      #pragma unroll
      for (int dx = 0; dx < 3; dx++){
        float wv = wmix[dt * 9 + dy * 3 + dx];
        #pragma unroll
        for (int p2 = 0; p2 < 4; p2++) a[p2] = fmaf(wv, sIn[rb + dx + p2], a[p2]);
      }
    }
  }
  size_t ob = (cbase + t) * HW_ + (size_t)y * 32 + x0;
  if constexpr (sizeof(OutT) == 2){
    __half2 h01 = __halves2half2(__float2half(a[0]), __float2half(a[1]));
    __half2 h23 = __halves2half2(__float2half(a[2]), __float2half(a[3]));
    *reinterpret_cast<__half2*>((__half*)out + ob)     = h01;
    *reinterpret_cast<__half2*>((__half*)out + ob + 2) = h23;
  } else {
    *(float4*)((float*)out + ob) = make_float4(a[0], a[1], a[2], a[3]);
  }
}

// ---------------- axial attention, one 32x32 sequence per wave ----------------
template<int AXIS, typename CtxT>
__global__ __launch_bounds__(256) void k_attn(
    const float* __restrict__ qg_, const __half* __restrict__ kg_,
    const float* vg_, CtxT* ctx,
    const float* __restrict__ cosT, const float* __restrict__ sinT)
{
  const int SS = (AXIS == 0) ? HW_ : (AXIS == 1) ? 32 : 1;
  const int GS = (AXIS == 2) ? 32 : 1;
  const int OS = (AXIS == 0) ? 32 : HW_;
  int bi = blockIdx.x;
  int ggrp = bi & 7;  bi >>= 3;
  int outer = bi & 31; bi >>= 5;
  int head = bi & 7;
  int b = bi >> 3;
  const size_t base = ((size_t)(b * C_ + head * 32)) * THW_ + (size_t)outer * OS + (size_t)(ggrp * 4) * GS;

  __shared__ float q_l[4 * 32 * 33], k_l[4 * 32 * 33], v_l[4 * 32 * 33];
  const int tid = threadIdx.x;

  for (int idx = tid; idx < 4096; idx += 256){
    int f, i, g;
    if (AXIS == 2){ i = idx & 31; g = (idx >> 5) & 3; f = idx >> 7; }
    else          { g = idx & 3;  i = (idx >> 2) & 31; f = idx >> 7; }
    size_t go = base + (size_t)f * THW_ + (size_t)i * SS + (size_t)g * GS;
    int lo = (g * 32 + i) * 33 + f;
    q_l[lo] = qg_[go];
    k_l[lo] = __half2float(kg_[go]);
    v_l[lo] = vg_[go];
  }
  __syncthreads();

  const int lane = tid & 63;
  const int g = tid >> 6;
  const int i = lane & 31;
  const int fh = lane >> 5;
  const int qb = (g * 32 + i) * 33 + fh * 16;
  float qr[16];
  #pragma unroll
  for (int u = 0; u < 16; u++) qr[u] = q_l[qb + u];
  #pragma unroll
  for (int u = 0; u < 16; u++){
    float part = __shfl_xor(qr[u], 32);
    float cv = cosT[i * 16 + u], sv = sinT[i * 16 + u];
    qr[u] = fh ? fmaf(qr[u], cv, part * sv) : fmaf(qr[u], cv, -part * sv);
  }
  for (int idx = tid; idx < 2048; idx += 256){
    int u = idx & 15, j = (idx >> 4) & 31, gg = idx >> 9;
    int kb = (gg * 32 + j) * 33;
    float k1 = k_l[kb + u], k2 = k_l[kb + 16 + u];
    float cv = cosT[j * 16 + u], sv = sinT[j * 16 + u];
    k_l[kb + u]      = k1 * cv - k2 * sv;
    k_l[kb + 16 + u] = fmaf(k2, cv, k1 * sv);
  }
  __syncthreads();

  float s_arr[32];
  const int kvb0 = g * 32 * 33 + fh * 16;
  #pragma unroll
  for (int j = 0; j < 32; j++){
    float p = 0.f;
    const float* kr = &k_l[kvb0 + j * 33];
    #pragma unroll
    for (int u = 0; u < 16; u++) p = fmaf(qr[u], kr[u], p);
    p += __shfl_xor(p, 32);
    p *= 0.17677669529663687f;
    if (AXIS == 0 && j > i) p = -1e30f;
    s_arr[j] = p;
  }
  float mx = s_arr[0];
  #pragma unroll
  for (int j = 1; j < 32; j++) mx = fmaxf(mx, s_arr[j]);
  float sum = 0.f;
  #pragma unroll
  for (int j = 0; j < 32; j++){ s_arr[j] = __expf(s_arr[j] - mx); sum += s_arr[j]; }
  float rinv = 1.f / sum;
  float acc[16];
  #pragma unroll
  for (int u = 0; u < 16; u++) acc[u] = 0.f;
  #pragma unroll
  for (int j = 0; j < 32; j++){
    float pv = s_arr[j] * rinv;
    const float* vr = &v_l[kvb0 + j * 33];
    #pragma unroll
    for (int u = 0; u < 16; u++) acc[u] = fmaf(pv, vr[u], acc[u]);
  }
  #pragma unroll
  for (int u = 0; u < 16; u++) q_l[qb + u] = acc[u];
  __syncthreads();
  for (int idx = tid; idx < 4096; idx += 256){
    int f, i2, g2;
    if (AXIS == 2){ i2 = idx & 31; g2 = (idx >> 5) & 3; f = idx >> 7; }
    else          { g2 = idx & 3;  i2 = (idx >> 2) & 31; f = idx >> 7; }
    size_t go = base + (size_t)f * THW_ + (size_t)i2 * SS + (size_t)g2 * GS;
    float val = q_l[(g2 * 32 + i2) * 33 + f];
    if constexpr (sizeof(CtxT) == 2) ctx[go] = __float2half(val);
    else                             ctx[go] = val;
  }
}

extern "C" void kernel_launch(void* const* d_in, const int* in_sizes, int n_in,
                              void* d_out, int out_size, void* d_ws, size_t ws_size,
                              hipStream_t stream)
{
  (void)in_sizes; (void)n_in; (void)out_size; (void)ws_size;
  const float* x       = (const float*)d_in[0];
  const float* w_qkv   = (const float*)d_in[1];
  const float* wk_bank = (const float*)d_in[2];
  const float* wv_bank = (const float*)d_in[3];
  const float* pre_w   = (const float*)d_in[4];
  const float* pre_b   = (const float*)d_in[5];
  const float* cw      = (const float*)d_in[6];
  const float* cb      = (const float*)d_in[7];
  const float* gate_w  = (const float*)d_in[8];
  const float* gate_b  = (const float*)d_in[9];
  const float* proj_w  = (const float*)d_in[10];

  float* ws = (float*)d_ws;
  const size_t SZ = (size_t)B_ * C_ * THW_;         // 16,777,216 floats (64 MB)
  float*  wsA   = ws;                               // k -> v_out -> ctx_w -> yT(bf16,lo)
  float*  wsB   = ws + SZ;                          // v -> ctx_t -> y
  float*  wsC   = ws + 2 * SZ;                      // lo: xT(bf16)->ctx_h(f16); hi: k_out(f16)->xT2(bf16)
  unsigned short* xT    = (unsigned short*)wsC;             // SZ bf16 elems (33.5 MB)
  __half*         ctxhH = (__half*)wsC;                     // ctx_h over dead xT
  __half*         koH   = (__half*)(ws + 2 * SZ + SZ / 2);  // hi half
  unsigned short* xT2   = (unsigned short*)koH;             // over dead k_out
  unsigned short* yT    = (unsigned short*)wsA;             // over dead ctx_w
  float* sm     = ws + 3 * SZ;                      // smalls
  float* qg     = sm;                               // 16384
  float* hbuf   = qg + 16384;                       // 16384
  float* alpha  = hbuf + 16384;                     // 192
  float* cosT   = alpha + 192;                      // 512
  float* sinT   = cosT + 512;                       // 512
  float* q = (float*)d_out;                         // q parked in d_out until proj

  k_rope_table<<<1, 512, 0, stream>>>(cosT, sinT);
  k_transpose_cvt<<<dim3(512, 4, 2), 256, 0, stream>>>(x, xT);

  k_mfma_qkv<<<dim3(6, 256, 2), 256, 0, stream>>>(w_qkv, xT, q, wsA, wsB);

  k_mean_hw<<<16384, 256, 0, stream>>>(q, qg);
  k_mix_pre<<<64, 256, 0, stream>>>(pre_w, pre_b, qg, hbuf);
  k_mix_alpha<<<64, 256, 0, stream>>>(cw, cb, hbuf, alpha);

  k_conv1<__half><<<16384, 256, 0, stream>>>(wsA, wk_bank, alpha, koH);  // k_out f16
  k_conv1<float ><<<16384, 256, 0, stream>>>(wsB, wv_bank, alpha, wsA);  // v_out over dead k

  k_attn<0, float ><<<4096, 256, 0, stream>>>(q, koH, wsA, wsB,   cosT, sinT); // ctx_t (v dead)
  k_attn<1, __half><<<4096, 256, 0, stream>>>(q, koH, wsA, ctxhH, cosT, sinT); // ctx_h f16 (xT dead)
  k_attn<2, float ><<<4096, 256, 0, stream>>>(q, koH, wsA, wsA,   cosT, sinT); // ctx_w in-place

  k_transpose_cvt<<<dim3(512, 4, 2), 256, 0, stream>>>(x, xT2);           // k_out dead
  k_mfma_gate<<<dim3(2, 256, 2), 256, 0, stream>>>(gate_w, xT2, gate_b,
                                                   wsB, ctxhH, wsA, wsB); // y over ctx_t (elementwise)
  k_transpose_cvt<<<dim3(512, 4, 2), 256, 0, stream>>>(wsB, yT);          // ctx_w dead
  k_mfma_proj<<<dim3(2, 256, 2), 256, 0, stream>>>(proj_w, yT, (float*)d_out); // q dead
}

// Round 4
// 778.872 us; speedup vs baseline: 2.7828x; 1.5422x over previous
//
#include <hip/hip_runtime.h>
#include <hip/hip_fp16.h>
#include <math.h>

#define B_   2
#define C_   256
#define T_   32
#define HW_  1024
#define THW_ 32768

using u32 = unsigned int;
typedef __attribute__((ext_vector_type(8))) short bf8_t;   // 8 bf16 in 4 VGPRs
typedef __attribute__((ext_vector_type(4))) float f4_t;

static __device__ __forceinline__ unsigned short f2bf(float x){
  u32 u = __float_as_uint(x);
  u32 r = (u + 0x7FFF + ((u >> 16) & 1)) >> 16;   // RNE
  return (unsigned short)r;
}
static __device__ __forceinline__ float h2f_u(unsigned short u){
  union { __half h; unsigned short us; } cv; cv.us = u; return __half2float(cv.h);
}
static __device__ __forceinline__ unsigned short f2h_u(float f){
  union { __half h; unsigned short us; } cv; cv.h = __float2half(f); return cv.us;
}
static __device__ __forceinline__ float ldf(const float* p){ return *p; }
static __device__ __forceinline__ float ldf(const __half* p){ return __half2float(*p); }

// ---------------- rope table ----------------
__global__ void k_rope_table(float* __restrict__ cosT, float* __restrict__ sinT){
  int tid = threadIdx.x;            // 512 threads, tid = i*16+u
  int i = tid >> 4, u = tid & 15;
  float invf = powf(10000.f, -(2.f * (float)u) / 32.f);
  float s, c;
  sincosf((float)i * invf, &s, &c);
  cosT[tid] = c;
  sinT[tid] = s;
}

// ---------------- transpose+cvt: [b][256][THW] (f32/f16) -> bf16 [b][THW][256] ----------------
template<typename InT>
__global__ __launch_bounds__(256) void k_transpose_cvt(
    const InT* __restrict__ in, unsigned short* __restrict__ outT)
{
  __shared__ float tile[64][65];
  int s0 = blockIdx.x * 64;     // 512
  int c0 = blockIdx.y * 64;     // 4
  int b  = blockIdx.z;
  int tid = threadIdx.x;
  for (int idx = tid; idx < 4096; idx += 256){
    int c = idx >> 6, s = idx & 63;
    tile[c][s] = ldf(&in[((size_t)(b * C_ + c0 + c)) * THW_ + s0 + s]);
  }
  __syncthreads();
  for (int idx = tid; idx < 4096; idx += 256){
    int s = idx >> 6, c = idx & 63;
    outT[((size_t)b * THW_ + s0 + s) * 256 + c0 + c] = f2bf(tile[c][s]);
  }
}

// ---------------- MFMA GEMM core: acc[4][4] += A[o0..o0+128)x256 (f32) * B^T panel (bf16) ----
static __device__ __forceinline__ void gemm_core(
    const float* __restrict__ A, int o0,
    const unsigned short* __restrict__ BT,   // pre-offset: + (b*THW + s0)*256
    unsigned short* As, unsigned short* Bs, f4_t acc[4][4])
{
  const int tid = threadIdx.x;
  const int lane = tid & 63, wv = tid >> 6;
  const int wm = wv >> 1, wn = wv & 1;
  const int m = lane & 15, kg = lane >> 4;
  const int srow = tid >> 1, ch = (tid & 1) * 32;       // staging: row, 32-elem half
  for (int ks = 0; ks < 4; ks++){
    __syncthreads();                                    // protect prior reads
    {
      const float* ga = A + (size_t)(o0 + srow) * 256 + ks * 64 + ch;
      float f[32];
      #pragma unroll
      for (int q2 = 0; q2 < 8; q2++) *(float4*)(f + q2 * 4) = *(const float4*)(ga + q2 * 4);
      #pragma unroll
      for (int q2 = 0; q2 < 4; q2++){
        bf8_t t;
        #pragma unroll
        for (int j = 0; j < 8; j++) t[j] = (short)f2bf(f[q2 * 8 + j]);
        *(bf8_t*)((char*)As + srow * 128 + ((ch * 2 + q2 * 16) ^ ((srow & 7) << 4))) = t;
      }
      const unsigned short* gbp = BT + (size_t)srow * 256 + ks * 64 + ch;
      #pragma unroll
      for (int q2 = 0; q2 < 4; q2++){
        bf8_t v = *(const bf8_t*)(gbp + q2 * 8);
        *(bf8_t*)((char*)Bs + srow * 128 + ((ch * 2 + q2 * 16) ^ ((srow & 7) << 4))) = v;
      }
    }
    __syncthreads();
    #pragma unroll
    for (int kk = 0; kk < 2; kk++){
      bf8_t af[4], bfr[4];
      #pragma unroll
      for (int mi = 0; mi < 4; mi++){
        int row = wm * 64 + mi * 16 + m;
        af[mi] = *(const bf8_t*)((const char*)As + row * 128 + ((kk * 64 + kg * 16) ^ ((row & 7) << 4)));
      }
      #pragma unroll
      for (int ni = 0; ni < 4; ni++){
        int row = wn * 64 + ni * 16 + m;
        bfr[ni] = *(const bf8_t*)((const char*)Bs + row * 128 + ((kk * 64 + kg * 16) ^ ((row & 7) << 4)));
      }
      #pragma unroll
      for (int mi = 0; mi < 4; mi++)
        #pragma unroll
        for (int ni = 0; ni < 4; ni++)
          acc[mi][ni] = __builtin_amdgcn_mfma_f32_16x16x32_bf16(af[mi], bfr[ni], acc[mi][ni], 0, 0, 0);
    }
  }
}

// ---------------- qkv GEMM: W[768][256] @ x -> q,k,v (f16) ----------------
__global__ __launch_bounds__(256) void k_mfma_qkv(
    const float* __restrict__ W, const unsigned short* __restrict__ xT,
    __half* __restrict__ q, __half* __restrict__ k, __half* __restrict__ v)
{
  __shared__ unsigned short As[8192], Bs[8192];
  const int bo = blockIdx.x;                  // 0..5
  const int s0 = blockIdx.y * 128;            // 256
  const int b  = blockIdx.z;
  f4_t acc[4][4];
  #pragma unroll
  for (int mi = 0; mi < 4; mi++)
    #pragma unroll
    for (int ni = 0; ni < 4; ni++) acc[mi][ni] = (f4_t)0.f;
  gemm_core(W, bo * 128, xT + ((size_t)b * THW_ + s0) * 256, As, Bs, acc);
  __half* outp = (bo < 2) ? q : (bo < 4) ? k : v;
  const int ro = (bo & 1) * 128;
  const int lane = threadIdx.x & 63, wv = threadIdx.x >> 6;
  const int wm = wv >> 1, wn = wv & 1;
  size_t obase = (size_t)(b * C_) * THW_;
  #pragma unroll
  for (int mi = 0; mi < 4; mi++)
    #pragma unroll
    for (int ni = 0; ni < 4; ni++)
      #pragma unroll
      for (int r = 0; r < 4; r++){
        int o = ro + wm * 64 + mi * 16 + (lane >> 4) * 4 + r;
        int s = s0 + wn * 64 + ni * 16 + (lane & 15);
        outp[obase + (size_t)o * THW_ + s] = __float2half(acc[mi][ni][r]);
      }
}

// ---------------- gate GEMM + sigmoid + combine (3 slices) -> y (f16) ----------------
__global__ __launch_bounds__(256) void k_mfma_gate(
    const float* __restrict__ W, const unsigned short* __restrict__ xT,
    const float* __restrict__ gb,
    const __half* ctx_t, const __half* __restrict__ ctx_h,
    const __half* __restrict__ ctx_w, __half* y)      // y aliases ctx_t elementwise
{
  __shared__ unsigned short As[8192], Bs[8192];
  const int bo = blockIdx.x;                  // 0..1
  const int s0 = blockIdx.y * 128;
  const int b  = blockIdx.z;
  const int lane = threadIdx.x & 63, wv = threadIdx.x >> 6;
  const int wm = wv >> 1, wn = wv & 1;
  const size_t obase = (size_t)(b * C_) * THW_;
  f4_t yacc[4][4];
  #pragma unroll
  for (int mi = 0; mi < 4; mi++)
    #pragma unroll
    for (int ni = 0; ni < 4; ni++) yacc[mi][ni] = (f4_t)0.f;
  for (int slice = 0; slice < 3; slice++){
    f4_t acc[4][4];
    #pragma unroll
    for (int mi = 0; mi < 4; mi++)
      #pragma unroll
      for (int ni = 0; ni < 4; ni++) acc[mi][ni] = (f4_t)0.f;
    gemm_core(W, slice * 256 + bo * 128, xT + ((size_t)b * THW_ + s0) * 256, As, Bs, acc);
    const __half* ctx = (slice == 0) ? ctx_t : (slice == 1) ? ctx_h : ctx_w;
    #pragma unroll
    for (int mi = 0; mi < 4; mi++)
      #pragma unroll
      for (int ni = 0; ni < 4; ni++)
        #pragma unroll
        for (int r = 0; r < 4; r++){
          int o = bo * 128 + wm * 64 + mi * 16 + (lane >> 4) * 4 + r;
          int s = s0 + wn * 64 + ni * 16 + (lane & 15);
          float lg = acc[mi][ni][r] + gb[slice * 256 + o];
          float g = 1.f / (1.f + __expf(-lg));
          yacc[mi][ni][r] += g * __half2float(ctx[obase + (size_t)o * THW_ + s]);
        }
  }
  #pragma unroll
  for (int mi = 0; mi < 4; mi++)
    #pragma unroll
    for (int ni = 0; ni < 4; ni++)
      #pragma unroll
      for (int r = 0; r < 4; r++){
        int o = bo * 128 + wm * 64 + mi * 16 + (lane >> 4) * 4 + r;
        int s = s0 + wn * 64 + ni * 16 + (lane & 15);
        y[obase + (size_t)o * THW_ + s] = __float2half(yacc[mi][ni][r]);
      }
}

// ---------------- proj GEMM -> d_out (f32) ----------------
__global__ __launch_bounds__(256) void k_mfma_proj(
    const float* __restrict__ W, const unsigned short* __restrict__ yT,
    float* __restrict__ out)
{
  __shared__ unsigned short As[8192], Bs[8192];
  const int bo = blockIdx.x;                  // 0..1
  const int s0 = blockIdx.y * 128;
  const int b  = blockIdx.z;
  f4_t acc[4][4];
  #pragma unroll
  for (int mi = 0; mi < 4; mi++)
    #pragma unroll
    for (int ni = 0; ni < 4; ni++) acc[mi][ni] = (f4_t)0.f;
  gemm_core(W, bo * 128, yT + ((size_t)b * THW_ + s0) * 256, As, Bs, acc);
  const int lane = threadIdx.x & 63, wv = threadIdx.x >> 6;
  const int wm = wv >> 1, wn = wv & 1;
  size_t obase = (size_t)(b * C_) * THW_;
  #pragma unroll
  for (int mi = 0; mi < 4; mi++)
    #pragma unroll
    for (int ni = 0; ni < 4; ni++)
      #pragma unroll
      for (int r = 0; r < 4; r++){
        int o = bo * 128 + wm * 64 + mi * 16 + (lane >> 4) * 4 + r;
        int s = s0 + wn * 64 + ni * 16 + (lane & 15);
        out[obase + (size_t)o * THW_ + s] = acc[mi][ni][r];
      }
}

// ---------------- mean over (H,W): qg[b,c,t] (q is f16) ----------------
__global__ __launch_bounds__(256) void k_mean_hw(const __half* __restrict__ q, float* __restrict__ qg){
  int bct = blockIdx.x;
  const __half2* p = (const __half2*)(q + (size_t)bct * HW_);
  __half2 v0 = p[threadIdx.x * 2], v1 = p[threadIdx.x * 2 + 1];
  float sum = __low2float(v0) + __high2float(v0) + __low2float(v1) + __high2float(v1);
  #pragma unroll
  for (int off = 32; off; off >>= 1) sum += __shfl_down(sum, off);
  __shared__ float red[4];
  int lane = threadIdx.x & 63, w = threadIdx.x >> 6;
  if (lane == 0) red[w] = sum;
  __syncthreads();
  if (threadIdx.x == 0) qg[bct] = (red[0] + red[1] + red[2] + red[3]) * (1.f / 1024.f);
}

// ---------------- mix pre: h = gelu(pre_w @ qg + pre_b) ----------------
__global__ __launch_bounds__(256) void k_mix_pre(const float* __restrict__ preW, const float* __restrict__ preB,
    const float* __restrict__ qg, float* __restrict__ hbuf){
  int b = blockIdx.x >> 5, t = blockIdx.x & 31;
  int o = threadIdx.x;
  __shared__ float qgl[256];
  qgl[o] = qg[((size_t)(b * C_ + o)) * T_ + t];
  __syncthreads();
  float a = preB[o];
  for (int c = 0; c < C_; c++) a = fmaf(preW[o * C_ + c], qgl[c], a);
  float g = 0.5f * a * (1.f + erff(a * 0.70710678118f));
  hbuf[((size_t)(b * C_ + o)) * T_ + t] = g;
}

// ---------------- mix logits + softmax over m ----------------
__global__ __launch_bounds__(256) void k_mix_alpha(const float* __restrict__ cw, const float* __restrict__ cb,
    const float* __restrict__ hbuf, float* __restrict__ alpha){
  int b = blockIdx.x >> 5, t = blockIdx.x & 31;
  int c = threadIdx.x;
  float hv[3];
  #pragma unroll
  for (int j = 0; j < 3; j++){
    int tt = t - 2 + j;
    hv[j] = (tt >= 0) ? hbuf[((size_t)(b * C_ + c)) * T_ + tt] : 0.f;
  }
  float p[3];
  #pragma unroll
  for (int m = 0; m < 3; m++){
    const float* w = cw + ((size_t)m * C_ + c) * 3;
    p[m] = w[0] * hv[0] + w[1] * hv[1] + w[2] * hv[2];
  }
  #pragma unroll
  for (int m = 0; m < 3; m++){
    #pragma unroll
    for (int off = 32; off; off >>= 1) p[m] += __shfl_down(p[m], off);
  }
  __shared__ float red[3][4];
  int lane = threadIdx.x & 63, w = threadIdx.x >> 6;
  if (lane == 0){ red[0][w] = p[0]; red[1][w] = p[1]; red[2][w] = p[2]; }
  __syncthreads();
  if (threadIdx.x == 0){
    float lg[3];
    #pragma unroll
    for (int m = 0; m < 3; m++) lg[m] = red[m][0] + red[m][1] + red[m][2] + red[m][3] + cb[m];
    float mx = fmaxf(lg[0], fmaxf(lg[1], lg[2]));
    float e0 = __expf(lg[0] - mx), e1 = __expf(lg[1] - mx), e2 = __expf(lg[2] - mx);
    float r = 1.f / (e0 + e1 + e2);
    alpha[((size_t)(b * 3 + 0)) * T_ + t] = e0 * r;
    alpha[((size_t)(b * 3 + 1)) * T_ + t] = e1 * r;
    alpha[((size_t)(b * 3 + 2)) * T_ + t] = e2 * r;
  }
}

// ---------------- alpha-mixed causal depthwise conv 3x3x3 (f16 in/out) ----------------
__global__ __launch_bounds__(256) void k_conv1(
    const __half* __restrict__ in_g, const float* __restrict__ bank,
    const float* __restrict__ alpha, __half* __restrict__ out)
{
  int bi = blockIdx.x;
  int c = bi & 255, t = (bi >> 8) & 31, b = bi >> 13;
  __shared__ float sIn[3 * 34 * 34];
  __shared__ float wmix[27];
  int tid = threadIdx.x;
  if (tid < 27){
    float sum = 0.f;
    #pragma unroll
    for (int m = 0; m < 3; m++)
      sum += alpha[((size_t)(b * 3 + m)) * T_ + t] * bank[((size_t)m * C_ + c) * 27 + tid];
    wmix[tid] = sum;
  }
  size_t cbase = ((size_t)(b * C_ + c)) * T_;
  for (int idx = tid; idx < 3 * 34 * 34; idx += 256){
    int tp = idx / 1156, rem = idx % 1156;
    int yy = rem / 34, xx = rem % 34;
    int tin = t - 2 + tp, y = yy - 1, x = xx - 1;
    bool ok = (tin >= 0) && (y >= 0) && (y < 32) && (x >= 0) && (x < 32);
    size_t g = ok ? ((cbase + tin) * HW_ + (size_t)y * 32 + x) : 0;
    sIn[idx] = ok ? __half2float(in_g[g]) : 0.f;
  }
  __syncthreads();
  int y = tid >> 3, x0 = (tid & 7) * 4;
  float a[4] = {0.f, 0.f, 0.f, 0.f};
  #pragma unroll
  for (int dt = 0; dt < 3; dt++){
    #pragma unroll
    for (int dy = 0; dy < 3; dy++){
      int rb = dt * 1156 + (y + dy) * 34 + x0;
      #pragma unroll
      for (int dx = 0; dx < 3; dx++){
        float wv = wmix[dt * 9 + dy * 3 + dx];
        #pragma unroll
        for (int p2 = 0; p2 < 4; p2++) a[p2] = fmaf(wv, sIn[rb + dx + p2], a[p2]);
      }
    }
  }
  size_t ob = (cbase + t) * HW_ + (size_t)y * 32 + x0;
  __half2 h01 = __halves2half2(__float2half(a[0]), __float2half(a[1]));
  __half2 h23 = __halves2half2(__float2half(a[2]), __float2half(a[3]));
  *reinterpret_cast<__half2*>(out + ob)     = h01;
  *reinterpret_cast<__half2*>(out + ob + 2) = h23;
}

// ---------------- axial attention, one 32x32 sequence per wave, all-f16 I/O ----------------
// Sibling-aware decode: the 8 ggrp blocks sharing cache lines get id%8-equal (same XCD)
// and adjacent per-XCD slots: ggrp=(id>>3)&7, rest=((id>>6)<<3)|(id&7).
template<int AXIS>
__global__ __launch_bounds__(256) void k_attn(
    const __half* __restrict__ qg_, const __half* __restrict__ kg_,
    const __half* vg_, __half* ctx,            // may alias (AXIS=2 in-place)
    const float* __restrict__ cosT, const float* __restrict__ sinT)
{
  const int SS = (AXIS == 0) ? HW_ : (AXIS == 1) ? 32 : 1;
  const int GS = (AXIS == 2) ? 32 : 1;
  const int OS = (AXIS == 0) ? 32 : HW_;
  int id = blockIdx.x;
  int ggrp = (id >> 3) & 7;
  int rest = ((id >> 6) << 3) | (id & 7);
  int outer = rest & 31;
  int head = (rest >> 5) & 7;
  int b = rest >> 8;
  const size_t base = ((size_t)(b * C_ + head * 32)) * THW_ + (size_t)outer * OS + (size_t)(ggrp * 4) * GS;

  __shared__ float q_l[4 * 32 * 33], k_l[4 * 32 * 33], v_l[4 * 32 * 33];
  const int tid = threadIdx.x;

  // staged load, ushort4 (4 halfs) per access
  for (int idx2 = tid; idx2 < 1024; idx2 += 256){
    size_t go; int r0, rstep, f;
    if (AXIS == 2){
      int ii = (idx2 & 7) * 4, g = (idx2 >> 3) & 3;
      f = idx2 >> 5;
      go = base + (size_t)f * THW_ + (size_t)g * GS + ii;     // 4 consecutive i
      r0 = g * 32 + ii; rstep = 1;
    } else {
      int i = idx2 & 31;
      f = idx2 >> 5;
      go = base + (size_t)f * THW_ + (size_t)i * SS;          // 4 consecutive g
      r0 = i; rstep = 32;
    }
    ushort4 qv = *(const ushort4*)((const unsigned short*)qg_ + go);
    ushort4 kv = *(const ushort4*)((const unsigned short*)kg_ + go);
    ushort4 vv = *(const ushort4*)((const unsigned short*)vg_ + go);
    const unsigned short qa[4] = {qv.x, qv.y, qv.z, qv.w};
    const unsigned short ka[4] = {kv.x, kv.y, kv.z, kv.w};
    const unsigned short va[4] = {vv.x, vv.y, vv.z, vv.w};
    #pragma unroll
    for (int p2 = 0; p2 < 4; p2++){
      int lo = (r0 + p2 * rstep) * 33 + f;
      q_l[lo] = h2f_u(qa[p2]);
      k_l[lo] = h2f_u(ka[p2]);
      v_l[lo] = h2f_u(va[p2]);
    }
  }
  __syncthreads();

  const int lane = tid & 63;
  const int g = tid >> 6;
  const int i = lane & 31;
  const int fh = lane >> 5;
  const int qb = (g * 32 + i) * 33 + fh * 16;
  float qr[16];
  #pragma unroll
  for (int u = 0; u < 16; u++) qr[u] = q_l[qb + u];
  #pragma unroll
  for (int u = 0; u < 16; u++){
    float part = __shfl_xor(qr[u], 32);
    float cv = cosT[i * 16 + u], sv = sinT[i * 16 + u];
    qr[u] = fh ? fmaf(qr[u], cv, part * sv) : fmaf(qr[u], cv, -part * sv);
  }
  for (int idx = tid; idx < 2048; idx += 256){
    int u = idx & 15, j = (idx >> 4) & 31, gg = idx >> 9;
    int kb = (gg * 32 + j) * 33;
    float k1 = k_l[kb + u], k2 = k_l[kb + 16 + u];
    float cv = cosT[j * 16 + u], sv = sinT[j * 16 + u];
    k_l[kb + u]      = k1 * cv - k2 * sv;
    k_l[kb + 16 + u] = fmaf(k2, cv, k1 * sv);
  }
  __syncthreads();

  float s_arr[32];
  const int kvb0 = g * 32 * 33 + fh * 16;
  #pragma unroll
  for (int j = 0; j < 32; j++){
    float p = 0.f;
    const float* kr = &k_l[kvb0 + j * 33];
    #pragma unroll
    for (int u = 0; u < 16; u++) p = fmaf(qr[u], kr[u], p);
    p += __shfl_xor(p, 32);
    p *= 0.17677669529663687f;
    if (AXIS == 0 && j > i) p = -1e30f;
    s_arr[j] = p;
  }
  float mx = s_arr[0];
  #pragma unroll
  for (int j = 1; j < 32; j++) mx = fmaxf(mx, s_arr[j]);
  float sum = 0.f;
  #pragma unroll
  for (int j = 0; j < 32; j++){ s_arr[j] = __expf(s_arr[j] - mx); sum += s_arr[j]; }
  float rinv = 1.f / sum;
  float acc[16];
  #pragma unroll
  for (int u = 0; u < 16; u++) acc[u] = 0.f;
  #pragma unroll
  for (int j = 0; j < 32; j++){
    float pv = s_arr[j] * rinv;
    const float* vr = &v_l[kvb0 + j * 33];
    #pragma unroll
    for (int u = 0; u < 16; u++) acc[u] = fmaf(pv, vr[u], acc[u]);
  }
  #pragma unroll
  for (int u = 0; u < 16; u++) q_l[qb + u] = acc[u];
  __syncthreads();

  // staged store, ushort4
  for (int idx2 = tid; idx2 < 1024; idx2 += 256){
    size_t go; int r0, rstep, f;
    if (AXIS == 2){
      int ii = (idx2 & 7) * 4, g2 = (idx2 >> 3) & 3;
      f = idx2 >> 5;
      go = base + (size_t)f * THW_ + (size_t)g2 * GS + ii;
      r0 = g2 * 32 + ii; rstep = 1;
    } else {
      int i2 = idx2 & 31;
      f = idx2 >> 5;
      go = base + (size_t)f * THW_ + (size_t)i2 * SS;
      r0 = i2; rstep = 32;
    }
    ushort4 ov;
    ov.x = f2h_u(q_l[(r0 + 0 * rstep) * 33 + f]);
    ov.y = f2h_u(q_l[(r0 + 1 * rstep) * 33 + f]);
    ov.z = f2h_u(q_l[(r0 + 2 * rstep) * 33 + f]);
    ov.w = f2h_u(q_l[(r0 + 3 * rstep) * 33 + f]);
    *(ushort4*)((unsigned short*)ctx + go) = ov;
  }
}

extern "C" void kernel_launch(void* const* d_in, const int* in_sizes, int n_in,
                              void* d_out, int out_size, void* d_ws, size_t ws_size,
                              hipStream_t stream)
{
  (void)in_sizes; (void)n_in; (void)out_size; (void)ws_size;
  const float* x       = (const float*)d_in[0];
  const float* w_qkv   = (const float*)d_in[1];
  const float* wk_bank = (const float*)d_in[2];
  const float* wv_bank = (const float*)d_in[3];
  const float* pre_w   = (const float*)d_in[4];
  const float* pre_b   = (const float*)d_in[5];
  const float* cw      = (const float*)d_in[6];
  const float* cb      = (const float*)d_in[7];
  const float* gate_w  = (const float*)d_in[8];
  const float* gate_b  = (const float*)d_in[9];
  const float* proj_w  = (const float*)d_in[10];

  const size_t SZ = (size_t)B_ * C_ * THW_;           // 16,777,216 elems
  __half* hb = (__half*)d_ws;                         // 32MB slots
  unsigned short* xT  = (unsigned short*)(hb + 0 * SZ);  // bf16, alive to gate
  __half* qH   = hb + 1 * SZ;                         // q
  __half* kH   = hb + 2 * SZ;                         // k -> ctx_t -> y
  __half* vH   = hb + 3 * SZ;                         // v -> ctx_h
  __half* koH  = hb + 4 * SZ;                         // k_out -> yT(bf16)
  __half* voH  = hb + 5 * SZ;                         // v_out -> ctx_w (in-place)
  __half* ctxtH = kH;
  __half* ctxhH = vH;
  __half* yH    = kH;                                 // gate writes y over ctx_t (same-thread elem)
  unsigned short* yT = (unsigned short*)koH;          // over dead k_out
  float* sm    = (float*)(hb + 6 * SZ);               // smalls (~136 KB)
  float* qg    = sm;                                  // 16384
  float* hbuf  = qg + 16384;                          // 16384
  float* alpha = hbuf + 16384;                        // 192
  float* cosT  = alpha + 192;                         // 512
  float* sinT  = cosT + 512;                          // 512

  k_rope_table<<<1, 512, 0, stream>>>(cosT, sinT);
  k_transpose_cvt<float><<<dim3(512, 4, 2), 256, 0, stream>>>(x, xT);

  k_mfma_qkv<<<dim3(6, 256, 2), 256, 0, stream>>>(w_qkv, xT, qH, kH, vH);

  k_mean_hw<<<16384, 256, 0, stream>>>(qH, qg);
  k_mix_pre<<<64, 256, 0, stream>>>(pre_w, pre_b, qg, hbuf);
  k_mix_alpha<<<64, 256, 0, stream>>>(cw, cb, hbuf, alpha);

  k_conv1<<<16384, 256, 0, stream>>>(kH, wk_bank, alpha, koH);   // k_out
  k_conv1<<<16384, 256, 0, stream>>>(vH, wv_bank, alpha, voH);   // v_out

  k_attn<0><<<4096, 256, 0, stream>>>(qH, koH, voH, ctxtH, cosT, sinT); // ctx_t (k dead)
  k_attn<1><<<4096, 256, 0, stream>>>(qH, koH, voH, ctxhH, cosT, sinT); // ctx_h (v dead)
  k_attn<2><<<4096, 256, 0, stream>>>(qH, koH, voH, voH,   cosT, sinT); // ctx_w in-place

  k_mfma_gate<<<dim3(2, 256, 2), 256, 0, stream>>>(gate_w, xT, gate_b,
                                                   ctxtH, ctxhH, voH, yH);
  k_transpose_cvt<__half><<<dim3(512, 4, 2), 256, 0, stream>>>(yH, yT);  // k_out dead
  k_mfma_proj<<<dim3(2, 256, 2), 256, 0, stream>>>(proj_w, yT, (float*)d_out);
}

// Round 5
// 685.525 us; speedup vs baseline: 3.1617x; 1.1362x over previous
//
#include <hip/hip_runtime.h>
#include <hip/hip_fp16.h>
#include <math.h>

#define B_   2
#define C_   256
#define T_   32
#define HW_  1024
#define THW_ 32768

using u32 = unsigned int;
typedef __attribute__((ext_vector_type(8))) short bf8_t;   // 8 bf16 in 4 VGPRs
typedef __attribute__((ext_vector_type(8))) unsigned short us8_t;
typedef __attribute__((ext_vector_type(4))) float f4_t;

static __device__ __forceinline__ unsigned short f2bf(float x){
  u32 u = __float_as_uint(x);
  u32 r = (u + 0x7FFF + ((u >> 16) & 1)) >> 16;   // RNE
  return (unsigned short)r;
}
static __device__ __forceinline__ float h2f_u(unsigned short u){
  union { __half h; unsigned short us; } cv; cv.us = u; return __half2float(cv.h);
}
static __device__ __forceinline__ unsigned short f2h_u(float f){
  union { __half h; unsigned short us; } cv; cv.h = __float2half(f); return cv.us;
}
static __device__ __forceinline__ float ldf(const float* p){ return *p; }
static __device__ __forceinline__ float ldf(const __half* p){ return __half2float(*p); }

// ---------------- rope table ----------------
__global__ void k_rope_table(float* __restrict__ cosT, float* __restrict__ sinT){
  int tid = threadIdx.x;            // 512 threads, tid = i*16+u
  int i = tid >> 4, u = tid & 15;
  float invf = powf(10000.f, -(2.f * (float)u) / 32.f);
  float s, c;
  sincosf((float)i * invf, &s, &c);
  cosT[tid] = c;
  sinT[tid] = s;
}

// ---------------- weight cvt: stack w_qkv(768), gate_w(768), proj_w(256) as bf16 [1792][256] --
__global__ void k_wcvt(const float* __restrict__ w_qkv, const float* __restrict__ gate_w,
                       const float* __restrict__ proj_w, unsigned short* __restrict__ out){
  int row = blockIdx.x, c = threadIdx.x;
  const float* src = (row < 768) ? w_qkv + (size_t)row * 256
                   : (row < 1536) ? gate_w + (size_t)(row - 768) * 256
                                  : proj_w + (size_t)(row - 1536) * 256;
  out[(size_t)row * 256 + c] = f2bf(src[c]);
}

// ---------------- transpose+cvt: [b][256][THW] (f32/f16) -> bf16 [b][THW][256] ----------------
template<typename InT>
__global__ __launch_bounds__(256) void k_transpose_cvt(
    const InT* __restrict__ in, unsigned short* __restrict__ outT)
{
  __shared__ float tile[64][65];
  int s0 = blockIdx.x * 64;     // 512
  int c0 = blockIdx.y * 64;     // 4
  int b  = blockIdx.z;
  int tid = threadIdx.x;
  for (int idx = tid; idx < 4096; idx += 256){
    int c = idx >> 6, s = idx & 63;
    tile[c][s] = ldf(&in[((size_t)(b * C_ + c0 + c)) * THW_ + s0 + s]);
  }
  __syncthreads();
  for (int idx = tid; idx < 4096; idx += 256){
    int s = idx >> 6, c = idx & 63;
    outT[((size_t)b * THW_ + s0 + s) * 256 + c0 + c] = f2bf(tile[c][s]);
  }
}

// ---------------- MFMA GEMM core (bf16 A bank): 128xBN tile, K=256 ----------------
// BN = 128 or 64. acc[4][BN/32]. LDS XOR-swizzled (T2). A: bf16 [rows][256] at row o0.
template<int BN>
static __device__ __forceinline__ void gemm_core_b(
    const unsigned short* __restrict__ A, int o0,
    const unsigned short* __restrict__ BT,   // pre-offset: + (b*THW + s0)*256
    unsigned short* As, unsigned short* Bs, f4_t acc[4][BN / 32])
{
  const int tid = threadIdx.x;
  const int lane = tid & 63, wv = tid >> 6;
  const int wm = wv >> 1, wn = wv & 1;
  const int m = lane & 15, kg = lane >> 4;
  const int arow = tid >> 1, aseg = (tid & 1) * 64;     // A: 128 rows, 2 thr/row, 64B each
  const int brow = (BN == 128) ? (tid >> 1) : (tid >> 2);
  const int bseg = (BN == 128) ? (tid & 1) * 64 : (tid & 3) * 32;
  for (int ks = 0; ks < 4; ks++){
    __syncthreads();                                    // protect prior reads
    {
      const unsigned short* ga = A + (size_t)(o0 + arow) * 256 + ks * 64 + aseg / 2;
      #pragma unroll
      for (int q2 = 0; q2 < 4; q2++){
        us8_t v = *(const us8_t*)(ga + q2 * 8);
        *(us8_t*)((char*)As + arow * 128 + ((aseg + q2 * 16) ^ ((arow & 7) << 4))) = v;
      }
      const unsigned short* gb = BT + (size_t)brow * 256 + ks * 64 + bseg / 2;
      #pragma unroll
      for (int q2 = 0; q2 < (BN == 128 ? 4 : 2); q2++){
        us8_t v = *(const us8_t*)(gb + q2 * 8);
        *(us8_t*)((char*)Bs + brow * 128 + ((bseg + q2 * 16) ^ ((brow & 7) << 4))) = v;
      }
    }
    __syncthreads();
    #pragma unroll
    for (int kk = 0; kk < 2; kk++){
      bf8_t af[4], bfr[BN / 32];
      #pragma unroll
      for (int mi = 0; mi < 4; mi++){
        int row = wm * 64 + mi * 16 + m;
        af[mi] = *(const bf8_t*)((const char*)As + row * 128 + ((kk * 64 + kg * 16) ^ ((row & 7) << 4)));
      }
      #pragma unroll
      for (int ni = 0; ni < BN / 32; ni++){
        int row = wn * (BN / 2) + ni * 16 + m;
        bfr[ni] = *(const bf8_t*)((const char*)Bs + row * 128 + ((kk * 64 + kg * 16) ^ ((row & 7) << 4)));
      }
      #pragma unroll
      for (int mi = 0; mi < 4; mi++)
        #pragma unroll
        for (int ni = 0; ni < BN / 32; ni++)
          acc[mi][ni] = __builtin_amdgcn_mfma_f32_16x16x32_bf16(af[mi], bfr[ni], acc[mi][ni], 0, 0, 0);
    }
  }
}

// ---------------- qkv GEMM: Wq(bf16)[768][256] @ x -> q,k,v (f16) ----------------
__global__ __launch_bounds__(256) void k_mfma_qkv(
    const unsigned short* __restrict__ Wb, const unsigned short* __restrict__ xT,
    __half* __restrict__ q, __half* __restrict__ k, __half* __restrict__ v)
{
  __shared__ unsigned short As[8192], Bs[8192];
  const int bo = blockIdx.x;                  // 0..5
  const int s0 = blockIdx.y * 128;            // 256
  const int b  = blockIdx.z;
  f4_t acc[4][4];
  #pragma unroll
  for (int mi = 0; mi < 4; mi++)
    #pragma unroll
    for (int ni = 0; ni < 4; ni++) acc[mi][ni] = (f4_t)0.f;
  gemm_core_b<128>(Wb, bo * 128, xT + ((size_t)b * THW_ + s0) * 256, As, Bs, acc);
  __half* outp = (bo < 2) ? q : (bo < 4) ? k : v;
  const int ro = (bo & 1) * 128;
  const int lane = threadIdx.x & 63, wv = threadIdx.x >> 6;
  const int wm = wv >> 1, wn = wv & 1;
  size_t obase = (size_t)(b * C_) * THW_;
  #pragma unroll
  for (int mi = 0; mi < 4; mi++)
    #pragma unroll
    for (int ni = 0; ni < 4; ni++)
      #pragma unroll
      for (int r = 0; r < 4; r++){
        int o = ro + wm * 64 + mi * 16 + (lane >> 4) * 4 + r;
        int s = s0 + wn * 64 + ni * 16 + (lane & 15);
        outp[obase + (size_t)o * THW_ + s] = __float2half(acc[mi][ni][r]);
      }
}

// ---------------- gate GEMM + sigmoid + combine (3 slices) -> y (f16), 128x64 tile --------
__global__ __launch_bounds__(256) void k_mfma_gate(
    const unsigned short* __restrict__ Wb,   // bf16 gate bank [768][256]
    const unsigned short* __restrict__ xT,
    const float* __restrict__ gb,
    const __half* ctx_t, const __half* __restrict__ ctx_h,
    const __half* __restrict__ ctx_w, __half* y)      // y aliases ctx_t elementwise
{
  __shared__ unsigned short As[8192], Bs[4096];
  const int bo = blockIdx.x;                  // 0..1
  const int s0 = blockIdx.y * 64;             // 512
  const int b  = blockIdx.z;
  const int lane = threadIdx.x & 63, wv = threadIdx.x >> 6;
  const int wm = wv >> 1, wn = wv & 1;
  const size_t obase = (size_t)(b * C_) * THW_;
  f4_t yacc[4][2];
  #pragma unroll
  for (int mi = 0; mi < 4; mi++)
    #pragma unroll
    for (int ni = 0; ni < 2; ni++) yacc[mi][ni] = (f4_t)0.f;
  for (int slice = 0; slice < 3; slice++){
    f4_t acc[4][2];
    #pragma unroll
    for (int mi = 0; mi < 4; mi++)
      #pragma unroll
      for (int ni = 0; ni < 2; ni++) acc[mi][ni] = (f4_t)0.f;
    gemm_core_b<64>(Wb, slice * 256 + bo * 128, xT + ((size_t)b * THW_ + s0) * 256, As, Bs, acc);
    const __half* ctx = (slice == 0) ? ctx_t : (slice == 1) ? ctx_h : ctx_w;
    #pragma unroll
    for (int mi = 0; mi < 4; mi++)
      #pragma unroll
      for (int ni = 0; ni < 2; ni++)
        #pragma unroll
        for (int r = 0; r < 4; r++){
          int o = bo * 128 + wm * 64 + mi * 16 + (lane >> 4) * 4 + r;
          int s = s0 + wn * 32 + ni * 16 + (lane & 15);
          float lg = acc[mi][ni][r] + gb[slice * 256 + o];
          float g = 1.f / (1.f + __expf(-lg));
          yacc[mi][ni][r] += g * __half2float(ctx[obase + (size_t)o * THW_ + s]);
        }
  }
  #pragma unroll
  for (int mi = 0; mi < 4; mi++)
    #pragma unroll
    for (int ni = 0; ni < 2; ni++)
      #pragma unroll
      for (int r = 0; r < 4; r++){
        int o = bo * 128 + wm * 64 + mi * 16 + (lane >> 4) * 4 + r;
        int s = s0 + wn * 32 + ni * 16 + (lane & 15);
        y[obase + (size_t)o * THW_ + s] = __float2half(yacc[mi][ni][r]);
      }
}

// ---------------- proj GEMM -> d_out (f32) ----------------
__global__ __launch_bounds__(256) void k_mfma_proj(
    const unsigned short* __restrict__ Wb, const unsigned short* __restrict__ yT,
    float* __restrict__ out)
{
  __shared__ unsigned short As[8192], Bs[8192];
  const int bo = blockIdx.x;                  // 0..1
  const int s0 = blockIdx.y * 128;
  const int b  = blockIdx.z;
  f4_t acc[4][4];
  #pragma unroll
  for (int mi = 0; mi < 4; mi++)
    #pragma unroll
    for (int ni = 0; ni < 4; ni++) acc[mi][ni] = (f4_t)0.f;
  gemm_core_b<128>(Wb, bo * 128, yT + ((size_t)b * THW_ + s0) * 256, As, Bs, acc);
  const int lane = threadIdx.x & 63, wv = threadIdx.x >> 6;
  const int wm = wv >> 1, wn = wv & 1;
  size_t obase = (size_t)(b * C_) * THW_;
  #pragma unroll
  for (int mi = 0; mi < 4; mi++)
    #pragma unroll
    for (int ni = 0; ni < 4; ni++)
      #pragma unroll
      for (int r = 0; r < 4; r++){
        int o = bo * 128 + wm * 64 + mi * 16 + (lane >> 4) * 4 + r;
        int s = s0 + wn * 64 + ni * 16 + (lane & 15);
        out[obase + (size_t)o * THW_ + s] = acc[mi][ni][r];
      }
}

// ---------------- mean over (H,W): qg[b,c,t] (q is f16) ----------------
__global__ __launch_bounds__(256) void k_mean_hw(const __half* __restrict__ q, float* __restrict__ qg){
  int bct = blockIdx.x;
  const __half2* p = (const __half2*)(q + (size_t)bct * HW_);
  __half2 v0 = p[threadIdx.x * 2], v1 = p[threadIdx.x * 2 + 1];
  float sum = __low2float(v0) + __high2float(v0) + __low2float(v1) + __high2float(v1);
  #pragma unroll
  for (int off = 32; off; off >>= 1) sum += __shfl_down(sum, off);
  __shared__ float red[4];
  int lane = threadIdx.x & 63, w = threadIdx.x >> 6;
  if (lane == 0) red[w] = sum;
  __syncthreads();
  if (threadIdx.x == 0) qg[bct] = (red[0] + red[1] + red[2] + red[3]) * (1.f / 1024.f);
}

// ---------------- mix pre: h = gelu(pre_w @ qg + pre_b) ----------------
__global__ __launch_bounds__(256) void k_mix_pre(const float* __restrict__ preW, const float* __restrict__ preB,
    const float* __restrict__ qg, float* __restrict__ hbuf){
  int b = blockIdx.x >> 5, t = blockIdx.x & 31;
  int o = threadIdx.x;
  __shared__ float qgl[256];
  qgl[o] = qg[((size_t)(b * C_ + o)) * T_ + t];
  __syncthreads();
  float a = preB[o];
  for (int c = 0; c < C_; c++) a = fmaf(preW[o * C_ + c], qgl[c], a);
  float g = 0.5f * a * (1.f + erff(a * 0.70710678118f));
  hbuf[((size_t)(b * C_ + o)) * T_ + t] = g;
}

// ---------------- mix logits + softmax over m ----------------
__global__ __launch_bounds__(256) void k_mix_alpha(const float* __restrict__ cw, const float* __restrict__ cb,
    const float* __restrict__ hbuf, float* __restrict__ alpha){
  int b = blockIdx.x >> 5, t = blockIdx.x & 31;
  int c = threadIdx.x;
  float hv[3];
  #pragma unroll
  for (int j = 0; j < 3; j++){
    int tt = t - 2 + j;
    hv[j] = (tt >= 0) ? hbuf[((size_t)(b * C_ + c)) * T_ + tt] : 0.f;
  }
  float p[3];
  #pragma unroll
  for (int m = 0; m < 3; m++){
    const float* w = cw + ((size_t)m * C_ + c) * 3;
    p[m] = w[0] * hv[0] + w[1] * hv[1] + w[2] * hv[2];
  }
  #pragma unroll
  for (int m = 0; m < 3; m++){
    #pragma unroll
    for (int off = 32; off; off >>= 1) p[m] += __shfl_down(p[m], off);
  }
  __shared__ float red[3][4];
  int lane = threadIdx.x & 63, w = threadIdx.x >> 6;
  if (lane == 0){ red[0][w] = p[0]; red[1][w] = p[1]; red[2][w] = p[2]; }
  __syncthreads();
  if (threadIdx.x == 0){
    float lg[3];
    #pragma unroll
    for (int m = 0; m < 3; m++) lg[m] = red[m][0] + red[m][1] + red[m][2] + red[m][3] + cb[m];
    float mx = fmaxf(lg[0], fmaxf(lg[1], lg[2]));
    float e0 = __expf(lg[0] - mx), e1 = __expf(lg[1] - mx), e2 = __expf(lg[2] - mx);
    float r = 1.f / (e0 + e1 + e2);
    alpha[((size_t)(b * 3 + 0)) * T_ + t] = e0 * r;
    alpha[((size_t)(b * 3 + 1)) * T_ + t] = e1 * r;
    alpha[((size_t)(b * 3 + 2)) * T_ + t] = e2 * r;
  }
}

// ---------------- alpha-mixed causal depthwise conv 3x3x3 (f16 in/out) ----------------
__global__ __launch_bounds__(256) void k_conv1(
    const __half* __restrict__ in_g, const float* __restrict__ bank,
    const float* __restrict__ alpha, __half* __restrict__ out)
{
  int bi = blockIdx.x;
  int c = bi & 255, t = (bi >> 8) & 31, b = bi >> 13;
  __shared__ float sIn[3 * 34 * 34];
  __shared__ float wmix[27];
  int tid = threadIdx.x;
  if (tid < 27){
    float sum = 0.f;
    #pragma unroll
    for (int m = 0; m < 3; m++)
      sum += alpha[((size_t)(b * 3 + m)) * T_ + t] * bank[((size_t)m * C_ + c) * 27 + tid];
    wmix[tid] = sum;
  }
  size_t cbase = ((size_t)(b * C_ + c)) * T_;
  for (int idx = tid; idx < 3 * 34 * 34; idx += 256){
    int tp = idx / 1156, rem = idx % 1156;
    int yy = rem / 34, xx = rem % 34;
    int tin = t - 2 + tp, y = yy - 1, x = xx - 1;
    bool ok = (tin >= 0) && (y >= 0) && (y < 32) && (x >= 0) && (x < 32);
    size_t g = ok ? ((cbase + tin) * HW_ + (size_t)y * 32 + x) : 0;
    sIn[idx] = ok ? __half2float(in_g[g]) : 0.f;
  }
  __syncthreads();
  int y = tid >> 3, x0 = (tid & 7) * 4;
  float a[4] = {0.f, 0.f, 0.f, 0.f};
  #pragma unroll
  for (int dt = 0; dt < 3; dt++){
    #pragma unroll
    for (int dy = 0; dy < 3; dy++){
      int rb = dt * 1156 + (y + dy) * 34 + x0;
      #pragma unroll
      for (int dx = 0; dx < 3; dx++){
        float wv = wmix[dt * 9 + dy * 3 + dx];
        #pragma unroll
        for (int p2 = 0; p2 < 4; p2++) a[p2] = fmaf(wv, sIn[rb + dx + p2], a[p2]);
      }
    }
  }
  size_t ob = (cbase + t) * HW_ + (size_t)y * 32 + x0;
  __half2 h01 = __halves2half2(__float2half(a[0]), __float2half(a[1]));
  __half2 h23 = __halves2half2(__float2half(a[2]), __float2half(a[3]));
  *reinterpret_cast<__half2*>(out + ob)     = h01;
  *reinterpret_cast<__half2*>(out + ob + 2) = h23;
}

// ---------------- axial attention, one 32x32 sequence per wave, all-f16 I/O ----------------
template<int AXIS>
__global__ __launch_bounds__(256) void k_attn(
    const __half* __restrict__ qg_, const __half* __restrict__ kg_,
    const __half* vg_, __half* ctx,            // may alias (AXIS=2 in-place)
    const float* __restrict__ cosT, const float* __restrict__ sinT)
{
  const int SS = (AXIS == 0) ? HW_ : (AXIS == 1) ? 32 : 1;
  const int GS = (AXIS == 2) ? 32 : 1;
  const int OS = (AXIS == 0) ? 32 : HW_;
  int id = blockIdx.x;
  int ggrp = (id >> 3) & 7;
  int rest = ((id >> 6) << 3) | (id & 7);
  int outer = rest & 31;
  int head = (rest >> 5) & 7;
  int b = rest >> 8;
  const size_t base = ((size_t)(b * C_ + head * 32)) * THW_ + (size_t)outer * OS + (size_t)(ggrp * 4) * GS;

  __shared__ float q_l[4 * 32 * 33], k_l[4 * 32 * 33], v_l[4 * 32 * 33];
  const int tid = threadIdx.x;

  for (int idx2 = tid; idx2 < 1024; idx2 += 256){
    size_t go; int r0, rstep, f;
    if (AXIS == 2){
      int ii = (idx2 & 7) * 4, g = (idx2 >> 3) & 3;
      f = idx2 >> 5;
      go = base + (size_t)f * THW_ + (size_t)g * GS + ii;
      r0 = g * 32 + ii; rstep = 1;
    } else {
      int i = idx2 & 31;
      f = idx2 >> 5;
      go = base + (size_t)f * THW_ + (size_t)i * SS;
      r0 = i; rstep = 32;
    }
    ushort4 qv = *(const ushort4*)((const unsigned short*)qg_ + go);
    ushort4 kv = *(const ushort4*)((const unsigned short*)kg_ + go);
    ushort4 vv = *(const ushort4*)((const unsigned short*)vg_ + go);
    const unsigned short qa[4] = {qv.x, qv.y, qv.z, qv.w};
    const unsigned short ka[4] = {kv.x, kv.y, kv.z, kv.w};
    const unsigned short va[4] = {vv.x, vv.y, vv.z, vv.w};
    #pragma unroll
    for (int p2 = 0; p2 < 4; p2++){
      int lo = (r0 + p2 * rstep) * 33 + f;
      q_l[lo] = h2f_u(qa[p2]);
      k_l[lo] = h2f_u(ka[p2]);
      v_l[lo] = h2f_u(va[p2]);
    }
  }
  __syncthreads();

  const int lane = tid & 63;
  const int g = tid >> 6;
  const int i = lane & 31;
  const int fh = lane >> 5;
  const int qb = (g * 32 + i) * 33 + fh * 16;
  float qr[16];
  #pragma unroll
  for (int u = 0; u < 16; u++) qr[u] = q_l[qb + u];
  #pragma unroll
  for (int u = 0; u < 16; u++){
    float part = __shfl_xor(qr[u], 32);
    float cv = cosT[i * 16 + u], sv = sinT[i * 16 + u];
    qr[u] = fh ? fmaf(qr[u], cv, part * sv) : fmaf(qr[u], cv, -part * sv);
  }
  for (int idx = tid; idx < 2048; idx += 256){
    int u = idx & 15, j = (idx >> 4) & 31, gg = idx >> 9;
    int kb = (gg * 32 + j) * 33;
    float k1 = k_l[kb + u], k2 = k_l[kb + 16 + u];
    float cv = cosT[j * 16 + u], sv = sinT[j * 16 + u];
    k_l[kb + u]      = k1 * cv - k2 * sv;
    k_l[kb + 16 + u] = fmaf(k2, cv, k1 * sv);
  }
  __syncthreads();

  float s_arr[32];
  const int kvb0 = g * 32 * 33 + fh * 16;
  #pragma unroll
  for (int j = 0; j < 32; j++){
    float p = 0.f;
    const float* kr = &k_l[kvb0 + j * 33];
    #pragma unroll
    for (int u = 0; u < 16; u++) p = fmaf(qr[u], kr[u], p);
    p += __shfl_xor(p, 32);
    p *= 0.17677669529663687f;
    if (AXIS == 0 && j > i) p = -1e30f;
    s_arr[j] = p;
  }
  float mx = s_arr[0];
  #pragma unroll
  for (int j = 1; j < 32; j++) mx = fmaxf(mx, s_arr[j]);
  float sum = 0.f;
  #pragma unroll
  for (int j = 0; j < 32; j++){ s_arr[j] = __expf(s_arr[j] - mx); sum += s_arr[j]; }
  float rinv = 1.f / sum;
  float acc[16];
  #pragma unroll
  for (int u = 0; u < 16; u++) acc[u] = 0.f;
  #pragma unroll
  for (int j = 0; j < 32; j++){
    float pv = s_arr[j] * rinv;
    const float* vr = &v_l[kvb0 + j * 33];
    #pragma unroll
    for (int u = 0; u < 16; u++) acc[u] = fmaf(pv, vr[u], acc[u]);
  }
  #pragma unroll
  for (int u = 0; u < 16; u++) q_l[qb + u] = acc[u];
  __syncthreads();

  for (int idx2 = tid; idx2 < 1024; idx2 += 256){
    size_t go; int r0, rstep, f;
    if (AXIS == 2){
      int ii = (idx2 & 7) * 4, g2 = (idx2 >> 3) & 3;
      f = idx2 >> 5;
      go = base + (size_t)f * THW_ + (size_t)g2 * GS + ii;
      r0 = g2 * 32 + ii; rstep = 1;
    } else {
      int i2 = idx2 & 31;
      f = idx2 >> 5;
      go = base + (size_t)f * THW_ + (size_t)i2 * SS;
      r0 = i2; rstep = 32;
    }
    ushort4 ov;
    ov.x = f2h_u(q_l[(r0 + 0 * rstep) * 33 + f]);
    ov.y = f2h_u(q_l[(r0 + 1 * rstep) * 33 + f]);
    ov.z = f2h_u(q_l[(r0 + 2 * rstep) * 33 + f]);
    ov.w = f2h_u(q_l[(r0 + 3 * rstep) * 33 + f]);
    *(ushort4*)((unsigned short*)ctx + go) = ov;
  }
}

extern "C" void kernel_launch(void* const* d_in, const int* in_sizes, int n_in,
                              void* d_out, int out_size, void* d_ws, size_t ws_size,
                              hipStream_t stream)
{
  (void)in_sizes; (void)n_in; (void)out_size; (void)ws_size;
  const float* x       = (const float*)d_in[0];
  const float* w_qkv   = (const float*)d_in[1];
  const float* wk_bank = (const float*)d_in[2];
  const float* wv_bank = (const float*)d_in[3];
  const float* pre_w   = (const float*)d_in[4];
  const float* pre_b   = (const float*)d_in[5];
  const float* cw      = (const float*)d_in[6];
  const float* cb      = (const float*)d_in[7];
  const float* gate_w  = (const float*)d_in[8];
  const float* gate_b  = (const float*)d_in[9];
  const float* proj_w  = (const float*)d_in[10];

  const size_t SZ = (size_t)B_ * C_ * THW_;           // 16,777,216 elems
  __half* hb = (__half*)d_ws;                         // 32MB slots
  unsigned short* xT  = (unsigned short*)(hb + 0 * SZ);  // bf16, alive to gate
  __half* qH   = hb + 1 * SZ;                         // q
  __half* kH   = hb + 2 * SZ;                         // k -> ctx_t -> y
  __half* vH   = hb + 3 * SZ;                         // v -> ctx_h
  __half* koH  = hb + 4 * SZ;                         // k_out -> yT(bf16)
  __half* voH  = hb + 5 * SZ;                         // v_out -> ctx_w (in-place)
  __half* ctxtH = kH;
  __half* ctxhH = vH;
  __half* yH    = kH;                                 // gate writes y over ctx_t (same-thread elem)
  unsigned short* yT = (unsigned short*)koH;          // over dead k_out
  float* sm    = (float*)(hb + 6 * SZ);               // smalls
  float* qg    = sm;                                  // 16384
  float* hbuf  = qg + 16384;                          // 16384
  float* alpha = hbuf + 16384;                        // 192
  float* cosT  = alpha + 192;                         // 512
  float* sinT  = cosT + 512;                          // 512
  unsigned short* wB = (unsigned short*)(sinT + 512); // 1792*256 bf16 (896 KB)
  unsigned short* wBq = wB;                           // [768][256]
  unsigned short* wBg = wB + 768 * 256;               // [768][256]
  unsigned short* wBp = wB + 1536 * 256;              // [256][256]

  k_rope_table<<<1, 512, 0, stream>>>(cosT, sinT);
  k_wcvt<<<1792, 256, 0, stream>>>(w_qkv, gate_w, proj_w, wB);
  k_transpose_cvt<float><<<dim3(512, 4, 2), 256, 0, stream>>>(x, xT);

  k_mfma_qkv<<<dim3(6, 256, 2), 256, 0, stream>>>(wBq, xT, qH, kH, vH);

  k_mean_hw<<<16384, 256, 0, stream>>>(qH, qg);
  k_mix_pre<<<64, 256, 0, stream>>>(pre_w, pre_b, qg, hbuf);
  k_mix_alpha<<<64, 256, 0, stream>>>(cw, cb, hbuf, alpha);

  k_conv1<<<16384, 256, 0, stream>>>(kH, wk_bank, alpha, koH);   // k_out
  k_conv1<<<16384, 256, 0, stream>>>(vH, wv_bank, alpha, voH);   // v_out

  k_attn<0><<<4096, 256, 0, stream>>>(qH, koH, voH, ctxtH, cosT, sinT); // ctx_t (k dead)
  k_attn<1><<<4096, 256, 0, stream>>>(qH, koH, voH, ctxhH, cosT, sinT); // ctx_h (v dead)
  k_attn<2><<<4096, 256, 0, stream>>>(qH, koH, voH, voH,   cosT, sinT); // ctx_w in-place

  k_mfma_gate<<<dim3(2, 512, 2), 256, 0, stream>>>(wBg, xT, gate_b,
                                                   ctxtH, ctxhH, voH, yH);
  k_transpose_cvt<__half><<<dim3(512, 4, 2), 256, 0, stream>>>(yH, yT);  // k_out dead
  k_mfma_proj<<<dim3(2, 256, 2), 256, 0, stream>>>(wBp, yT, (float*)d_out);
}

// Round 6
// 572.286 us; speedup vs baseline: 3.7873x; 1.1979x over previous
//
#include <hip/hip_runtime.h>
#include <hip/hip_fp16.h>
#include <math.h>

#define B_   2
#define C_   256
#define T_   32
#define HW_  1024
#define THW_ 32768

using u32 = unsigned int;
typedef __attribute__((ext_vector_type(8))) short bf8_t;   // 8 bf16 in 4 VGPRs
typedef __attribute__((ext_vector_type(8))) unsigned short us8_t;
typedef __attribute__((ext_vector_type(8))) _Float16 h8_t; // 8 f16 in 4 VGPRs
typedef __attribute__((ext_vector_type(4))) float f4_t;

static __device__ __forceinline__ unsigned short f2bf(float x){
  u32 u = __float_as_uint(x);
  u32 r = (u + 0x7FFF + ((u >> 16) & 1)) >> 16;   // RNE
  return (unsigned short)r;
}
static __device__ __forceinline__ float h2f_u(unsigned short u){
  union { __half h; unsigned short us; } cv; cv.us = u; return __half2float(cv.h);
}
static __device__ __forceinline__ unsigned short f2h_u(float f){
  union { __half h; unsigned short us; } cv; cv.h = __float2half(f); return cv.us;
}
static __device__ __forceinline__ float ldf(const float* p){ return *p; }
static __device__ __forceinline__ float ldf(const __half* p){ return __half2float(*p); }

// ---------------- rope table ----------------
__global__ void k_rope_table(float* __restrict__ cosT, float* __restrict__ sinT){
  int tid = threadIdx.x;            // 512 threads, tid = i*16+u
  int i = tid >> 4, u = tid & 15;
  float invf = powf(10000.f, -(2.f * (float)u) / 32.f);
  float s, c;
  sincosf((float)i * invf, &s, &c);
  cosT[tid] = c;
  sinT[tid] = s;
}

// ---------------- weight cvt: stack w_qkv(768), gate_w(768), proj_w(256) as bf16 [1792][256] --
__global__ void k_wcvt(const float* __restrict__ w_qkv, const float* __restrict__ gate_w,
                       const float* __restrict__ proj_w, unsigned short* __restrict__ out){
  int row = blockIdx.x, c = threadIdx.x;
  const float* src = (row < 768) ? w_qkv + (size_t)row * 256
                   : (row < 1536) ? gate_w + (size_t)(row - 768) * 256
                                  : proj_w + (size_t)(row - 1536) * 256;
  out[(size_t)row * 256 + c] = f2bf(src[c]);
}

// ---------------- transpose+cvt: [b][256][THW] (f32/f16) -> bf16 [b][THW][256] ----------------
template<typename InT>
__global__ __launch_bounds__(256) void k_transpose_cvt(
    const InT* __restrict__ in, unsigned short* __restrict__ outT)
{
  __shared__ float tile[64][65];
  int s0 = blockIdx.x * 64;     // 512
  int c0 = blockIdx.y * 64;     // 4
  int b  = blockIdx.z;
  int tid = threadIdx.x;
  for (int idx = tid; idx < 4096; idx += 256){
    int c = idx >> 6, s = idx & 63;
    tile[c][s] = ldf(&in[((size_t)(b * C_ + c0 + c)) * THW_ + s0 + s]);
  }
  __syncthreads();
  for (int idx = tid; idx < 4096; idx += 256){
    int s = idx >> 6, c = idx & 63;
    outT[((size_t)b * THW_ + s0 + s) * 256 + c0 + c] = f2bf(tile[c][s]);
  }
}

// ---------------- MFMA GEMM core (bf16 A bank): 128xBN tile, K=256 ----------------
template<int BN>
static __device__ __forceinline__ void gemm_core_b(
    const unsigned short* __restrict__ A, int o0,
    const unsigned short* __restrict__ BT,   // pre-offset: + (b*THW + s0)*256
    unsigned short* As, unsigned short* Bs, f4_t acc[4][BN / 32])
{
  const int tid = threadIdx.x;
  const int lane = tid & 63, wv = tid >> 6;
  const int wm = wv >> 1, wn = wv & 1;
  const int m = lane & 15, kg = lane >> 4;
  const int arow = tid >> 1, aseg = (tid & 1) * 64;     // A: 128 rows, 2 thr/row, 64B each
  const int brow = (BN == 128) ? (tid >> 1) : (tid >> 2);
  const int bseg = (BN == 128) ? (tid & 1) * 64 : (tid & 3) * 32;
  for (int ks = 0; ks < 4; ks++){
    __syncthreads();                                    // protect prior reads
    {
      const unsigned short* ga = A + (size_t)(o0 + arow) * 256 + ks * 64 + aseg / 2;
      #pragma unroll
      for (int q2 = 0; q2 < 4; q2++){
        us8_t v = *(const us8_t*)(ga + q2 * 8);
        *(us8_t*)((char*)As + arow * 128 + ((aseg + q2 * 16) ^ ((arow & 7) << 4))) = v;
      }
      const unsigned short* gb = BT + (size_t)brow * 256 + ks * 64 + bseg / 2;
      #pragma unroll
      for (int q2 = 0; q2 < (BN == 128 ? 4 : 2); q2++){
        us8_t v = *(const us8_t*)(gb + q2 * 8);
        *(us8_t*)((char*)Bs + brow * 128 + ((bseg + q2 * 16) ^ ((brow & 7) << 4))) = v;
      }
    }
    __syncthreads();
    #pragma unroll
    for (int kk = 0; kk < 2; kk++){
      bf8_t af[4], bfr[BN / 32];
      #pragma unroll
      for (int mi = 0; mi < 4; mi++){
        int row = wm * 64 + mi * 16 + m;
        af[mi] = *(const bf8_t*)((const char*)As + row * 128 + ((kk * 64 + kg * 16) ^ ((row & 7) << 4)));
      }
      #pragma unroll
      for (int ni = 0; ni < BN / 32; ni++){
        int row = wn * (BN / 2) + ni * 16 + m;
        bfr[ni] = *(const bf8_t*)((const char*)Bs + row * 128 + ((kk * 64 + kg * 16) ^ ((row & 7) << 4)));
      }
      #pragma unroll
      for (int mi = 0; mi < 4; mi++)
        #pragma unroll
        for (int ni = 0; ni < BN / 32; ni++)
          acc[mi][ni] = __builtin_amdgcn_mfma_f32_16x16x32_bf16(af[mi], bfr[ni], acc[mi][ni], 0, 0, 0);
    }
  }
}

// ---------------- qkv GEMM: Wq(bf16)[768][256] @ x -> q,k,v (f16) ----------------
__global__ __launch_bounds__(256) void k_mfma_qkv(
    const unsigned short* __restrict__ Wb, const unsigned short* __restrict__ xT,
    __half* __restrict__ q, __half* __restrict__ k, __half* __restrict__ v)
{
  __shared__ unsigned short As[8192], Bs[8192];
  const int bo = blockIdx.x;                  // 0..5
  const int s0 = blockIdx.y * 128;            // 256
  const int b  = blockIdx.z;
  f4_t acc[4][4];
  #pragma unroll
  for (int mi = 0; mi < 4; mi++)
    #pragma unroll
    for (int ni = 0; ni < 4; ni++) acc[mi][ni] = (f4_t)0.f;
  gemm_core_b<128>(Wb, bo * 128, xT + ((size_t)b * THW_ + s0) * 256, As, Bs, acc);
  __half* outp = (bo < 2) ? q : (bo < 4) ? k : v;
  const int ro = (bo & 1) * 128;
  const int lane = threadIdx.x & 63, wv = threadIdx.x >> 6;
  const int wm = wv >> 1, wn = wv & 1;
  size_t obase = (size_t)(b * C_) * THW_;
  #pragma unroll
  for (int mi = 0; mi < 4; mi++)
    #pragma unroll
    for (int ni = 0; ni < 4; ni++)
      #pragma unroll
      for (int r = 0; r < 4; r++){
        int o = ro + wm * 64 + mi * 16 + (lane >> 4) * 4 + r;
        int s = s0 + wn * 64 + ni * 16 + (lane & 15);
        outp[obase + (size_t)o * THW_ + s] = __float2half(acc[mi][ni][r]);
      }
}

// ---------------- gate GEMM + sigmoid + combine (3 slices) -> y (f16), 128x64 tile --------
__global__ __launch_bounds__(256) void k_mfma_gate(
    const unsigned short* __restrict__ Wb,   // bf16 gate bank [768][256]
    const unsigned short* __restrict__ xT,
    const float* __restrict__ gb,
    const __half* ctx_t, const __half* __restrict__ ctx_h,
    const __half* __restrict__ ctx_w, __half* y)      // y aliases ctx_t elementwise
{
  __shared__ unsigned short As[8192], Bs[4096];
  const int bo = blockIdx.x;                  // 0..1
  const int s0 = blockIdx.y * 64;             // 512
  const int b  = blockIdx.z;
  const int lane = threadIdx.x & 63, wv = threadIdx.x >> 6;
  const int wm = wv >> 1, wn = wv & 1;
  const size_t obase = (size_t)(b * C_) * THW_;
  f4_t yacc[4][2];
  #pragma unroll
  for (int mi = 0; mi < 4; mi++)
    #pragma unroll
    for (int ni = 0; ni < 2; ni++) yacc[mi][ni] = (f4_t)0.f;
  for (int slice = 0; slice < 3; slice++){
    f4_t acc[4][2];
    #pragma unroll
    for (int mi = 0; mi < 4; mi++)
      #pragma unroll
      for (int ni = 0; ni < 2; ni++) acc[mi][ni] = (f4_t)0.f;
    gemm_core_b<64>(Wb, slice * 256 + bo * 128, xT + ((size_t)b * THW_ + s0) * 256, As, Bs, acc);
    const __half* ctx = (slice == 0) ? ctx_t : (slice == 1) ? ctx_h : ctx_w;
    #pragma unroll
    for (int mi = 0; mi < 4; mi++)
      #pragma unroll
      for (int ni = 0; ni < 2; ni++)
        #pragma unroll
        for (int r = 0; r < 4; r++){
          int o = bo * 128 + wm * 64 + mi * 16 + (lane >> 4) * 4 + r;
          int s = s0 + wn * 32 + ni * 16 + (lane & 15);
          float lg = acc[mi][ni][r] + gb[slice * 256 + o];
          float g = 1.f / (1.f + __expf(-lg));
          yacc[mi][ni][r] += g * __half2float(ctx[obase + (size_t)o * THW_ + s]);
        }
  }
  #pragma unroll
  for (int mi = 0; mi < 4; mi++)
    #pragma unroll
    for (int ni = 0; ni < 2; ni++)
      #pragma unroll
      for (int r = 0; r < 4; r++){
        int o = bo * 128 + wm * 64 + mi * 16 + (lane >> 4) * 4 + r;
        int s = s0 + wn * 32 + ni * 16 + (lane & 15);
        y[obase + (size_t)o * THW_ + s] = __float2half(yacc[mi][ni][r]);
      }
}

// ---------------- proj GEMM -> d_out (f32) ----------------
__global__ __launch_bounds__(256) void k_mfma_proj(
    const unsigned short* __restrict__ Wb, const unsigned short* __restrict__ yT,
    float* __restrict__ out)
{
  __shared__ unsigned short As[8192], Bs[8192];
  const int bo = blockIdx.x;                  // 0..1
  const int s0 = blockIdx.y * 128;
  const int b  = blockIdx.z;
  f4_t acc[4][4];
  #pragma unroll
  for (int mi = 0; mi < 4; mi++)
    #pragma unroll
    for (int ni = 0; ni < 4; ni++) acc[mi][ni] = (f4_t)0.f;
  gemm_core_b<128>(Wb, bo * 128, yT + ((size_t)b * THW_ + s0) * 256, As, Bs, acc);
  const int lane = threadIdx.x & 63, wv = threadIdx.x >> 6;
  const int wm = wv >> 1, wn = wv & 1;
  size_t obase = (size_t)(b * C_) * THW_;
  #pragma unroll
  for (int mi = 0; mi < 4; mi++)
    #pragma unroll
    for (int ni = 0; ni < 4; ni++)
      #pragma unroll
      for (int r = 0; r < 4; r++){
        int o = bo * 128 + wm * 64 + mi * 16 + (lane >> 4) * 4 + r;
        int s = s0 + wn * 64 + ni * 16 + (lane & 15);
        out[obase + (size_t)o * THW_ + s] = acc[mi][ni][r];
      }
}

// ---------------- mean over (H,W): qg[b,c,t] (q is f16) ----------------
__global__ __launch_bounds__(256) void k_mean_hw(const __half* __restrict__ q, float* __restrict__ qg){
  int bct = blockIdx.x;
  const __half2* p = (const __half2*)(q + (size_t)bct * HW_);
  __half2 v0 = p[threadIdx.x * 2], v1 = p[threadIdx.x * 2 + 1];
  float sum = __low2float(v0) + __high2float(v0) + __low2float(v1) + __high2float(v1);
  #pragma unroll
  for (int off = 32; off; off >>= 1) sum += __shfl_down(sum, off);
  __shared__ float red[4];
  int lane = threadIdx.x & 63, w = threadIdx.x >> 6;
  if (lane == 0) red[w] = sum;
  __syncthreads();
  if (threadIdx.x == 0) qg[bct] = (red[0] + red[1] + red[2] + red[3]) * (1.f / 1024.f);
}

// ---------------- mix pre: h = gelu(pre_w @ qg + pre_b) ----------------
__global__ __launch_bounds__(256) void k_mix_pre(const float* __restrict__ preW, const float* __restrict__ preB,
    const float* __restrict__ qg, float* __restrict__ hbuf){
  int b = blockIdx.x >> 5, t = blockIdx.x & 31;
  int o = threadIdx.x;
  __shared__ float qgl[256];
  qgl[o] = qg[((size_t)(b * C_ + o)) * T_ + t];
  __syncthreads();
  float a = preB[o];
  for (int c = 0; c < C_; c++) a = fmaf(preW[o * C_ + c], qgl[c], a);
  float g = 0.5f * a * (1.f + erff(a * 0.70710678118f));
  hbuf[((size_t)(b * C_ + o)) * T_ + t] = g;
}

// ---------------- mix logits + softmax over m ----------------
__global__ __launch_bounds__(256) void k_mix_alpha(const float* __restrict__ cw, const float* __restrict__ cb,
    const float* __restrict__ hbuf, float* __restrict__ alpha){
  int b = blockIdx.x >> 5, t = blockIdx.x & 31;
  int c = threadIdx.x;
  float hv[3];
  #pragma unroll
  for (int j = 0; j < 3; j++){
    int tt = t - 2 + j;
    hv[j] = (tt >= 0) ? hbuf[((size_t)(b * C_ + c)) * T_ + tt] : 0.f;
  }
  float p[3];
  #pragma unroll
  for (int m = 0; m < 3; m++){
    const float* w = cw + ((size_t)m * C_ + c) * 3;
    p[m] = w[0] * hv[0] + w[1] * hv[1] + w[2] * hv[2];
  }
  #pragma unroll
  for (int m = 0; m < 3; m++){
    #pragma unroll
    for (int off = 32; off; off >>= 1) p[m] += __shfl_down(p[m], off);
  }
  __shared__ float red[3][4];
  int lane = threadIdx.x & 63, w = threadIdx.x >> 6;
  if (lane == 0){ red[0][w] = p[0]; red[1][w] = p[1]; red[2][w] = p[2]; }
  __syncthreads();
  if (threadIdx.x == 0){
    float lg[3];
    #pragma unroll
    for (int m = 0; m < 3; m++) lg[m] = red[m][0] + red[m][1] + red[m][2] + red[m][3] + cb[m];
    float mx = fmaxf(lg[0], fmaxf(lg[1], lg[2]));
    float e0 = __expf(lg[0] - mx), e1 = __expf(lg[1] - mx), e2 = __expf(lg[2] - mx);
    float r = 1.f / (e0 + e1 + e2);
    alpha[((size_t)(b * 3 + 0)) * T_ + t] = e0 * r;
    alpha[((size_t)(b * 3 + 1)) * T_ + t] = e1 * r;
    alpha[((size_t)(b * 3 + 2)) * T_ + t] = e2 * r;
  }
}

// ---------------- alpha-mixed causal depthwise conv 3x3x3 (f16 in/out) ----------------
__global__ __launch_bounds__(256) void k_conv1(
    const __half* __restrict__ in_g, const float* __restrict__ bank,
    const float* __restrict__ alpha, __half* __restrict__ out)
{
  int bi = blockIdx.x;
  int c = bi & 255, t = (bi >> 8) & 31, b = bi >> 13;
  __shared__ float sIn[3 * 34 * 34];
  __shared__ float wmix[27];
  int tid = threadIdx.x;
  if (tid < 27){
    float sum = 0.f;
    #pragma unroll
    for (int m = 0; m < 3; m++)
      sum += alpha[((size_t)(b * 3 + m)) * T_ + t] * bank[((size_t)m * C_ + c) * 27 + tid];
    wmix[tid] = sum;
  }
  size_t cbase = ((size_t)(b * C_ + c)) * T_;
  for (int idx = tid; idx < 3 * 34 * 34; idx += 256){
    int tp = idx / 1156, rem = idx % 1156;
    int yy = rem / 34, xx = rem % 34;
    int tin = t - 2 + tp, y = yy - 1, x = xx - 1;
    bool ok = (tin >= 0) && (y >= 0) && (y < 32) && (x >= 0) && (x < 32);
    size_t g = ok ? ((cbase + tin) * HW_ + (size_t)y * 32 + x) : 0;
    sIn[idx] = ok ? __half2float(in_g[g]) : 0.f;
  }
  __syncthreads();
  int y = tid >> 3, x0 = (tid & 7) * 4;
  float a[4] = {0.f, 0.f, 0.f, 0.f};
  #pragma unroll
  for (int dt = 0; dt < 3; dt++){
    #pragma unroll
    for (int dy = 0; dy < 3; dy++){
      int rb = dt * 1156 + (y + dy) * 34 + x0;
      #pragma unroll
      for (int dx = 0; dx < 3; dx++){
        float wv = wmix[dt * 9 + dy * 3 + dx];
        #pragma unroll
        for (int p2 = 0; p2 < 4; p2++) a[p2] = fmaf(wv, sIn[rb + dx + p2], a[p2]);
      }
    }
  }
  size_t ob = (cbase + t) * HW_ + (size_t)y * 32 + x0;
  __half2 h01 = __halves2half2(__float2half(a[0]), __float2half(a[1]));
  __half2 h23 = __halves2half2(__float2half(a[2]), __float2half(a[3]));
  *reinterpret_cast<__half2*>(out + ob)     = h01;
  *reinterpret_cast<__half2*>(out + ob + 2) = h23;
}

// ---------------- axial attention via MFMA, one 32x32 sequence per wave ----------------
// LDS pool (ushort idx): qk(seq,w,row,col) = seq*2560 + w*1280 + row*40 + col  (w: 0=q,1=k)
//                        vp(seq,w,row,col) = 10240 + same                      (w: 0=vT,1=p)
// O (f32) reuses qk[seq] space: fbase[seq*1280 + i*33 + d].
template<int AXIS>
__global__ __launch_bounds__(256) void k_attn(
    const __half* __restrict__ qg_, const __half* __restrict__ kg_,
    const __half* vg_, __half* ctx,            // may alias (AXIS=2 in-place)
    const float* __restrict__ cosT, const float* __restrict__ sinT)
{
  const int SS = (AXIS == 0) ? HW_ : (AXIS == 1) ? 32 : 1;
  const int GS = (AXIS == 2) ? 32 : 1;
  const int OS = (AXIS == 0) ? 32 : HW_;
  int id = blockIdx.x;
  int ggrp = (id >> 3) & 7;
  int rest = ((id >> 6) << 3) | (id & 7);
  int outer = rest & 31;
  int head = (rest >> 5) & 7;
  int b = rest >> 8;
  const size_t base = ((size_t)(b * C_ + head * 32)) * THW_ + (size_t)outer * OS + (size_t)(ggrp * 4) * GS;

  __shared__ __align__(16) unsigned short smem[20480];   // 40 KB
  const int tid = threadIdx.x;

  // ---- staged load: q,k -> [i][d]; v -> transposed [d][j] ----
  for (int idx2 = tid; idx2 < 1024; idx2 += 256){
    if (AXIS == 2){
      int ii = (idx2 & 7) * 4, g = (idx2 >> 3) & 3, f = idx2 >> 5;
      size_t go = base + (size_t)f * THW_ + (size_t)g * GS + ii;
      ushort4 qv = *(const ushort4*)((const unsigned short*)qg_ + go);
      ushort4 kv = *(const ushort4*)((const unsigned short*)kg_ + go);
      ushort4 vv = *(const ushort4*)((const unsigned short*)vg_ + go);
      const unsigned short qa[4] = {qv.x, qv.y, qv.z, qv.w};
      const unsigned short ka[4] = {kv.x, kv.y, kv.z, kv.w};
      const unsigned short va[4] = {vv.x, vv.y, vv.z, vv.w};
      #pragma unroll
      for (int p2 = 0; p2 < 4; p2++){
        smem[g * 2560 + (ii + p2) * 40 + f] = qa[p2];
        smem[g * 2560 + 1280 + (ii + p2) * 40 + f] = ka[p2];
        smem[10240 + g * 2560 + f * 40 + ii + p2] = va[p2];
      }
    } else {
      int i = idx2 & 31, f = idx2 >> 5;
      size_t go = base + (size_t)f * THW_ + (size_t)i * SS;
      ushort4 qv = *(const ushort4*)((const unsigned short*)qg_ + go);
      ushort4 kv = *(const ushort4*)((const unsigned short*)kg_ + go);
      ushort4 vv = *(const ushort4*)((const unsigned short*)vg_ + go);
      const unsigned short qa[4] = {qv.x, qv.y, qv.z, qv.w};
      const unsigned short ka[4] = {kv.x, kv.y, kv.z, kv.w};
      const unsigned short va[4] = {vv.x, vv.y, vv.z, vv.w};
      #pragma unroll
      for (int p2 = 0; p2 < 4; p2++){
        smem[p2 * 2560 + i * 40 + f] = qa[p2];
        smem[p2 * 2560 + 1280 + i * 40 + f] = ka[p2];
        smem[10240 + p2 * 2560 + f * 40 + i] = va[p2];
      }
    }
  }
  __syncthreads();

  // ---- RoPE in-place on q,k (f32 math, f16 store) ----
  for (int idx = tid; idx < 4096; idx += 256){
    int u = idx & 15, j = (idx >> 4) & 31, g = (idx >> 9) & 3, wq = idx >> 11;
    unsigned short* row = &smem[g * 2560 + wq * 1280 + j * 40];
    float a = h2f_u(row[u]), bb = h2f_u(row[u + 16]);
    float cv = cosT[j * 16 + u], sv = sinT[j * 16 + u];
    row[u]      = f2h_u(a * cv - bb * sv);
    row[u + 16] = f2h_u(fmaf(bb, cv, a * sv));
  }
  __syncthreads();

  const int lane = tid & 63;
  const int seq = tid >> 6;
  const int m = lane & 15, kg = lane >> 4;
  const int sq = seq * 2560;

  // ---- QK^T: 4 MFMAs (A=Q rows, B=K rows, K-dim=32) ----
  h8_t aQ[2], bK[2];
  #pragma unroll
  for (int t2 = 0; t2 < 2; t2++){
    aQ[t2] = *(const h8_t*)&smem[sq + (t2 * 16 + m) * 40 + kg * 8];
    bK[t2] = *(const h8_t*)&smem[sq + 1280 + (t2 * 16 + m) * 40 + kg * 8];
  }
  f4_t s_[2][2];
  #pragma unroll
  for (int ti = 0; ti < 2; ti++)
    #pragma unroll
    for (int tj = 0; tj < 2; tj++){
      s_[ti][tj] = (f4_t)0.f;
      s_[ti][tj] = __builtin_amdgcn_mfma_f32_16x16x32_f16(aQ[ti], bK[tj], s_[ti][tj], 0, 0, 0);
    }

  // ---- scale + causal mask + softmax (rows i spread over kg,r; cols j over m) ----
  float rinv_[2][4];
  #pragma unroll
  for (int ti = 0; ti < 2; ti++)
    #pragma unroll
    for (int r = 0; r < 4; r++){
      int i = ti * 16 + kg * 4 + r;
      float a0 = s_[ti][0][r] * 0.17677669529663687f;
      float a1 = s_[ti][1][r] * 0.17677669529663687f;
      if (AXIS == 0){
        if (m > i)      a0 = -1e30f;
        if (16 + m > i) a1 = -1e30f;
      }
      float mxv = fmaxf(a0, a1);
      #pragma unroll
      for (int off = 8; off; off >>= 1) mxv = fmaxf(mxv, __shfl_xor(mxv, off));
      float e0 = __expf(a0 - mxv), e1 = __expf(a1 - mxv);
      float sv = e0 + e1;
      #pragma unroll
      for (int off = 8; off; off >>= 1) sv += __shfl_xor(sv, off);
      smem[10240 + sq + 1280 + i * 40 + m]      = f2h_u(e0);
      smem[10240 + sq + 1280 + i * 40 + m + 16] = f2h_u(e1);
      rinv_[ti][r] = 1.f / sv;
    }

  asm volatile("" ::: "memory");   // keep P-writes before P-frag reads

  // ---- PV: 4 MFMAs (A=P rows, B=V^T rows) ----
  h8_t aP[2], bV[2];
  #pragma unroll
  for (int t2 = 0; t2 < 2; t2++){
    aP[t2] = *(const h8_t*)&smem[10240 + sq + 1280 + (t2 * 16 + m) * 40 + kg * 8];
    bV[t2] = *(const h8_t*)&smem[10240 + sq + (t2 * 16 + m) * 40 + kg * 8];
  }
  f4_t o_[2][2];
  #pragma unroll
  for (int ti = 0; ti < 2; ti++)
    #pragma unroll
    for (int td = 0; td < 2; td++){
      o_[ti][td] = (f4_t)0.f;
      o_[ti][td] = __builtin_amdgcn_mfma_f32_16x16x32_f16(aP[ti], bV[td], o_[ti][td], 0, 0, 0);
    }

  // ---- O (normalized) -> f32 LDS over dead Q/K space ----
  float* fbase = (float*)smem;
  #pragma unroll
  for (int ti = 0; ti < 2; ti++)
    #pragma unroll
    for (int td = 0; td < 2; td++)
      #pragma unroll
      for (int r = 0; r < 4; r++){
        int i = ti * 16 + kg * 4 + r, d = td * 16 + m;
        fbase[seq * 1280 + i * 33 + d] = o_[ti][td][r] * rinv_[ti][r];
      }
  __syncthreads();

  // ---- staged store ----
  for (int idx2 = tid; idx2 < 1024; idx2 += 256){
    if (AXIS == 2){
      int ii = (idx2 & 7) * 4, g2 = (idx2 >> 3) & 3, f = idx2 >> 5;
      size_t go = base + (size_t)f * THW_ + (size_t)g2 * GS + ii;
      ushort4 ov;
      ov.x = f2h_u(fbase[g2 * 1280 + (ii + 0) * 33 + f]);
      ov.y = f2h_u(fbase[g2 * 1280 + (ii + 1) * 33 + f]);
      ov.z = f2h_u(fbase[g2 * 1280 + (ii + 2) * 33 + f]);
      ov.w = f2h_u(fbase[g2 * 1280 + (ii + 3) * 33 + f]);
      *(ushort4*)((unsigned short*)ctx + go) = ov;
    } else {
      int i2 = idx2 & 31, f = idx2 >> 5;
      size_t go = base + (size_t)f * THW_ + (size_t)i2 * SS;
      ushort4 ov;
      ov.x = f2h_u(fbase[0 * 1280 + i2 * 33 + f]);
      ov.y = f2h_u(fbase[1 * 1280 + i2 * 33 + f]);
      ov.z = f2h_u(fbase[2 * 1280 + i2 * 33 + f]);
      ov.w = f2h_u(fbase[3 * 1280 + i2 * 33 + f]);
      *(ushort4*)((unsigned short*)ctx + go) = ov;
    }
  }
}

extern "C" void kernel_launch(void* const* d_in, const int* in_sizes, int n_in,
                              void* d_out, int out_size, void* d_ws, size_t ws_size,
                              hipStream_t stream)
{
  (void)in_sizes; (void)n_in; (void)out_size; (void)ws_size;
  const float* x       = (const float*)d_in[0];
  const float* w_qkv   = (const float*)d_in[1];
  const float* wk_bank = (const float*)d_in[2];
  const float* wv_bank = (const float*)d_in[3];
  const float* pre_w   = (const float*)d_in[4];
  const float* pre_b   = (const float*)d_in[5];
  const float* cw      = (const float*)d_in[6];
  const float* cb      = (const float*)d_in[7];
  const float* gate_w  = (const float*)d_in[8];
  const float* gate_b  = (const float*)d_in[9];
  const float* proj_w  = (const float*)d_in[10];

  const size_t SZ = (size_t)B_ * C_ * THW_;           // 16,777,216 elems
  __half* hb = (__half*)d_ws;                         // 32MB slots
  unsigned short* xT  = (unsigned short*)(hb + 0 * SZ);  // bf16, alive to gate
  __half* qH   = hb + 1 * SZ;                         // q
  __half* kH   = hb + 2 * SZ;                         // k -> ctx_t -> y
  __half* vH   = hb + 3 * SZ;                         // v -> ctx_h
  __half* koH  = hb + 4 * SZ;                         // k_out -> yT(bf16)
  __half* voH  = hb + 5 * SZ;                         // v_out -> ctx_w (in-place)
  __half* ctxtH = kH;
  __half* ctxhH = vH;
  __half* yH    = kH;                                 // gate writes y over ctx_t (same-thread elem)
  unsigned short* yT = (unsigned short*)koH;          // over dead k_out
  float* sm    = (float*)(hb + 6 * SZ);               // smalls
  float* qg    = sm;                                  // 16384
  float* hbuf  = qg + 16384;                          // 16384
  float* alpha = hbuf + 16384;                        // 192
  float* cosT  = alpha + 192;                         // 512
  float* sinT  = cosT + 512;                          // 512
  unsigned short* wB = (unsigned short*)(sinT + 512); // 1792*256 bf16 (896 KB)
  unsigned short* wBq = wB;                           // [768][256]
  unsigned short* wBg = wB + 768 * 256;               // [768][256]
  unsigned short* wBp = wB + 1536 * 256;              // [256][256]

  k_rope_table<<<1, 512, 0, stream>>>(cosT, sinT);
  k_wcvt<<<1792, 256, 0, stream>>>(w_qkv, gate_w, proj_w, wB);
  k_transpose_cvt<float><<<dim3(512, 4, 2), 256, 0, stream>>>(x, xT);

  k_mfma_qkv<<<dim3(6, 256, 2), 256, 0, stream>>>(wBq, xT, qH, kH, vH);

  k_mean_hw<<<16384, 256, 0, stream>>>(qH, qg);
  k_mix_pre<<<64, 256, 0, stream>>>(pre_w, pre_b, qg, hbuf);
  k_mix_alpha<<<64, 256, 0, stream>>>(cw, cb, hbuf, alpha);

  k_conv1<<<16384, 256, 0, stream>>>(kH, wk_bank, alpha, koH);   // k_out
  k_conv1<<<16384, 256, 0, stream>>>(vH, wv_bank, alpha, voH);   // v_out

  k_attn<0><<<4096, 256, 0, stream>>>(qH, koH, voH, ctxtH, cosT, sinT); // ctx_t (k dead)
  k_attn<1><<<4096, 256, 0, stream>>>(qH, koH, voH, ctxhH, cosT, sinT); // ctx_h (v dead)
  k_attn<2><<<4096, 256, 0, stream>>>(qH, koH, voH, voH,   cosT, sinT); // ctx_w in-place

  k_mfma_gate<<<dim3(2, 512, 2), 256, 0, stream>>>(wBg, xT, gate_b,
                                                   ctxtH, ctxhH, voH, yH);
  k_transpose_cvt<__half><<<dim3(512, 4, 2), 256, 0, stream>>>(yH, yT);  // k_out dead
  k_mfma_proj<<<dim3(2, 256, 2), 256, 0, stream>>>(wBp, yT, (float*)d_out);
}

// Round 8
// 531.036 us; speedup vs baseline: 4.0815x; 1.0777x over previous
//
#include <hip/hip_runtime.h>
#include <hip/hip_fp16.h>
#include <math.h>

#define B_   2
#define C_   256
#define T_   32
#define HW_  1024
#define THW_ 32768

using u32 = unsigned int;
typedef __attribute__((ext_vector_type(8))) short bf8_t;   // 8 bf16 in 4 VGPRs
typedef __attribute__((ext_vector_type(8))) unsigned short us8_t;
typedef __attribute__((ext_vector_type(8))) _Float16 h8_t; // 8 f16 in 4 VGPRs
typedef __attribute__((ext_vector_type(2))) __fp16 fp16v2; // builtin cvt_pkrtz return type
typedef __attribute__((ext_vector_type(4))) float f4_t;

static __device__ __forceinline__ unsigned short f2bf(float x){
  u32 u = __float_as_uint(x);
  u32 r = (u + 0x7FFF + ((u >> 16) & 1)) >> 16;   // RNE
  return (unsigned short)r;
}
static __device__ __forceinline__ float h2f_u(unsigned short u){
  union { __half h; unsigned short us; } cv; cv.us = u; return __half2float(cv.h);
}
static __device__ __forceinline__ unsigned short f2h_u(float f){
  union { __half h; unsigned short us; } cv; cv.h = __float2half(f); return cv.us;
}
static __device__ __forceinline__ u32 pkrtz(float a, float b){
  union { fp16v2 h; u32 w; } cv; cv.h = __builtin_amdgcn_cvt_pkrtz(a, b); return cv.w;
}
static __device__ __forceinline__ float ldf(const float* p){ return *p; }
static __device__ __forceinline__ float ldf(const __half* p){ return __half2float(*p); }

// ---------------- rope table ----------------
__global__ void k_rope_table(float* __restrict__ cosT, float* __restrict__ sinT){
  int tid = threadIdx.x;            // 512 threads, tid = i*16+u
  int i = tid >> 4, u = tid & 15;
  float invf = powf(10000.f, -(2.f * (float)u) / 32.f);
  float s, c;
  sincosf((float)i * invf, &s, &c);
  cosT[tid] = c;
  sinT[tid] = s;
}

// ---------------- weight cvt: stack w_qkv(768), gate_w(768), proj_w(256) as bf16 [1792][256] --
__global__ void k_wcvt(const float* __restrict__ w_qkv, const float* __restrict__ gate_w,
                       const float* __restrict__ proj_w, unsigned short* __restrict__ out){
  int row = blockIdx.x, c = threadIdx.x;
  const float* src = (row < 768) ? w_qkv + (size_t)row * 256
                   : (row < 1536) ? gate_w + (size_t)(row - 768) * 256
                                  : proj_w + (size_t)(row - 1536) * 256;
  out[(size_t)row * 256 + c] = f2bf(src[c]);
}

// ---------------- transpose+cvt: [b][256][THW] (f32/f16) -> bf16 [b][THW][256] ----------------
template<typename InT>
__global__ __launch_bounds__(256) void k_transpose_cvt(
    const InT* __restrict__ in, unsigned short* __restrict__ outT)
{
  __shared__ float tile[64][65];
  int s0 = blockIdx.x * 64;     // 512
  int c0 = blockIdx.y * 64;     // 4
  int b  = blockIdx.z;
  int tid = threadIdx.x;
  for (int idx = tid; idx < 4096; idx += 256){
    int c = idx >> 6, s = idx & 63;
    tile[c][s] = ldf(&in[((size_t)(b * C_ + c0 + c)) * THW_ + s0 + s]);
  }
  __syncthreads();
  for (int idx = tid; idx < 4096; idx += 256){
    int s = idx >> 6, c = idx & 63;
    outT[((size_t)b * THW_ + s0 + s) * 256 + c0 + c] = f2bf(tile[c][s]);
  }
}

// ---------------- MFMA GEMM core (bf16 A bank): 128xBN tile, K=256 ----------------
template<int BN>
static __device__ __forceinline__ void gemm_core_b(
    const unsigned short* __restrict__ A, int o0,
    const unsigned short* __restrict__ BT,   // pre-offset: + (b*THW + s0)*256
    unsigned short* As, unsigned short* Bs, f4_t acc[4][BN / 32])
{
  const int tid = threadIdx.x;
  const int lane = tid & 63, wv = tid >> 6;
  const int wm = wv >> 1, wn = wv & 1;
  const int m = lane & 15, kg = lane >> 4;
  const int arow = tid >> 1, aseg = (tid & 1) * 64;     // A: 128 rows, 2 thr/row, 64B each
  const int brow = (BN == 128) ? (tid >> 1) : (tid >> 2);
  const int bseg = (BN == 128) ? (tid & 1) * 64 : (tid & 3) * 32;
  for (int ks = 0; ks < 4; ks++){
    __syncthreads();                                    // protect prior reads
    {
      const unsigned short* ga = A + (size_t)(o0 + arow) * 256 + ks * 64 + aseg / 2;
      #pragma unroll
      for (int q2 = 0; q2 < 4; q2++){
        us8_t v = *(const us8_t*)(ga + q2 * 8);
        *(us8_t*)((char*)As + arow * 128 + ((aseg + q2 * 16) ^ ((arow & 7) << 4))) = v;
      }
      const unsigned short* gb = BT + (size_t)brow * 256 + ks * 64 + bseg / 2;
      #pragma unroll
      for (int q2 = 0; q2 < (BN == 128 ? 4 : 2); q2++){
        us8_t v = *(const us8_t*)(gb + q2 * 8);
        *(us8_t*)((char*)Bs + brow * 128 + ((bseg + q2 * 16) ^ ((brow & 7) << 4))) = v;
      }
    }
    __syncthreads();
    #pragma unroll
    for (int kk = 0; kk < 2; kk++){
      bf8_t af[4], bfr[BN / 32];
      #pragma unroll
      for (int mi = 0; mi < 4; mi++){
        int row = wm * 64 + mi * 16 + m;
        af[mi] = *(const bf8_t*)((const char*)As + row * 128 + ((kk * 64 + kg * 16) ^ ((row & 7) << 4)));
      }
      #pragma unroll
      for (int ni = 0; ni < BN / 32; ni++){
        int row = wn * (BN / 2) + ni * 16 + m;
        bfr[ni] = *(const bf8_t*)((const char*)Bs + row * 128 + ((kk * 64 + kg * 16) ^ ((row & 7) << 4)));
      }
      #pragma unroll
      for (int mi = 0; mi < 4; mi++)
        #pragma unroll
        for (int ni = 0; ni < BN / 32; ni++)
          acc[mi][ni] = __builtin_amdgcn_mfma_f32_16x16x32_bf16(af[mi], bfr[ni], acc[mi][ni], 0, 0, 0);
    }
  }
}

// ---------------- qkv GEMM: Wq(bf16)[768][256] @ x -> q,k,v (f16) ----------------
__global__ __launch_bounds__(256) void k_mfma_qkv(
    const unsigned short* __restrict__ Wb, const unsigned short* __restrict__ xT,
    __half* __restrict__ q, __half* __restrict__ k, __half* __restrict__ v)
{
  __shared__ unsigned short As[8192], Bs[8192];
  const int bo = blockIdx.x;                  // 0..5
  const int s0 = blockIdx.y * 128;            // 256
  const int b  = blockIdx.z;
  f4_t acc[4][4];
  #pragma unroll
  for (int mi = 0; mi < 4; mi++)
    #pragma unroll
    for (int ni = 0; ni < 4; ni++) acc[mi][ni] = (f4_t)0.f;
  gemm_core_b<128>(Wb, bo * 128, xT + ((size_t)b * THW_ + s0) * 256, As, Bs, acc);
  __half* outp = (bo < 2) ? q : (bo < 4) ? k : v;
  const int ro = (bo & 1) * 128;
  const int lane = threadIdx.x & 63, wv = threadIdx.x >> 6;
  const int wm = wv >> 1, wn = wv & 1;
  size_t obase = (size_t)(b * C_) * THW_;
  #pragma unroll
  for (int mi = 0; mi < 4; mi++)
    #pragma unroll
    for (int ni = 0; ni < 4; ni++)
      #pragma unroll
      for (int r = 0; r < 4; r++){
        int o = ro + wm * 64 + mi * 16 + (lane >> 4) * 4 + r;
        int s = s0 + wn * 64 + ni * 16 + (lane & 15);
        outp[obase + (size_t)o * THW_ + s] = __float2half(acc[mi][ni][r]);
      }
}

// ---------------- gate GEMM + sigmoid + combine (3 slices) -> y (f16), 128x64 tile --------
__global__ __launch_bounds__(256) void k_mfma_gate(
    const unsigned short* __restrict__ Wb,   // bf16 gate bank [768][256]
    const unsigned short* __restrict__ xT,
    const float* __restrict__ gb,
    const __half* ctx_t, const __half* __restrict__ ctx_h,
    const __half* __restrict__ ctx_w, __half* y)      // y aliases ctx_t elementwise
{
  __shared__ unsigned short As[8192], Bs[4096];
  const int bo = blockIdx.x;                  // 0..1
  const int s0 = blockIdx.y * 64;             // 512
  const int b  = blockIdx.z;
  const int lane = threadIdx.x & 63, wv = threadIdx.x >> 6;
  const int wm = wv >> 1, wn = wv & 1;
  const size_t obase = (size_t)(b * C_) * THW_;
  f4_t yacc[4][2];
  #pragma unroll
  for (int mi = 0; mi < 4; mi++)
    #pragma unroll
    for (int ni = 0; ni < 2; ni++) yacc[mi][ni] = (f4_t)0.f;
  for (int slice = 0; slice < 3; slice++){
    f4_t acc[4][2];
    #pragma unroll
    for (int mi = 0; mi < 4; mi++)
      #pragma unroll
      for (int ni = 0; ni < 2; ni++) acc[mi][ni] = (f4_t)0.f;
    gemm_core_b<64>(Wb, slice * 256 + bo * 128, xT + ((size_t)b * THW_ + s0) * 256, As, Bs, acc);
    const __half* ctx = (slice == 0) ? ctx_t : (slice == 1) ? ctx_h : ctx_w;
    #pragma unroll
    for (int mi = 0; mi < 4; mi++)
      #pragma unroll
      for (int ni = 0; ni < 2; ni++)
        #pragma unroll
        for (int r = 0; r < 4; r++){
          int o = bo * 128 + wm * 64 + mi * 16 + (lane >> 4) * 4 + r;
          int s = s0 + wn * 32 + ni * 16 + (lane & 15);
          float lg = acc[mi][ni][r] + gb[slice * 256 + o];
          float g = 1.f / (1.f + __expf(-lg));
          yacc[mi][ni][r] += g * __half2float(ctx[obase + (size_t)o * THW_ + s]);
        }
  }
  #pragma unroll
  for (int mi = 0; mi < 4; mi++)
    #pragma unroll
    for (int ni = 0; ni < 2; ni++)
      #pragma unroll
      for (int r = 0; r < 4; r++){
        int o = bo * 128 + wm * 64 + mi * 16 + (lane >> 4) * 4 + r;
        int s = s0 + wn * 32 + ni * 16 + (lane & 15);
        y[obase + (size_t)o * THW_ + s] = __float2half(yacc[mi][ni][r]);
      }
}

// ---------------- proj GEMM -> d_out (f32) ----------------
__global__ __launch_bounds__(256) void k_mfma_proj(
    const unsigned short* __restrict__ Wb, const unsigned short* __restrict__ yT,
    float* __restrict__ out)
{
  __shared__ unsigned short As[8192], Bs[8192];
  const int bo = blockIdx.x;                  // 0..1
  const int s0 = blockIdx.y * 128;
  const int b  = blockIdx.z;
  f4_t acc[4][4];
  #pragma unroll
  for (int mi = 0; mi < 4; mi++)
    #pragma unroll
    for (int ni = 0; ni < 4; ni++) acc[mi][ni] = (f4_t)0.f;
  gemm_core_b<128>(Wb, bo * 128, yT + ((size_t)b * THW_ + s0) * 256, As, Bs, acc);
  const int lane = threadIdx.x & 63, wv = threadIdx.x >> 6;
  const int wm = wv >> 1, wn = wv & 1;
  size_t obase = (size_t)(b * C_) * THW_;
  #pragma unroll
  for (int mi = 0; mi < 4; mi++)
    #pragma unroll
    for (int ni = 0; ni < 4; ni++)
      #pragma unroll
      for (int r = 0; r < 4; r++){
        int o = bo * 128 + wm * 64 + mi * 16 + (lane >> 4) * 4 + r;
        int s = s0 + wn * 64 + ni * 16 + (lane & 15);
        out[obase + (size_t)o * THW_ + s] = acc[mi][ni][r];
      }
}

// ---------------- mean over (H,W): qg[b,c,t] (q is f16) ----------------
__global__ __launch_bounds__(256) void k_mean_hw(const __half* __restrict__ q, float* __restrict__ qg){
  int bct = blockIdx.x;
  const __half2* p = (const __half2*)(q + (size_t)bct * HW_);
  __half2 v0 = p[threadIdx.x * 2], v1 = p[threadIdx.x * 2 + 1];
  float sum = __low2float(v0) + __high2float(v0) + __low2float(v1) + __high2float(v1);
  #pragma unroll
  for (int off = 32; off; off >>= 1) sum += __shfl_down(sum, off);
  __shared__ float red[4];
  int lane = threadIdx.x & 63, w = threadIdx.x >> 6;
  if (lane == 0) red[w] = sum;
  __syncthreads();
  if (threadIdx.x == 0) qg[bct] = (red[0] + red[1] + red[2] + red[3]) * (1.f / 1024.f);
}

// ---------------- mix pre: h = gelu(pre_w @ qg + pre_b) ----------------
__global__ __launch_bounds__(256) void k_mix_pre(const float* __restrict__ preW, const float* __restrict__ preB,
    const float* __restrict__ qg, float* __restrict__ hbuf){
  int b = blockIdx.x >> 5, t = blockIdx.x & 31;
  int o = threadIdx.x;
  __shared__ float qgl[256];
  qgl[o] = qg[((size_t)(b * C_ + o)) * T_ + t];
  __syncthreads();
  float a = preB[o];
  for (int c = 0; c < C_; c++) a = fmaf(preW[o * C_ + c], qgl[c], a);
  float g = 0.5f * a * (1.f + erff(a * 0.70710678118f));
  hbuf[((size_t)(b * C_ + o)) * T_ + t] = g;
}

// ---------------- mix logits + softmax over m ----------------
__global__ __launch_bounds__(256) void k_mix_alpha(const float* __restrict__ cw, const float* __restrict__ cb,
    const float* __restrict__ hbuf, float* __restrict__ alpha){
  int b = blockIdx.x >> 5, t = blockIdx.x & 31;
  int c = threadIdx.x;
  float hv[3];
  #pragma unroll
  for (int j = 0; j < 3; j++){
    int tt = t - 2 + j;
    hv[j] = (tt >= 0) ? hbuf[((size_t)(b * C_ + c)) * T_ + tt] : 0.f;
  }
  float p[3];
  #pragma unroll
  for (int m = 0; m < 3; m++){
    const float* w = cw + ((size_t)m * C_ + c) * 3;
    p[m] = w[0] * hv[0] + w[1] * hv[1] + w[2] * hv[2];
  }
  #pragma unroll
  for (int m = 0; m < 3; m++){
    #pragma unroll
    for (int off = 32; off; off >>= 1) p[m] += __shfl_down(p[m], off);
  }
  __shared__ float red[3][4];
  int lane = threadIdx.x & 63, w = threadIdx.x >> 6;
  if (lane == 0){ red[0][w] = p[0]; red[1][w] = p[1]; red[2][w] = p[2]; }
  __syncthreads();
  if (threadIdx.x == 0){
    float lg[3];
    #pragma unroll
    for (int m = 0; m < 3; m++) lg[m] = red[m][0] + red[m][1] + red[m][2] + red[m][3] + cb[m];
    float mx = fmaxf(lg[0], fmaxf(lg[1], lg[2]));
    float e0 = __expf(lg[0] - mx), e1 = __expf(lg[1] - mx), e2 = __expf(lg[2] - mx);
    float r = 1.f / (e0 + e1 + e2);
    alpha[((size_t)(b * 3 + 0)) * T_ + t] = e0 * r;
    alpha[((size_t)(b * 3 + 1)) * T_ + t] = e1 * r;
    alpha[((size_t)(b * 3 + 2)) * T_ + t] = e2 * r;
  }
}

// ---------------- alpha-mixed causal depthwise conv 3x3x3 (f16 in/out) ----------------
__global__ __launch_bounds__(256) void k_conv1(
    const __half* __restrict__ in_g, const float* __restrict__ bank,
    const float* __restrict__ alpha, __half* __restrict__ out)
{
  int bi = blockIdx.x;
  int c = bi & 255, t = (bi >> 8) & 31, b = bi >> 13;
  __shared__ float sIn[3 * 34 * 34];
  __shared__ float wmix[27];
  int tid = threadIdx.x;
  if (tid < 27){
    float sum = 0.f;
    #pragma unroll
    for (int m = 0; m < 3; m++)
      sum += alpha[((size_t)(b * 3 + m)) * T_ + t] * bank[((size_t)m * C_ + c) * 27 + tid];
    wmix[tid] = sum;
  }
  size_t cbase = ((size_t)(b * C_ + c)) * T_;
  for (int idx = tid; idx < 3 * 34 * 34; idx += 256){
    int tp = idx / 1156, rem = idx % 1156;
    int yy = rem / 34, xx = rem % 34;
    int tin = t - 2 + tp, y = yy - 1, x = xx - 1;
    bool ok = (tin >= 0) && (y >= 0) && (y < 32) && (x >= 0) && (x < 32);
    size_t g = ok ? ((cbase + tin) * HW_ + (size_t)y * 32 + x) : 0;
    sIn[idx] = ok ? __half2float(in_g[g]) : 0.f;
  }
  __syncthreads();
  int y = tid >> 3, x0 = (tid & 7) * 4;
  float a[4] = {0.f, 0.f, 0.f, 0.f};
  #pragma unroll
  for (int dt = 0; dt < 3; dt++){
    #pragma unroll
    for (int dy = 0; dy < 3; dy++){
      int rb = dt * 1156 + (y + dy) * 34 + x0;
      #pragma unroll
      for (int dx = 0; dx < 3; dx++){
        float wv = wmix[dt * 9 + dy * 3 + dx];
        #pragma unroll
        for (int p2 = 0; p2 < 4; p2++) a[p2] = fmaf(wv, sIn[rb + dx + p2], a[p2]);
      }
    }
  }
  size_t ob = (cbase + t) * HW_ + (size_t)y * 32 + x0;
  __half2 h01 = __halves2half2(__float2half(a[0]), __float2half(a[1]));
  __half2 h23 = __halves2half2(__float2half(a[2]), __float2half(a[3]));
  *reinterpret_cast<__half2*>(out + ob)     = h01;
  *reinterpret_cast<__half2*>(out + ob + 2) = h23;
}

// ---------------- axial attention via MFMA, one 32x32 sequence per wave ----------------
// LDS (ushort idx): q[seq]: seq*2560 + i*40 + f ; k[seq]: +1280 ; v[seq]: 10240 + seq*1280 + d*40 + j
// O aliases q/k region after barrier:
//   AXIS 0/1: idx = ((i*32+d)<<2 ^ (((i>>2)&3)<<2)) + g    (g-interleaved, vector read)
//   AXIS 2:   idx = g*1152 + d*36 + (i ^ ((d&3)<<2))       (i-contiguous, vector read)
// RoPE folded into staging; swapped QK^T; P stays in registers (pkrtz + shuffle regroup).
template<int AXIS>
__global__ __launch_bounds__(256) void k_attn(
    const __half* __restrict__ qg_, const __half* __restrict__ kg_,
    const __half* vg_, __half* ctx,            // may alias (AXIS=2 in-place)
    const float* __restrict__ cosT, const float* __restrict__ sinT)
{
  const int SS = (AXIS == 0) ? HW_ : (AXIS == 1) ? 32 : 1;
  const int GS = (AXIS == 2) ? 32 : 1;
  const int OS = (AXIS == 0) ? 32 : HW_;
  int id = blockIdx.x;
  int ggrp = (id >> 3) & 7;
  int rest = ((id >> 6) << 3) | (id & 7);
  int outer = rest & 31;
  int head = (rest >> 5) & 7;
  int b = rest >> 8;
  const size_t base = ((size_t)(b * C_ + head * 32)) * THW_ + (size_t)outer * OS + (size_t)(ggrp * 4) * GS;

  __shared__ __align__(16) unsigned short smem[15360];   // 30 KB
  const int tid = threadIdx.x;
  const unsigned short* qp = (const unsigned short*)qg_;
  const unsigned short* kp = (const unsigned short*)kg_;
  const unsigned short* vp = (const unsigned short*)vg_;

  // ---- staged load q,k with RoPE folded (register rotate) ----
  for (int idx2 = tid; idx2 < 512; idx2 += 256){
    if (AXIS != 2){
      int i = idx2 & 31, u = idx2 >> 5;                  // u in 0..15
      size_t glo = base + (size_t)u * THW_ + (size_t)i * SS;
      size_t ghi = glo + (size_t)16 * THW_;
      ushort4 ql = *(const ushort4*)(qp + glo), qh = *(const ushort4*)(qp + ghi);
      ushort4 kl = *(const ushort4*)(kp + glo), kh = *(const ushort4*)(kp + ghi);
      float cv = cosT[i * 16 + u], sv = sinT[i * 16 + u];
      const unsigned short qla[4] = {ql.x, ql.y, ql.z, ql.w}, qha[4] = {qh.x, qh.y, qh.z, qh.w};
      const unsigned short kla[4] = {kl.x, kl.y, kl.z, kl.w}, kha[4] = {kh.x, kh.y, kh.z, kh.w};
      #pragma unroll
      for (int g = 0; g < 4; g++){
        int rb = g * 2560 + i * 40;
        float a = h2f_u(qla[g]), b2 = h2f_u(qha[g]);
        smem[rb + u]      = f2h_u(a * cv - b2 * sv);
        smem[rb + u + 16] = f2h_u(fmaf(b2, cv, a * sv));
        a = h2f_u(kla[g]); b2 = h2f_u(kha[g]);
        smem[rb + 1280 + u]      = f2h_u(a * cv - b2 * sv);
        smem[rb + 1280 + u + 16] = f2h_u(fmaf(b2, cv, a * sv));
      }
    } else {
      int ii = (idx2 & 7) * 4, g = (idx2 >> 3) & 3, u = idx2 >> 5;
      size_t glo = base + (size_t)u * THW_ + (size_t)g * GS + ii;
      size_t ghi = glo + (size_t)16 * THW_;
      ushort4 ql = *(const ushort4*)(qp + glo), qh = *(const ushort4*)(qp + ghi);
      ushort4 kl = *(const ushort4*)(kp + glo), kh = *(const ushort4*)(kp + ghi);
      const unsigned short qla[4] = {ql.x, ql.y, ql.z, ql.w}, qha[4] = {qh.x, qh.y, qh.z, qh.w};
      const unsigned short kla[4] = {kl.x, kl.y, kl.z, kl.w}, kha[4] = {kh.x, kh.y, kh.z, kh.w};
      #pragma unroll
      for (int p2 = 0; p2 < 4; p2++){
        int i = ii + p2;
        int rb = g * 2560 + i * 40;
        float cv = cosT[i * 16 + u], sv = sinT[i * 16 + u];
        float a = h2f_u(qla[p2]), b2 = h2f_u(qha[p2]);
        smem[rb + u]      = f2h_u(a * cv - b2 * sv);
        smem[rb + u + 16] = f2h_u(fmaf(b2, cv, a * sv));
        a = h2f_u(kla[p2]); b2 = h2f_u(kha[p2]);
        smem[rb + 1280 + u]      = f2h_u(a * cv - b2 * sv);
        smem[rb + 1280 + u + 16] = f2h_u(fmaf(b2, cv, a * sv));
      }
    }
  }
  // ---- staged load v -> transposed [d][j] ----
  for (int idx2 = tid; idx2 < 1024; idx2 += 256){
    if (AXIS != 2){
      int i = idx2 & 31, f = idx2 >> 5;
      size_t go = base + (size_t)f * THW_ + (size_t)i * SS;
      ushort4 vv = *(const ushort4*)(vp + go);
      const unsigned short va[4] = {vv.x, vv.y, vv.z, vv.w};
      #pragma unroll
      for (int g = 0; g < 4; g++) smem[10240 + g * 1280 + f * 40 + i] = va[g];
    } else {
      int ii = (idx2 & 7) * 4, g = (idx2 >> 3) & 3, f = idx2 >> 5;
      size_t go = base + (size_t)f * THW_ + (size_t)g * GS + ii;
      ushort4 vv = *(const ushort4*)(vp + go);
      const unsigned short va[4] = {vv.x, vv.y, vv.z, vv.w};
      #pragma unroll
      for (int p2 = 0; p2 < 4; p2++) smem[10240 + g * 1280 + f * 40 + ii + p2] = va[p2];
    }
  }
  __syncthreads();

  const int lane = tid & 63;
  const int seq = tid >> 6;
  const int m = lane & 15, kg = lane >> 4;
  const int sq = seq * 2560;

  // ---- frag loads ----
  h8_t aQ[2], bK[2], bV[2];
  #pragma unroll
  for (int t2 = 0; t2 < 2; t2++){
    aQ[t2] = *(const h8_t*)&smem[sq + (t2 * 16 + m) * 40 + kg * 8];
    bK[t2] = *(const h8_t*)&smem[sq + 1280 + (t2 * 16 + m) * 40 + kg * 8];
    bV[t2] = *(const h8_t*)&smem[10240 + seq * 1280 + (t2 * 16 + m) * 40 + kg * 8];
  }

  // ---- swapped QK^T: st[tk][tq] -> lane holds S[i=tq*16+m][j=tk*16+kg*4+r] ----
  f4_t st[2][2];
  #pragma unroll
  for (int tk = 0; tk < 2; tk++)
    #pragma unroll
    for (int tq = 0; tq < 2; tq++){
      st[tk][tq] = (f4_t)0.f;
      st[tk][tq] = __builtin_amdgcn_mfma_f32_16x16x32_f16(bK[tk], aQ[tq], st[tk][tq], 0, 0, 0);
    }

  // ---- softmax along lane-local rows, P scaled by 1/rowsum, packed f16 pairs ----
  u32 pkk[2][2][2];             // [tq][tk][pair]
  #pragma unroll
  for (int tq = 0; tq < 2; tq++){
    const int i = tq * 16 + m;
    float e[2][4];
    float mx = -3.0e38f;
    #pragma unroll
    for (int tk = 0; tk < 2; tk++)
      #pragma unroll
      for (int r = 0; r < 4; r++){
        float s = st[tk][tq][r] * 0.17677669529663687f;
        if (AXIS == 0 && (tk * 16 + kg * 4 + r) > i) s = -1e30f;
        e[tk][r] = s;
        mx = fmaxf(mx, s);
      }
    mx = fmaxf(mx, __shfl_xor(mx, 16));
    mx = fmaxf(mx, __shfl_xor(mx, 32));
    float sum = 0.f;
    #pragma unroll
    for (int tk = 0; tk < 2; tk++)
      #pragma unroll
      for (int r = 0; r < 4; r++){
        e[tk][r] = __expf(e[tk][r] - mx);
        sum += e[tk][r];
      }
    sum += __shfl_xor(sum, 16);
    sum += __shfl_xor(sum, 32);
    float rinv = 1.f / sum;
    #pragma unroll
    for (int tk = 0; tk < 2; tk++){
      pkk[tq][tk][0] = pkrtz(e[tk][0] * rinv, e[tk][1] * rinv);
      pkk[tq][tk][1] = pkrtz(e[tk][2] * rinv, e[tk][3] * rinv);
    }
  }

  // ---- regroup P -> A-frag via shuffles: word w = j-pair (kg*8+2w, +1) ----
  h8_t aP[2];
  #pragma unroll
  for (int tq = 0; tq < 2; tq++){
    union { u32 w[4]; h8_t h; } uu;
    #pragma unroll
    for (int w = 0; w < 4; w++){
      int srcLane = ((kg & 1) * 2 + (w >> 1)) * 16 + m;
      u32 v0 = __shfl(pkk[tq][0][w & 1], srcLane);
      u32 v1 = __shfl(pkk[tq][1][w & 1], srcLane);
      uu.w[w] = (kg >= 2) ? v1 : v0;
    }
    aP[tq] = uu.h;
  }

  // ---- PV: O[i=tq*16+kg*4+r][d=td*16+m], pre-normalized ----
  f4_t o_[2][2];
  #pragma unroll
  for (int tq = 0; tq < 2; tq++)
    #pragma unroll
    for (int td = 0; td < 2; td++){
      o_[tq][td] = (f4_t)0.f;
      o_[tq][td] = __builtin_amdgcn_mfma_f32_16x16x32_f16(aP[tq], bV[td], o_[tq][td], 0, 0, 0);
    }

  __syncthreads();   // all waves done reading q/k before O overwrites it

  #pragma unroll
  for (int tq = 0; tq < 2; tq++)
    #pragma unroll
    for (int td = 0; td < 2; td++)
      #pragma unroll
      for (int r = 0; r < 4; r++){
        int i = tq * 16 + kg * 4 + r, d = td * 16 + m;
        if (AXIS != 2){
          int a4 = (((i * 32 + d) << 2) ^ (kg << 2)) + seq;   // (i>>2)&3 == kg
          smem[a4] = f2h_u(o_[tq][td][r]);
        } else {
          smem[seq * 1152 + d * 36 + (i ^ ((d & 3) << 2))] = f2h_u(o_[tq][td][r]);
        }
      }
  __syncthreads();

  // ---- staged store (vector LDS reads) ----
  for (int idx2 = tid; idx2 < 1024; idx2 += 256){
    if (AXIS != 2){
      int i2 = idx2 & 31, f = idx2 >> 5;
      int a4 = ((i2 * 32 + f) << 2) ^ ((((i2 >> 2) & 3)) << 2);
      ushort4 ov = *(const ushort4*)&smem[a4];
      size_t go = base + (size_t)f * THW_ + (size_t)i2 * SS;
      *(ushort4*)((unsigned short*)ctx + go) = ov;
    } else {
      int ii = (idx2 & 7) * 4, g2 = (idx2 >> 3) & 3, f = idx2 >> 5;
      ushort4 ov = *(const ushort4*)&smem[g2 * 1152 + f * 36 + (ii ^ ((f & 3) << 2))];
      size_t go = base + (size_t)f * THW_ + (size_t)g2 * GS + ii;
      *(ushort4*)((unsigned short*)ctx + go) = ov;
    }
  }
}

extern "C" void kernel_launch(void* const* d_in, const int* in_sizes, int n_in,
                              void* d_out, int out_size, void* d_ws, size_t ws_size,
                              hipStream_t stream)
{
  (void)in_sizes; (void)n_in; (void)out_size; (void)ws_size;
  const float* x       = (const float*)d_in[0];
  const float* w_qkv   = (const float*)d_in[1];
  const float* wk_bank = (const float*)d_in[2];
  const float* wv_bank = (const float*)d_in[3];
  const float* pre_w   = (const float*)d_in[4];
  const float* pre_b   = (const float*)d_in[5];
  const float* cw      = (const float*)d_in[6];
  const float* cb      = (const float*)d_in[7];
  const float* gate_w  = (const float*)d_in[8];
  const float* gate_b  = (const float*)d_in[9];
  const float* proj_w  = (const float*)d_in[10];

  const size_t SZ = (size_t)B_ * C_ * THW_;           // 16,777,216 elems
  __half* hb = (__half*)d_ws;                         // 32MB slots
  unsigned short* xT  = (unsigned short*)(hb + 0 * SZ);  // bf16, alive to gate
  __half* qH   = hb + 1 * SZ;                         // q
  __half* kH   = hb + 2 * SZ;                         // k -> ctx_t -> y
  __half* vH   = hb + 3 * SZ;                         // v -> ctx_h
  __half* koH  = hb + 4 * SZ;                         // k_out -> yT(bf16)
  __half* voH  = hb + 5 * SZ;                         // v_out -> ctx_w (in-place)
  __half* ctxtH = kH;
  __half* ctxhH = vH;
  __half* yH    = kH;                                 // gate writes y over ctx_t (same-thread elem)
  unsigned short* yT = (unsigned short*)koH;          // over dead k_out
  float* sm    = (float*)(hb + 6 * SZ);               // smalls
  float* qg    = sm;                                  // 16384
  float* hbuf  = qg + 16384;                          // 16384
  float* alpha = hbuf + 16384;                        // 192
  float* cosT  = alpha + 192;                         // 512
  float* sinT  = cosT + 512;                          // 512
  unsigned short* wB = (unsigned short*)(sinT + 512); // 1792*256 bf16 (896 KB)
  unsigned short* wBq = wB;                           // [768][256]
  unsigned short* wBg = wB + 768 * 256;               // [768][256]
  unsigned short* wBp = wB + 1536 * 256;              // [256][256]

  k_rope_table<<<1, 512, 0, stream>>>(cosT, sinT);
  k_wcvt<<<1792, 256, 0, stream>>>(w_qkv, gate_w, proj_w, wB);
  k_transpose_cvt<float><<<dim3(512, 4, 2), 256, 0, stream>>>(x, xT);

  k_mfma_qkv<<<dim3(6, 256, 2), 256, 0, stream>>>(wBq, xT, qH, kH, vH);

  k_mean_hw<<<16384, 256, 0, stream>>>(qH, qg);
  k_mix_pre<<<64, 256, 0, stream>>>(pre_w, pre_b, qg, hbuf);
  k_mix_alpha<<<64, 256, 0, stream>>>(cw, cb, hbuf, alpha);

  k_conv1<<<16384, 256, 0, stream>>>(kH, wk_bank, alpha, koH);   // k_out
  k_conv1<<<16384, 256, 0, stream>>>(vH, wv_bank, alpha, voH);   // v_out

  k_attn<0><<<4096, 256, 0, stream>>>(qH, koH, voH, ctxtH, cosT, sinT); // ctx_t (k dead)
  k_attn<1><<<4096, 256, 0, stream>>>(qH, koH, voH, ctxhH, cosT, sinT); // ctx_h (v dead)
  k_attn<2><<<4096, 256, 0, stream>>>(qH, koH, voH, voH,   cosT, sinT); // ctx_w in-place

  k_mfma_gate<<<dim3(2, 512, 2), 256, 0, stream>>>(wBg, xT, gate_b,
                                                   ctxtH, ctxhH, voH, yH);
  k_transpose_cvt<__half><<<dim3(512, 4, 2), 256, 0, stream>>>(yH, yT);  // k_out dead
  k_mfma_proj<<<dim3(2, 256, 2), 256, 0, stream>>>(wBp, yT, (float*)d_out);
}

// Round 9
// 501.235 us; speedup vs baseline: 4.3241x; 1.0595x over previous
//
#include <hip/hip_runtime.h>
#include <hip/hip_fp16.h>
#include <math.h>

#define B_   2
#define C_   256
#define T_   32
#define HW_  1024
#define THW_ 32768

using u32 = unsigned int;
typedef __attribute__((ext_vector_type(8))) short bf8_t;   // 8 bf16 in 4 VGPRs
typedef __attribute__((ext_vector_type(8))) unsigned short us8_t;
typedef __attribute__((ext_vector_type(8))) _Float16 h8_t; // 8 f16 in 4 VGPRs
typedef __attribute__((ext_vector_type(2))) __fp16 fp16v2; // builtin cvt_pkrtz return type
typedef __attribute__((ext_vector_type(4))) float f4_t;

static __device__ __forceinline__ unsigned short f2bf(float x){
  u32 u = __float_as_uint(x);
  u32 r = (u + 0x7FFF + ((u >> 16) & 1)) >> 16;   // RNE
  return (unsigned short)r;
}
static __device__ __forceinline__ float h2f_u(unsigned short u){
  union { __half h; unsigned short us; } cv; cv.us = u; return __half2float(cv.h);
}
static __device__ __forceinline__ unsigned short f2h_u(float f){
  union { __half h; unsigned short us; } cv; cv.h = __float2half(f); return cv.us;
}
static __device__ __forceinline__ u32 pkrtz(float a, float b){
  union { fp16v2 h; u32 w; } cv; cv.h = __builtin_amdgcn_cvt_pkrtz(a, b); return cv.w;
}
static __device__ __forceinline__ float ldf(const float* p){ return *p; }
static __device__ __forceinline__ float ldf(const __half* p){ return __half2float(*p); }

// ---------------- rope table ----------------
__global__ void k_rope_table(float* __restrict__ cosT, float* __restrict__ sinT){
  int tid = threadIdx.x;            // 512 threads, tid = i*16+u
  int i = tid >> 4, u = tid & 15;
  float invf = powf(10000.f, -(2.f * (float)u) / 32.f);
  float s, c;
  sincosf((float)i * invf, &s, &c);
  cosT[tid] = c;
  sinT[tid] = s;
}

// ---------------- weight cvt: stack w_qkv(768), gate_w(768), proj_w(256) as bf16 [1792][256] --
__global__ void k_wcvt(const float* __restrict__ w_qkv, const float* __restrict__ gate_w,
                       const float* __restrict__ proj_w, unsigned short* __restrict__ out){
  int row = blockIdx.x, c = threadIdx.x;
  const float* src = (row < 768) ? w_qkv + (size_t)row * 256
                   : (row < 1536) ? gate_w + (size_t)(row - 768) * 256
                                  : proj_w + (size_t)(row - 1536) * 256;
  out[(size_t)row * 256 + c] = f2bf(src[c]);
}

// ---------------- transpose+cvt: [b][256][THW] f32 -> bf16 [b][THW][256] ----------------
template<typename InT>
__global__ __launch_bounds__(256) void k_transpose_cvt(
    const InT* __restrict__ in, unsigned short* __restrict__ outT)
{
  __shared__ float tile[64][65];
  int s0 = blockIdx.x * 64;     // 512
  int c0 = blockIdx.y * 64;     // 4
  int b  = blockIdx.z;
  int tid = threadIdx.x;
  for (int idx = tid; idx < 4096; idx += 256){
    int c = idx >> 6, s = idx & 63;
    tile[c][s] = ldf(&in[((size_t)(b * C_ + c0 + c)) * THW_ + s0 + s]);
  }
  __syncthreads();
  for (int idx = tid; idx < 4096; idx += 256){
    int s = idx >> 6, c = idx & 63;
    outT[((size_t)b * THW_ + s0 + s) * 256 + c0 + c] = f2bf(tile[c][s]);
  }
}

// ---------------- MFMA GEMM core (bf16 A bank): 128xBN tile, K=256 ----------------
template<int BN>
static __device__ __forceinline__ void gemm_core_b(
    const unsigned short* __restrict__ A, int o0,
    const unsigned short* __restrict__ BT,   // pre-offset: + (b*THW + s0)*256
    unsigned short* As, unsigned short* Bs, f4_t acc[4][BN / 32])
{
  const int tid = threadIdx.x;
  const int lane = tid & 63, wv = tid >> 6;
  const int wm = wv >> 1, wn = wv & 1;
  const int m = lane & 15, kg = lane >> 4;
  const int arow = tid >> 1, aseg = (tid & 1) * 64;     // A: 128 rows, 2 thr/row, 64B each
  const int brow = (BN == 128) ? (tid >> 1) : (tid >> 2);
  const int bseg = (BN == 128) ? (tid & 1) * 64 : (tid & 3) * 32;
  for (int ks = 0; ks < 4; ks++){
    __syncthreads();                                    // protect prior reads
    {
      const unsigned short* ga = A + (size_t)(o0 + arow) * 256 + ks * 64 + aseg / 2;
      #pragma unroll
      for (int q2 = 0; q2 < 4; q2++){
        us8_t v = *(const us8_t*)(ga + q2 * 8);
        *(us8_t*)((char*)As + arow * 128 + ((aseg + q2 * 16) ^ ((arow & 7) << 4))) = v;
      }
      const unsigned short* gb = BT + (size_t)brow * 256 + ks * 64 + bseg / 2;
      #pragma unroll
      for (int q2 = 0; q2 < (BN == 128 ? 4 : 2); q2++){
        us8_t v = *(const us8_t*)(gb + q2 * 8);
        *(us8_t*)((char*)Bs + brow * 128 + ((bseg + q2 * 16) ^ ((brow & 7) << 4))) = v;
      }
    }
    __syncthreads();
    #pragma unroll
    for (int kk = 0; kk < 2; kk++){
      bf8_t af[4], bfr[BN / 32];
      #pragma unroll
      for (int mi = 0; mi < 4; mi++){
        int row = wm * 64 + mi * 16 + m;
        af[mi] = *(const bf8_t*)((const char*)As + row * 128 + ((kk * 64 + kg * 16) ^ ((row & 7) << 4)));
      }
      #pragma unroll
      for (int ni = 0; ni < BN / 32; ni++){
        int row = wn * (BN / 2) + ni * 16 + m;
        bfr[ni] = *(const bf8_t*)((const char*)Bs + row * 128 + ((kk * 64 + kg * 16) ^ ((row & 7) << 4)));
      }
      #pragma unroll
      for (int mi = 0; mi < 4; mi++)
        #pragma unroll
        for (int ni = 0; ni < BN / 32; ni++)
          acc[mi][ni] = __builtin_amdgcn_mfma_f32_16x16x32_bf16(af[mi], bfr[ni], acc[mi][ni], 0, 0, 0);
    }
  }
}

// ---------------- qkv GEMM: Wq(bf16)[768][256] @ x -> q,k,v (f16) ----------------
__global__ __launch_bounds__(256) void k_mfma_qkv(
    const unsigned short* __restrict__ Wb, const unsigned short* __restrict__ xT,
    __half* __restrict__ q, __half* __restrict__ k, __half* __restrict__ v)
{
  __shared__ unsigned short As[8192], Bs[8192];
  const int bo = blockIdx.x;                  // 0..5
  const int s0 = blockIdx.y * 128;            // 256
  const int b  = blockIdx.z;
  f4_t acc[4][4];
  #pragma unroll
  for (int mi = 0; mi < 4; mi++)
    #pragma unroll
    for (int ni = 0; ni < 4; ni++) acc[mi][ni] = (f4_t)0.f;
  gemm_core_b<128>(Wb, bo * 128, xT + ((size_t)b * THW_ + s0) * 256, As, Bs, acc);
  __half* outp = (bo < 2) ? q : (bo < 4) ? k : v;
  const int ro = (bo & 1) * 128;
  const int lane = threadIdx.x & 63, wv = threadIdx.x >> 6;
  const int wm = wv >> 1, wn = wv & 1;
  size_t obase = (size_t)(b * C_) * THW_;
  #pragma unroll
  for (int mi = 0; mi < 4; mi++)
    #pragma unroll
    for (int ni = 0; ni < 4; ni++)
      #pragma unroll
      for (int r = 0; r < 4; r++){
        int o = ro + wm * 64 + mi * 16 + (lane >> 4) * 4 + r;
        int s = s0 + wn * 64 + ni * 16 + (lane & 15);
        outp[obase + (size_t)o * THW_ + s] = __float2half(acc[mi][ni][r]);
      }
}

// ---------------- gate GEMM + sigmoid + combine, 3 slices interleaved, yT(bf16) direct ------
// Tile 64(o) x 64(s) per slice. grid (4 bo, 512 s0, 2 b), block 256 = 4 waves (2x2).
// LDS: As3 3x[64][64] (24KB) + Bs [64][64] (8KB); epilogue reuses As3 as [64][72] transpose tile.
__global__ __launch_bounds__(256) void k_mfma_gate2(
    const unsigned short* __restrict__ Wb,   // bf16 gate bank [768][256]
    const unsigned short* __restrict__ xT,
    const float* __restrict__ gb,
    const __half* __restrict__ ctx_t, const __half* __restrict__ ctx_h,
    const __half* __restrict__ ctx_w,
    unsigned short* __restrict__ yT)         // bf16 [b][THW][256]
{
  __shared__ unsigned short As3[12288];
  __shared__ unsigned short Bs[4096];
  const int bo = blockIdx.x;                  // 0..3
  const int s0 = blockIdx.y * 64;
  const int b  = blockIdx.z;
  const int tid = threadIdx.x;
  const int lane = tid & 63, wv = tid >> 6;
  const int wm = wv >> 1, wn = wv & 1;
  const int m = lane & 15, kg = lane >> 4;
  const unsigned short* xbase = xT + ((size_t)b * THW_ + s0) * 256;

  f4_t acc[3][2][2];
  #pragma unroll
  for (int sl = 0; sl < 3; sl++)
    #pragma unroll
    for (int mi = 0; mi < 2; mi++)
      #pragma unroll
      for (int ni = 0; ni < 2; ni++) acc[sl][mi][ni] = (f4_t)0.f;

  for (int ks = 0; ks < 4; ks++){
    __syncthreads();
    #pragma unroll
    for (int rep = 0; rep < 2; rep++){
      int idx = rep * 256 + tid;              // 0..511
      int row = idx >> 3, seg = idx & 7;
      us8_t v = *(const us8_t*)(xbase + (size_t)row * 256 + ks * 64 + seg * 8);
      *(us8_t*)((char*)Bs + row * 128 + ((seg * 16) ^ ((row & 7) << 4))) = v;
    }
    #pragma unroll
    for (int sl = 0; sl < 3; sl++){
      #pragma unroll
      for (int rep = 0; rep < 2; rep++){
        int idx = rep * 256 + tid;
        int row = idx >> 3, seg = idx & 7;
        us8_t v = *(const us8_t*)(Wb + (size_t)(sl * 256 + bo * 64 + row) * 256 + ks * 64 + seg * 8);
        *(us8_t*)((char*)As3 + sl * 8192 + row * 128 + ((seg * 16) ^ ((row & 7) << 4))) = v;
      }
    }
    __syncthreads();
    #pragma unroll
    for (int kk = 0; kk < 2; kk++){
      bf8_t bfr[2], af[3][2];
      #pragma unroll
      for (int ni = 0; ni < 2; ni++){
        int row = wn * 32 + ni * 16 + m;
        bfr[ni] = *(const bf8_t*)((const char*)Bs + row * 128 + ((kk * 64 + kg * 16) ^ ((row & 7) << 4)));
      }
      #pragma unroll
      for (int sl = 0; sl < 3; sl++)
        #pragma unroll
        for (int mi = 0; mi < 2; mi++){
          int row = wm * 32 + mi * 16 + m;
          af[sl][mi] = *(const bf8_t*)((const char*)As3 + sl * 8192 + row * 128 + ((kk * 64 + kg * 16) ^ ((row & 7) << 4)));
        }
      #pragma unroll
      for (int sl = 0; sl < 3; sl++)
        #pragma unroll
        for (int mi = 0; mi < 2; mi++)
          #pragma unroll
          for (int ni = 0; ni < 2; ni++)
            acc[sl][mi][ni] = __builtin_amdgcn_mfma_f32_16x16x32_bf16(af[sl][mi], bfr[ni], acc[sl][mi][ni], 0, 0, 0);
    }
  }

  // epilogue: sigmoid-gate + combine 3 slices
  const size_t obase = (size_t)(b * C_) * THW_;
  f4_t yacc[2][2];
  #pragma unroll
  for (int mi = 0; mi < 2; mi++)
    #pragma unroll
    for (int ni = 0; ni < 2; ni++) yacc[mi][ni] = (f4_t)0.f;
  #pragma unroll
  for (int sl = 0; sl < 3; sl++){
    const __half* ctx = (sl == 0) ? ctx_t : (sl == 1) ? ctx_h : ctx_w;
    #pragma unroll
    for (int mi = 0; mi < 2; mi++)
      #pragma unroll
      for (int ni = 0; ni < 2; ni++)
        #pragma unroll
        for (int r = 0; r < 4; r++){
          int ol = wm * 32 + mi * 16 + kg * 4 + r;
          int s  = s0 + wn * 32 + ni * 16 + m;
          float lg = acc[sl][mi][ni][r] + gb[sl * 256 + bo * 64 + ol];
          float g = __builtin_amdgcn_rcpf(1.f + __expf(-lg));
          yacc[mi][ni][r] += g * __half2float(ctx[obase + (size_t)(bo * 64 + ol) * THW_ + s]);
        }
  }

  __syncthreads();                            // done reading As3/Bs fragments
  // transpose tile [s_local][72] bf16 in As3, then coalesced yT write
  unsigned short* tile = As3;
  #pragma unroll
  for (int mi = 0; mi < 2; mi++)
    #pragma unroll
    for (int ni = 0; ni < 2; ni++){
      int ol = wm * 32 + mi * 16 + kg * 4;
      int sl2 = wn * 32 + ni * 16 + m;
      ushort4 w4;
      w4.x = f2bf(yacc[mi][ni][0]);
      w4.y = f2bf(yacc[mi][ni][1]);
      w4.z = f2bf(yacc[mi][ni][2]);
      w4.w = f2bf(yacc[mi][ni][3]);
      *(ushort4*)&tile[sl2 * 72 + ol] = w4;
    }
  __syncthreads();
  {
    int sr = tid >> 2, oc = (tid & 3) * 16;
    us8_t v0 = *(const us8_t*)&tile[sr * 72 + oc];
    us8_t v1 = *(const us8_t*)&tile[sr * 72 + oc + 8];
    unsigned short* dst = yT + ((size_t)b * THW_ + s0 + sr) * 256 + bo * 64 + oc;
    *(us8_t*)dst = v0;
    *(us8_t*)(dst + 8) = v1;
  }
}

// ---------------- proj GEMM -> d_out (f32) ----------------
__global__ __launch_bounds__(256) void k_mfma_proj(
    const unsigned short* __restrict__ Wb, const unsigned short* __restrict__ yT,
    float* __restrict__ out)
{
  __shared__ unsigned short As[8192], Bs[8192];
  const int bo = blockIdx.x;                  // 0..1
  const int s0 = blockIdx.y * 128;
  const int b  = blockIdx.z;
  f4_t acc[4][4];
  #pragma unroll
  for (int mi = 0; mi < 4; mi++)
    #pragma unroll
    for (int ni = 0; ni < 4; ni++) acc[mi][ni] = (f4_t)0.f;
  gemm_core_b<128>(Wb, bo * 128, yT + ((size_t)b * THW_ + s0) * 256, As, Bs, acc);
  const int lane = threadIdx.x & 63, wv = threadIdx.x >> 6;
  const int wm = wv >> 1, wn = wv & 1;
  size_t obase = (size_t)(b * C_) * THW_;
  #pragma unroll
  for (int mi = 0; mi < 4; mi++)
    #pragma unroll
    for (int ni = 0; ni < 4; ni++)
      #pragma unroll
      for (int r = 0; r < 4; r++){
        int o = bo * 128 + wm * 64 + mi * 16 + (lane >> 4) * 4 + r;
        int s = s0 + wn * 64 + ni * 16 + (lane & 15);
        out[obase + (size_t)o * THW_ + s] = acc[mi][ni][r];
      }
}

// ---------------- mean over (H,W): qg[b,c,t] (q is f16) ----------------
__global__ __launch_bounds__(256) void k_mean_hw(const __half* __restrict__ q, float* __restrict__ qg){
  int bct = blockIdx.x;
  const __half2* p = (const __half2*)(q + (size_t)bct * HW_);
  __half2 v0 = p[threadIdx.x * 2], v1 = p[threadIdx.x * 2 + 1];
  float sum = __low2float(v0) + __high2float(v0) + __low2float(v1) + __high2float(v1);
  #pragma unroll
  for (int off = 32; off; off >>= 1) sum += __shfl_down(sum, off);
  __shared__ float red[4];
  int lane = threadIdx.x & 63, w = threadIdx.x >> 6;
  if (lane == 0) red[w] = sum;
  __syncthreads();
  if (threadIdx.x == 0) qg[bct] = (red[0] + red[1] + red[2] + red[3]) * (1.f / 1024.f);
}

// ---------------- mix pre: h = gelu(pre_w @ qg + pre_b) ----------------
__global__ __launch_bounds__(256) void k_mix_pre(const float* __restrict__ preW, const float* __restrict__ preB,
    const float* __restrict__ qg, float* __restrict__ hbuf){
  int b = blockIdx.x >> 5, t = blockIdx.x & 31;
  int o = threadIdx.x;
  __shared__ float qgl[256];
  qgl[o] = qg[((size_t)(b * C_ + o)) * T_ + t];
  __syncthreads();
  float a = preB[o];
  for (int c = 0; c < C_; c++) a = fmaf(preW[o * C_ + c], qgl[c], a);
  float g = 0.5f * a * (1.f + erff(a * 0.70710678118f));
  hbuf[((size_t)(b * C_ + o)) * T_ + t] = g;
}

// ---------------- mix logits + softmax over m ----------------
__global__ __launch_bounds__(256) void k_mix_alpha(const float* __restrict__ cw, const float* __restrict__ cb,
    const float* __restrict__ hbuf, float* __restrict__ alpha){
  int b = blockIdx.x >> 5, t = blockIdx.x & 31;
  int c = threadIdx.x;
  float hv[3];
  #pragma unroll
  for (int j = 0; j < 3; j++){
    int tt = t - 2 + j;
    hv[j] = (tt >= 0) ? hbuf[((size_t)(b * C_ + c)) * T_ + tt] : 0.f;
  }
  float p[3];
  #pragma unroll
  for (int m = 0; m < 3; m++){
    const float* w = cw + ((size_t)m * C_ + c) * 3;
    p[m] = w[0] * hv[0] + w[1] * hv[1] + w[2] * hv[2];
  }
  #pragma unroll
  for (int m = 0; m < 3; m++){
    #pragma unroll
    for (int off = 32; off; off >>= 1) p[m] += __shfl_down(p[m], off);
  }
  __shared__ float red[3][4];
  int lane = threadIdx.x & 63, w = threadIdx.x >> 6;
  if (lane == 0){ red[0][w] = p[0]; red[1][w] = p[1]; red[2][w] = p[2]; }
  __syncthreads();
  if (threadIdx.x == 0){
    float lg[3];
    #pragma unroll
    for (int m = 0; m < 3; m++) lg[m] = red[m][0] + red[m][1] + red[m][2] + red[m][3] + cb[m];
    float mx = fmaxf(lg[0], fmaxf(lg[1], lg[2]));
    float e0 = __expf(lg[0] - mx), e1 = __expf(lg[1] - mx), e2 = __expf(lg[2] - mx);
    float r = 1.f / (e0 + e1 + e2);
    alpha[((size_t)(b * 3 + 0)) * T_ + t] = e0 * r;
    alpha[((size_t)(b * 3 + 1)) * T_ + t] = e1 * r;
    alpha[((size_t)(b * 3 + 2)) * T_ + t] = e2 * r;
  }
}

// ---------------- alpha-mixed causal depthwise conv 3x3x3 (f16 in/out) ----------------
__global__ __launch_bounds__(256) void k_conv1(
    const __half* __restrict__ in_g, const float* __restrict__ bank,
    const float* __restrict__ alpha, __half* __restrict__ out)
{
  int bi = blockIdx.x;
  int c = bi & 255, t = (bi >> 8) & 31, b = bi >> 13;
  __shared__ float sIn[3 * 34 * 34];
  __shared__ float wmix[27];
  int tid = threadIdx.x;
  if (tid < 27){
    float sum = 0.f;
    #pragma unroll
    for (int m = 0; m < 3; m++)
      sum += alpha[((size_t)(b * 3 + m)) * T_ + t] * bank[((size_t)m * C_ + c) * 27 + tid];
    wmix[tid] = sum;
  }
  size_t cbase = ((size_t)(b * C_ + c)) * T_;
  for (int idx = tid; idx < 3 * 34 * 34; idx += 256){
    int tp = idx / 1156, rem = idx % 1156;
    int yy = rem / 34, xx = rem % 34;
    int tin = t - 2 + tp, y = yy - 1, x = xx - 1;
    bool ok = (tin >= 0) && (y >= 0) && (y < 32) && (x >= 0) && (x < 32);
    size_t g = ok ? ((cbase + tin) * HW_ + (size_t)y * 32 + x) : 0;
    sIn[idx] = ok ? __half2float(in_g[g]) : 0.f;
  }
  __syncthreads();
  int y = tid >> 3, x0 = (tid & 7) * 4;
  float a[4] = {0.f, 0.f, 0.f, 0.f};
  #pragma unroll
  for (int dt = 0; dt < 3; dt++){
    #pragma unroll
    for (int dy = 0; dy < 3; dy++){
      int rb = dt * 1156 + (y + dy) * 34 + x0;
      #pragma unroll
      for (int dx = 0; dx < 3; dx++){
        float wv = wmix[dt * 9 + dy * 3 + dx];
        #pragma unroll
        for (int p2 = 0; p2 < 4; p2++) a[p2] = fmaf(wv, sIn[rb + dx + p2], a[p2]);
      }
    }
  }
  size_t ob = (cbase + t) * HW_ + (size_t)y * 32 + x0;
  __half2 h01 = __halves2half2(__float2half(a[0]), __float2half(a[1]));
  __half2 h23 = __halves2half2(__float2half(a[2]), __float2half(a[3]));
  *reinterpret_cast<__half2*>(out + ob)     = h01;
  *reinterpret_cast<__half2*>(out + ob + 2) = h23;
}

// ---------------- axial attention via MFMA, one 32x32 sequence per wave ----------------
template<int AXIS>
__global__ __launch_bounds__(256) void k_attn(
    const __half* __restrict__ qg_, const __half* __restrict__ kg_,
    const __half* vg_, __half* ctx,            // may alias (AXIS=2 in-place)
    const float* __restrict__ cosT, const float* __restrict__ sinT)
{
  const int SS = (AXIS == 0) ? HW_ : (AXIS == 1) ? 32 : 1;
  const int GS = (AXIS == 2) ? 32 : 1;
  const int OS = (AXIS == 0) ? 32 : HW_;
  int id = blockIdx.x;
  int ggrp = (id >> 3) & 7;
  int rest = ((id >> 6) << 3) | (id & 7);
  int outer = rest & 31;
  int head = (rest >> 5) & 7;
  int b = rest >> 8;
  const size_t base = ((size_t)(b * C_ + head * 32)) * THW_ + (size_t)outer * OS + (size_t)(ggrp * 4) * GS;

  __shared__ __align__(16) unsigned short smem[15360];   // 30 KB
  const int tid = threadIdx.x;
  const unsigned short* qp = (const unsigned short*)qg_;
  const unsigned short* kp = (const unsigned short*)kg_;
  const unsigned short* vp = (const unsigned short*)vg_;

  for (int idx2 = tid; idx2 < 512; idx2 += 256){
    if (AXIS != 2){
      int i = idx2 & 31, u = idx2 >> 5;
      size_t glo = base + (size_t)u * THW_ + (size_t)i * SS;
      size_t ghi = glo + (size_t)16 * THW_;
      ushort4 ql = *(const ushort4*)(qp + glo), qh = *(const ushort4*)(qp + ghi);
      ushort4 kl = *(const ushort4*)(kp + glo), kh = *(const ushort4*)(kp + ghi);
      float cv = cosT[i * 16 + u], sv = sinT[i * 16 + u];
      const unsigned short qla[4] = {ql.x, ql.y, ql.z, ql.w}, qha[4] = {qh.x, qh.y, qh.z, qh.w};
      const unsigned short kla[4] = {kl.x, kl.y, kl.z, kl.w}, kha[4] = {kh.x, kh.y, kh.z, kh.w};
      #pragma unroll
      for (int g = 0; g < 4; g++){
        int rb = g * 2560 + i * 40;
        float a = h2f_u(qla[g]), b2 = h2f_u(qha[g]);
        smem[rb + u]      = f2h_u(a * cv - b2 * sv);
        smem[rb + u + 16] = f2h_u(fmaf(b2, cv, a * sv));
        a = h2f_u(kla[g]); b2 = h2f_u(kha[g]);
        smem[rb + 1280 + u]      = f2h_u(a * cv - b2 * sv);
        smem[rb + 1280 + u + 16] = f2h_u(fmaf(b2, cv, a * sv));
      }
    } else {
      int ii = (idx2 & 7) * 4, g = (idx2 >> 3) & 3, u = idx2 >> 5;
      size_t glo = base + (size_t)u * THW_ + (size_t)g * GS + ii;
      size_t ghi = glo + (size_t)16 * THW_;
      ushort4 ql = *(const ushort4*)(qp + glo), qh = *(const ushort4*)(qp + ghi);
      ushort4 kl = *(const ushort4*)(kp + glo), kh = *(const ushort4*)(kp + ghi);
      const unsigned short qla[4] = {ql.x, ql.y, ql.z, ql.w}, qha[4] = {qh.x, qh.y, qh.z, qh.w};
      const unsigned short kla[4] = {kl.x, kl.y, kl.z, kl.w}, kha[4] = {kh.x, kh.y, kh.z, kh.w};
      #pragma unroll
      for (int p2 = 0; p2 < 4; p2++){
        int i = ii + p2;
        int rb = g * 2560 + i * 40;
        float cv = cosT[i * 16 + u], sv = sinT[i * 16 + u];
        float a = h2f_u(qla[p2]), b2 = h2f_u(qha[p2]);
        smem[rb + u]      = f2h_u(a * cv - b2 * sv);
        smem[rb + u + 16] = f2h_u(fmaf(b2, cv, a * sv));
        a = h2f_u(kla[p2]); b2 = h2f_u(kha[p2]);
        smem[rb + 1280 + u]      = f2h_u(a * cv - b2 * sv);
        smem[rb + 1280 + u + 16] = f2h_u(fmaf(b2, cv, a * sv));
      }
    }
  }
  for (int idx2 = tid; idx2 < 1024; idx2 += 256){
    if (AXIS != 2){
      int i = idx2 & 31, f = idx2 >> 5;
      size_t go = base + (size_t)f * THW_ + (size_t)i * SS;
      ushort4 vv = *(const ushort4*)(vp + go);
      const unsigned short va[4] = {vv.x, vv.y, vv.z, vv.w};
      #pragma unroll
      for (int g = 0; g < 4; g++) smem[10240 + g * 1280 + f * 40 + i] = va[g];
    } else {
      int ii = (idx2 & 7) * 4, g = (idx2 >> 3) & 3, f = idx2 >> 5;
      size_t go = base + (size_t)f * THW_ + (size_t)g * GS + ii;
      ushort4 vv = *(const ushort4*)(vp + go);
      const unsigned short va[4] = {vv.x, vv.y, vv.z, vv.w};
      #pragma unroll
      for (int p2 = 0; p2 < 4; p2++) smem[10240 + g * 1280 + f * 40 + ii + p2] = va[p2];
    }
  }
  __syncthreads();

  const int lane = tid & 63;
  const int seq = tid >> 6;
  const int m = lane & 15, kg = lane >> 4;
  const int sq = seq * 2560;

  h8_t aQ[2], bK[2], bV[2];
  #pragma unroll
  for (int t2 = 0; t2 < 2; t2++){
    aQ[t2] = *(const h8_t*)&smem[sq + (t2 * 16 + m) * 40 + kg * 8];
    bK[t2] = *(const h8_t*)&smem[sq + 1280 + (t2 * 16 + m) * 40 + kg * 8];
    bV[t2] = *(const h8_t*)&smem[10240 + seq * 1280 + (t2 * 16 + m) * 40 + kg * 8];
  }

  f4_t st[2][2];
  #pragma unroll
  for (int tk = 0; tk < 2; tk++)
    #pragma unroll
    for (int tq = 0; tq < 2; tq++){
      st[tk][tq] = (f4_t)0.f;
      st[tk][tq] = __builtin_amdgcn_mfma_f32_16x16x32_f16(bK[tk], aQ[tq], st[tk][tq], 0, 0, 0);
    }

  u32 pkk[2][2][2];             // [tq][tk][pair]
  #pragma unroll
  for (int tq = 0; tq < 2; tq++){
    const int i = tq * 16 + m;
    float e[2][4];
    float mx = -3.0e38f;
    #pragma unroll
    for (int tk = 0; tk < 2; tk++)
      #pragma unroll
      for (int r = 0; r < 4; r++){
        float s = st[tk][tq][r] * 0.17677669529663687f;
        if (AXIS == 0 && (tk * 16 + kg * 4 + r) > i) s = -1e30f;
        e[tk][r] = s;
        mx = fmaxf(mx, s);
      }
    mx = fmaxf(mx, __shfl_xor(mx, 16));
    mx = fmaxf(mx, __shfl_xor(mx, 32));
    float sum = 0.f;
    #pragma unroll
    for (int tk = 0; tk < 2; tk++)
      #pragma unroll
      for (int r = 0; r < 4; r++){
        e[tk][r] = __expf(e[tk][r] - mx);
        sum += e[tk][r];
      }
    sum += __shfl_xor(sum, 16);
    sum += __shfl_xor(sum, 32);
    float rinv = 1.f / sum;
    #pragma unroll
    for (int tk = 0; tk < 2; tk++){
      pkk[tq][tk][0] = pkrtz(e[tk][0] * rinv, e[tk][1] * rinv);
      pkk[tq][tk][1] = pkrtz(e[tk][2] * rinv, e[tk][3] * rinv);
    }
  }

  h8_t aP[2];
  #pragma unroll
  for (int tq = 0; tq < 2; tq++){
    union { u32 w[4]; h8_t h; } uu;
    #pragma unroll
    for (int w = 0; w < 4; w++){
      int srcLane = ((kg & 1) * 2 + (w >> 1)) * 16 + m;
      u32 v0 = __shfl(pkk[tq][0][w & 1], srcLane);
      u32 v1 = __shfl(pkk[tq][1][w & 1], srcLane);
      uu.w[w] = (kg >= 2) ? v1 : v0;
    }
    aP[tq] = uu.h;
  }

  f4_t o_[2][2];
  #pragma unroll
  for (int tq = 0; tq < 2; tq++)
    #pragma unroll
    for (int td = 0; td < 2; td++){
      o_[tq][td] = (f4_t)0.f;
      o_[tq][td] = __builtin_amdgcn_mfma_f32_16x16x32_f16(aP[tq], bV[td], o_[tq][td], 0, 0, 0);
    }

  __syncthreads();

  #pragma unroll
  for (int tq = 0; tq < 2; tq++)
    #pragma unroll
    for (int td = 0; td < 2; td++)
      #pragma unroll
      for (int r = 0; r < 4; r++){
        int i = tq * 16 + kg * 4 + r, d = td * 16 + m;
        if (AXIS != 2){
          int a4 = (((i * 32 + d) << 2) ^ (kg << 2)) + seq;
          smem[a4] = f2h_u(o_[tq][td][r]);
        } else {
          smem[seq * 1152 + d * 36 + (i ^ ((d & 3) << 2))] = f2h_u(o_[tq][td][r]);
        }
      }
  __syncthreads();

  for (int idx2 = tid; idx2 < 1024; idx2 += 256){
    if (AXIS != 2){
      int i2 = idx2 & 31, f = idx2 >> 5;
      int a4 = ((i2 * 32 + f) << 2) ^ ((((i2 >> 2) & 3)) << 2);
      ushort4 ov = *(const ushort4*)&smem[a4];
      size_t go = base + (size_t)f * THW_ + (size_t)i2 * SS;
      *(ushort4*)((unsigned short*)ctx + go) = ov;
    } else {
      int ii = (idx2 & 7) * 4, g2 = (idx2 >> 3) & 3, f = idx2 >> 5;
      ushort4 ov = *(const ushort4*)&smem[g2 * 1152 + f * 36 + (ii ^ ((f & 3) << 2))];
      size_t go = base + (size_t)f * THW_ + (size_t)g2 * GS + ii;
      *(ushort4*)((unsigned short*)ctx + go) = ov;
    }
  }
}

extern "C" void kernel_launch(void* const* d_in, const int* in_sizes, int n_in,
                              void* d_out, int out_size, void* d_ws, size_t ws_size,
                              hipStream_t stream)
{
  (void)in_sizes; (void)n_in; (void)out_size; (void)ws_size;
  const float* x       = (const float*)d_in[0];
  const float* w_qkv   = (const float*)d_in[1];
  const float* wk_bank = (const float*)d_in[2];
  const float* wv_bank = (const float*)d_in[3];
  const float* pre_w   = (const float*)d_in[4];
  const float* pre_b   = (const float*)d_in[5];
  const float* cw      = (const float*)d_in[6];
  const float* cb      = (const float*)d_in[7];
  const float* gate_w  = (const float*)d_in[8];
  const float* gate_b  = (const float*)d_in[9];
  const float* proj_w  = (const float*)d_in[10];

  const size_t SZ = (size_t)B_ * C_ * THW_;           // 16,777,216 elems
  __half* hb = (__half*)d_ws;                         // 32MB slots
  unsigned short* xT  = (unsigned short*)(hb + 0 * SZ);  // bf16, alive to gate
  __half* qH   = hb + 1 * SZ;                         // q
  __half* kH   = hb + 2 * SZ;                         // k -> ctx_t
  __half* vH   = hb + 3 * SZ;                         // v -> ctx_h
  __half* koH  = hb + 4 * SZ;                         // k_out -> yT(bf16)
  __half* voH  = hb + 5 * SZ;                         // v_out -> ctx_w (in-place)
  __half* ctxtH = kH;
  __half* ctxhH = vH;
  unsigned short* yT = (unsigned short*)koH;          // over dead k_out
  float* sm    = (float*)(hb + 6 * SZ);               // smalls
  float* qg    = sm;                                  // 16384
  float* hbuf  = qg + 16384;                          // 16384
  float* alpha = hbuf + 16384;                        // 192
  float* cosT  = alpha + 192;                         // 512
  float* sinT  = cosT + 512;                          // 512
  unsigned short* wB = (unsigned short*)(sinT + 512); // 1792*256 bf16 (896 KB)
  unsigned short* wBq = wB;                           // [768][256]
  unsigned short* wBg = wB + 768 * 256;               // [768][256]
  unsigned short* wBp = wB + 1536 * 256;              // [256][256]

  k_rope_table<<<1, 512, 0, stream>>>(cosT, sinT);
  k_wcvt<<<1792, 256, 0, stream>>>(w_qkv, gate_w, proj_w, wB);
  k_transpose_cvt<float><<<dim3(512, 4, 2), 256, 0, stream>>>(x, xT);

  k_mfma_qkv<<<dim3(6, 256, 2), 256, 0, stream>>>(wBq, xT, qH, kH, vH);

  k_mean_hw<<<16384, 256, 0, stream>>>(qH, qg);
  k_mix_pre<<<64, 256, 0, stream>>>(pre_w, pre_b, qg, hbuf);
  k_mix_alpha<<<64, 256, 0, stream>>>(cw, cb, hbuf, alpha);

  k_conv1<<<16384, 256, 0, stream>>>(kH, wk_bank, alpha, koH);   // k_out
  k_conv1<<<16384, 256, 0, stream>>>(vH, wv_bank, alpha, voH);   // v_out

  k_attn<0><<<4096, 256, 0, stream>>>(qH, koH, voH, ctxtH, cosT, sinT); // ctx_t (k dead)
  k_attn<1><<<4096, 256, 0, stream>>>(qH, koH, voH, ctxhH, cosT, sinT); // ctx_h (v dead)
  k_attn<2><<<4096, 256, 0, stream>>>(qH, koH, voH, voH,   cosT, sinT); // ctx_w in-place

  k_mfma_gate2<<<dim3(4, 512, 2), 256, 0, stream>>>(wBg, xT, gate_b,
                                                    ctxtH, ctxhH, voH, yT); // yT over dead k_out
  k_mfma_proj<<<dim3(2, 256, 2), 256, 0, stream>>>(wBp, yT, (float*)d_out);
}

// Round 10
// 462.266 us; speedup vs baseline: 4.6887x; 1.0843x over previous
//
#include <hip/hip_runtime.h>
#include <hip/hip_fp16.h>
#include <math.h>

#define B_   2
#define C_   256
#define T_   32
#define HW_  1024
#define THW_ 32768

using u32 = unsigned int;
typedef __attribute__((ext_vector_type(8))) short bf8_t;   // 8 bf16 in 4 VGPRs
typedef __attribute__((ext_vector_type(8))) unsigned short us8_t;
typedef __attribute__((ext_vector_type(8))) _Float16 h8_t; // 8 f16 in 4 VGPRs
typedef __attribute__((ext_vector_type(2))) __fp16 fp16v2; // builtin cvt_pkrtz return type
typedef __attribute__((ext_vector_type(4))) float f4_t;

static __device__ __forceinline__ unsigned short f2bf(float x){
  u32 u = __float_as_uint(x);
  u32 r = (u + 0x7FFF + ((u >> 16) & 1)) >> 16;   // RNE
  return (unsigned short)r;
}
static __device__ __forceinline__ float h2f_u(unsigned short u){
  union { __half h; unsigned short us; } cv; cv.us = u; return __half2float(cv.h);
}
static __device__ __forceinline__ unsigned short f2h_u(float f){
  union { __half h; unsigned short us; } cv; cv.h = __float2half(f); return cv.us;
}
static __device__ __forceinline__ u32 pkrtz(float a, float b){
  union { fp16v2 h; u32 w; } cv; cv.h = __builtin_amdgcn_cvt_pkrtz(a, b); return cv.w;
}
static __device__ __forceinline__ float ldf(const float* p){ return *p; }
static __device__ __forceinline__ float ldf(const __half* p){ return __half2float(*p); }

// ---------------- rope table ----------------
__global__ void k_rope_table(float* __restrict__ cosT, float* __restrict__ sinT){
  int tid = threadIdx.x;            // 512 threads, tid = i*16+u
  int i = tid >> 4, u = tid & 15;
  float invf = powf(10000.f, -(2.f * (float)u) / 32.f);
  float s, c;
  sincosf((float)i * invf, &s, &c);
  cosT[tid] = c;
  sinT[tid] = s;
}

// ---------------- weight cvt: stack w_qkv(768), gate_w(768), proj_w(256) as bf16 [1792][256] --
__global__ void k_wcvt(const float* __restrict__ w_qkv, const float* __restrict__ gate_w,
                       const float* __restrict__ proj_w, unsigned short* __restrict__ out){
  int row = blockIdx.x, c = threadIdx.x;
  const float* src = (row < 768) ? w_qkv + (size_t)row * 256
                   : (row < 1536) ? gate_w + (size_t)(row - 768) * 256
                                  : proj_w + (size_t)(row - 1536) * 256;
  out[(size_t)row * 256 + c] = f2bf(src[c]);
}

// ---------------- transpose+cvt: [b][256][THW] f32 -> bf16 [b][THW][256] ----------------
template<typename InT>
__global__ __launch_bounds__(256) void k_transpose_cvt(
    const InT* __restrict__ in, unsigned short* __restrict__ outT)
{
  __shared__ float tile[64][65];
  int s0 = blockIdx.x * 64;     // 512
  int c0 = blockIdx.y * 64;     // 4
  int b  = blockIdx.z;
  int tid = threadIdx.x;
  for (int idx = tid; idx < 4096; idx += 256){
    int c = idx >> 6, s = idx & 63;
    tile[c][s] = ldf(&in[((size_t)(b * C_ + c0 + c)) * THW_ + s0 + s]);
  }
  __syncthreads();
  for (int idx = tid; idx < 4096; idx += 256){
    int s = idx >> 6, c = idx & 63;
    outT[((size_t)b * THW_ + s0 + s) * 256 + c0 + c] = f2bf(tile[c][s]);
  }
}

// ---------------- MFMA GEMM core (bf16 A bank): 128xBN tile, K=256 ----------------
template<int BN>
static __device__ __forceinline__ void gemm_core_b(
    const unsigned short* __restrict__ A, int o0,
    const unsigned short* __restrict__ BT,   // pre-offset: + (b*THW + s0)*256
    unsigned short* As, unsigned short* Bs, f4_t acc[4][BN / 32])
{
  const int tid = threadIdx.x;
  const int lane = tid & 63, wv = tid >> 6;
  const int wm = wv >> 1, wn = wv & 1;
  const int m = lane & 15, kg = lane >> 4;
  const int arow = tid >> 1, aseg = (tid & 1) * 64;     // A: 128 rows, 2 thr/row, 64B each
  const int brow = (BN == 128) ? (tid >> 1) : (tid >> 2);
  const int bseg = (BN == 128) ? (tid & 1) * 64 : (tid & 3) * 32;
  for (int ks = 0; ks < 4; ks++){
    __syncthreads();                                    // protect prior reads
    {
      const unsigned short* ga = A + (size_t)(o0 + arow) * 256 + ks * 64 + aseg / 2;
      #pragma unroll
      for (int q2 = 0; q2 < 4; q2++){
        us8_t v = *(const us8_t*)(ga + q2 * 8);
        *(us8_t*)((char*)As + arow * 128 + ((aseg + q2 * 16) ^ ((arow & 7) << 4))) = v;
      }
      const unsigned short* gb = BT + (size_t)brow * 256 + ks * 64 + bseg / 2;
      #pragma unroll
      for (int q2 = 0; q2 < (BN == 128 ? 4 : 2); q2++){
        us8_t v = *(const us8_t*)(gb + q2 * 8);
        *(us8_t*)((char*)Bs + brow * 128 + ((bseg + q2 * 16) ^ ((brow & 7) << 4))) = v;
      }
    }
    __syncthreads();
    #pragma unroll
    for (int kk = 0; kk < 2; kk++){
      bf8_t af[4], bfr[BN / 32];
      #pragma unroll
      for (int mi = 0; mi < 4; mi++){
        int row = wm * 64 + mi * 16 + m;
        af[mi] = *(const bf8_t*)((const char*)As + row * 128 + ((kk * 64 + kg * 16) ^ ((row & 7) << 4)));
      }
      #pragma unroll
      for (int ni = 0; ni < BN / 32; ni++){
        int row = wn * (BN / 2) + ni * 16 + m;
        bfr[ni] = *(const bf8_t*)((const char*)Bs + row * 128 + ((kk * 64 + kg * 16) ^ ((row & 7) << 4)));
      }
      #pragma unroll
      for (int mi = 0; mi < 4; mi++)
        #pragma unroll
        for (int ni = 0; ni < BN / 32; ni++)
          acc[mi][ni] = __builtin_amdgcn_mfma_f32_16x16x32_bf16(af[mi], bfr[ni], acc[mi][ni], 0, 0, 0);
    }
  }
}

// ---------------- qkv GEMM: Wq(bf16)[768][256] @ x -> q,k,v (f16) ----------------
__global__ __launch_bounds__(256) void k_mfma_qkv(
    const unsigned short* __restrict__ Wb, const unsigned short* __restrict__ xT,
    __half* __restrict__ q, __half* __restrict__ k, __half* __restrict__ v)
{
  __shared__ unsigned short As[8192], Bs[8192];
  const int bo = blockIdx.x;                  // 0..5
  const int s0 = blockIdx.y * 128;            // 256
  const int b  = blockIdx.z;
  f4_t acc[4][4];
  #pragma unroll
  for (int mi = 0; mi < 4; mi++)
    #pragma unroll
    for (int ni = 0; ni < 4; ni++) acc[mi][ni] = (f4_t)0.f;
  gemm_core_b<128>(Wb, bo * 128, xT + ((size_t)b * THW_ + s0) * 256, As, Bs, acc);
  __half* outp = (bo < 2) ? q : (bo < 4) ? k : v;
  const int ro = (bo & 1) * 128;
  const int lane = threadIdx.x & 63, wv = threadIdx.x >> 6;
  const int wm = wv >> 1, wn = wv & 1;
  size_t obase = (size_t)(b * C_) * THW_;
  #pragma unroll
  for (int mi = 0; mi < 4; mi++)
    #pragma unroll
    for (int ni = 0; ni < 4; ni++)
      #pragma unroll
      for (int r = 0; r < 4; r++){
        int o = ro + wm * 64 + mi * 16 + (lane >> 4) * 4 + r;
        int s = s0 + wn * 64 + ni * 16 + (lane & 15);
        outp[obase + (size_t)o * THW_ + s] = __float2half(acc[mi][ni][r]);
      }
}

// ---------------- gate GEMM + sigmoid + combine, 3 slices interleaved, yT(bf16) direct ------
__global__ __launch_bounds__(256) void k_mfma_gate2(
    const unsigned short* __restrict__ Wb,   // bf16 gate bank [768][256]
    const unsigned short* __restrict__ xT,
    const float* __restrict__ gb,
    const __half* __restrict__ ctx_t, const __half* __restrict__ ctx_h,
    const __half* __restrict__ ctx_w,
    unsigned short* __restrict__ yT)         // bf16 [b][THW][256]
{
  __shared__ unsigned short As3[12288];
  __shared__ unsigned short Bs[4096];
  const int bo = blockIdx.x;                  // 0..3
  const int s0 = blockIdx.y * 64;
  const int b  = blockIdx.z;
  const int tid = threadIdx.x;
  const int lane = tid & 63, wv = tid >> 6;
  const int wm = wv >> 1, wn = wv & 1;
  const int m = lane & 15, kg = lane >> 4;
  const unsigned short* xbase = xT + ((size_t)b * THW_ + s0) * 256;

  f4_t acc[3][2][2];
  #pragma unroll
  for (int sl = 0; sl < 3; sl++)
    #pragma unroll
    for (int mi = 0; mi < 2; mi++)
      #pragma unroll
      for (int ni = 0; ni < 2; ni++) acc[sl][mi][ni] = (f4_t)0.f;

  for (int ks = 0; ks < 4; ks++){
    __syncthreads();
    #pragma unroll
    for (int rep = 0; rep < 2; rep++){
      int idx = rep * 256 + tid;              // 0..511
      int row = idx >> 3, seg = idx & 7;
      us8_t v = *(const us8_t*)(xbase + (size_t)row * 256 + ks * 64 + seg * 8);
      *(us8_t*)((char*)Bs + row * 128 + ((seg * 16) ^ ((row & 7) << 4))) = v;
    }
    #pragma unroll
    for (int sl = 0; sl < 3; sl++){
      #pragma unroll
      for (int rep = 0; rep < 2; rep++){
        int idx = rep * 256 + tid;
        int row = idx >> 3, seg = idx & 7;
        us8_t v = *(const us8_t*)(Wb + (size_t)(sl * 256 + bo * 64 + row) * 256 + ks * 64 + seg * 8);
        *(us8_t*)((char*)As3 + sl * 8192 + row * 128 + ((seg * 16) ^ ((row & 7) << 4))) = v;
      }
    }
    __syncthreads();
    #pragma unroll
    for (int kk = 0; kk < 2; kk++){
      bf8_t bfr[2], af[3][2];
      #pragma unroll
      for (int ni = 0; ni < 2; ni++){
        int row = wn * 32 + ni * 16 + m;
        bfr[ni] = *(const bf8_t*)((const char*)Bs + row * 128 + ((kk * 64 + kg * 16) ^ ((row & 7) << 4)));
      }
      #pragma unroll
      for (int sl = 0; sl < 3; sl++)
        #pragma unroll
        for (int mi = 0; mi < 2; mi++){
          int row = wm * 32 + mi * 16 + m;
          af[sl][mi] = *(const bf8_t*)((const char*)As3 + sl * 8192 + row * 128 + ((kk * 64 + kg * 16) ^ ((row & 7) << 4)));
        }
      #pragma unroll
      for (int sl = 0; sl < 3; sl++)
        #pragma unroll
        for (int mi = 0; mi < 2; mi++)
          #pragma unroll
          for (int ni = 0; ni < 2; ni++)
            acc[sl][mi][ni] = __builtin_amdgcn_mfma_f32_16x16x32_bf16(af[sl][mi], bfr[ni], acc[sl][mi][ni], 0, 0, 0);
    }
  }

  const size_t obase = (size_t)(b * C_) * THW_;
  f4_t yacc[2][2];
  #pragma unroll
  for (int mi = 0; mi < 2; mi++)
    #pragma unroll
    for (int ni = 0; ni < 2; ni++) yacc[mi][ni] = (f4_t)0.f;
  #pragma unroll
  for (int sl = 0; sl < 3; sl++){
    const __half* ctx = (sl == 0) ? ctx_t : (sl == 1) ? ctx_h : ctx_w;
    #pragma unroll
    for (int mi = 0; mi < 2; mi++)
      #pragma unroll
      for (int ni = 0; ni < 2; ni++)
        #pragma unroll
        for (int r = 0; r < 4; r++){
          int ol = wm * 32 + mi * 16 + kg * 4 + r;
          int s  = s0 + wn * 32 + ni * 16 + m;
          float lg = acc[sl][mi][ni][r] + gb[sl * 256 + bo * 64 + ol];
          float g = __builtin_amdgcn_rcpf(1.f + __expf(-lg));
          yacc[mi][ni][r] += g * __half2float(ctx[obase + (size_t)(bo * 64 + ol) * THW_ + s]);
        }
  }

  __syncthreads();
  unsigned short* tile = As3;
  #pragma unroll
  for (int mi = 0; mi < 2; mi++)
    #pragma unroll
    for (int ni = 0; ni < 2; ni++){
      int ol = wm * 32 + mi * 16 + kg * 4;
      int sl2 = wn * 32 + ni * 16 + m;
      ushort4 w4;
      w4.x = f2bf(yacc[mi][ni][0]);
      w4.y = f2bf(yacc[mi][ni][1]);
      w4.z = f2bf(yacc[mi][ni][2]);
      w4.w = f2bf(yacc[mi][ni][3]);
      *(ushort4*)&tile[sl2 * 72 + ol] = w4;
    }
  __syncthreads();
  {
    int sr = tid >> 2, oc = (tid & 3) * 16;
    us8_t v0 = *(const us8_t*)&tile[sr * 72 + oc];
    us8_t v1 = *(const us8_t*)&tile[sr * 72 + oc + 8];
    unsigned short* dst = yT + ((size_t)b * THW_ + s0 + sr) * 256 + bo * 64 + oc;
    *(us8_t*)dst = v0;
    *(us8_t*)(dst + 8) = v1;
  }
}

// ---------------- proj GEMM -> d_out (f32) ----------------
__global__ __launch_bounds__(256) void k_mfma_proj(
    const unsigned short* __restrict__ Wb, const unsigned short* __restrict__ yT,
    float* __restrict__ out)
{
  __shared__ unsigned short As[8192], Bs[8192];
  const int bo = blockIdx.x;                  // 0..1
  const int s0 = blockIdx.y * 128;
  const int b  = blockIdx.z;
  f4_t acc[4][4];
  #pragma unroll
  for (int mi = 0; mi < 4; mi++)
    #pragma unroll
    for (int ni = 0; ni < 4; ni++) acc[mi][ni] = (f4_t)0.f;
  gemm_core_b<128>(Wb, bo * 128, yT + ((size_t)b * THW_ + s0) * 256, As, Bs, acc);
  const int lane = threadIdx.x & 63, wv = threadIdx.x >> 6;
  const int wm = wv >> 1, wn = wv & 1;
  size_t obase = (size_t)(b * C_) * THW_;
  #pragma unroll
  for (int mi = 0; mi < 4; mi++)
    #pragma unroll
    for (int ni = 0; ni < 4; ni++)
      #pragma unroll
      for (int r = 0; r < 4; r++){
        int o = bo * 128 + wm * 64 + mi * 16 + (lane >> 4) * 4 + r;
        int s = s0 + wn * 64 + ni * 16 + (lane & 15);
        out[obase + (size_t)o * THW_ + s] = acc[mi][ni][r];
      }
}

// ---------------- mean over (H,W): qg[b,c,t] (q is f16) ----------------
__global__ __launch_bounds__(256) void k_mean_hw(const __half* __restrict__ q, float* __restrict__ qg){
  int bct = blockIdx.x;
  const __half2* p = (const __half2*)(q + (size_t)bct * HW_);
  __half2 v0 = p[threadIdx.x * 2], v1 = p[threadIdx.x * 2 + 1];
  float sum = __low2float(v0) + __high2float(v0) + __low2float(v1) + __high2float(v1);
  #pragma unroll
  for (int off = 32; off; off >>= 1) sum += __shfl_down(sum, off);
  __shared__ float red[4];
  int lane = threadIdx.x & 63, w = threadIdx.x >> 6;
  if (lane == 0) red[w] = sum;
  __syncthreads();
  if (threadIdx.x == 0) qg[bct] = (red[0] + red[1] + red[2] + red[3]) * (1.f / 1024.f);
}

// ---------------- mix pre: h = gelu(pre_w @ qg + pre_b) ----------------
__global__ __launch_bounds__(256) void k_mix_pre(const float* __restrict__ preW, const float* __restrict__ preB,
    const float* __restrict__ qg, float* __restrict__ hbuf){
  int b = blockIdx.x >> 5, t = blockIdx.x & 31;
  int o = threadIdx.x;
  __shared__ float qgl[256];
  qgl[o] = qg[((size_t)(b * C_ + o)) * T_ + t];
  __syncthreads();
  float a = preB[o];
  for (int c = 0; c < C_; c++) a = fmaf(preW[o * C_ + c], qgl[c], a);
  float g = 0.5f * a * (1.f + erff(a * 0.70710678118f));
  hbuf[((size_t)(b * C_ + o)) * T_ + t] = g;
}

// ---------------- mix logits + softmax over m ----------------
__global__ __launch_bounds__(256) void k_mix_alpha(const float* __restrict__ cw, const float* __restrict__ cb,
    const float* __restrict__ hbuf, float* __restrict__ alpha){
  int b = blockIdx.x >> 5, t = blockIdx.x & 31;
  int c = threadIdx.x;
  float hv[3];
  #pragma unroll
  for (int j = 0; j < 3; j++){
    int tt = t - 2 + j;
    hv[j] = (tt >= 0) ? hbuf[((size_t)(b * C_ + c)) * T_ + tt] : 0.f;
  }
  float p[3];
  #pragma unroll
  for (int m = 0; m < 3; m++){
    const float* w = cw + ((size_t)m * C_ + c) * 3;
    p[m] = w[0] * hv[0] + w[1] * hv[1] + w[2] * hv[2];
  }
  #pragma unroll
  for (int m = 0; m < 3; m++){
    #pragma unroll
    for (int off = 32; off; off >>= 1) p[m] += __shfl_down(p[m], off);
  }
  __shared__ float red[3][4];
  int lane = threadIdx.x & 63, w = threadIdx.x >> 6;
  if (lane == 0){ red[0][w] = p[0]; red[1][w] = p[1]; red[2][w] = p[2]; }
  __syncthreads();
  if (threadIdx.x == 0){
    float lg[3];
    #pragma unroll
    for (int m = 0; m < 3; m++) lg[m] = red[m][0] + red[m][1] + red[m][2] + red[m][3] + cb[m];
    float mx = fmaxf(lg[0], fmaxf(lg[1], lg[2]));
    float e0 = __expf(lg[0] - mx), e1 = __expf(lg[1] - mx), e2 = __expf(lg[2] - mx);
    float r = 1.f / (e0 + e1 + e2);
    alpha[((size_t)(b * 3 + 0)) * T_ + t] = e0 * r;
    alpha[((size_t)(b * 3 + 1)) * T_ + t] = e1 * r;
    alpha[((size_t)(b * 3 + 2)) * T_ + t] = e2 * r;
  }
}

// ---------------- alpha-mixed causal depthwise conv 3x3x3, k AND v in one grid ----------------
__global__ __launch_bounds__(256) void k_conv_both(
    const __half* __restrict__ kin, const __half* __restrict__ vin,
    const float* __restrict__ wkb, const float* __restrict__ wvb,
    const float* __restrict__ alpha,
    __half* __restrict__ kout, __half* __restrict__ vout)
{
  int bi = blockIdx.x;
  int which = bi >> 14;
  int rest = bi & 16383;
  int c = rest & 255, t = (rest >> 8) & 31, b = (rest >> 13) & 1;
  const __half* in_g = which ? vin : kin;
  const float* bank  = which ? wvb : wkb;
  __half* out        = which ? vout : kout;
  __shared__ float sIn[3 * 34 * 34];
  __shared__ float wmix[27];
  int tid = threadIdx.x;
  if (tid < 27){
    float sum = 0.f;
    #pragma unroll
    for (int m = 0; m < 3; m++)
      sum += alpha[((size_t)(b * 3 + m)) * T_ + t] * bank[((size_t)m * C_ + c) * 27 + tid];
    wmix[tid] = sum;
  }
  size_t cbase = ((size_t)(b * C_ + c)) * T_;
  for (int idx = tid; idx < 3 * 34 * 34; idx += 256){
    int tp = idx / 1156, rem = idx % 1156;
    int yy = rem / 34, xx = rem % 34;
    int tin = t - 2 + tp, y = yy - 1, x = xx - 1;
    bool ok = (tin >= 0) && (y >= 0) && (y < 32) && (x >= 0) && (x < 32);
    size_t g = ok ? ((cbase + tin) * HW_ + (size_t)y * 32 + x) : 0;
    sIn[idx] = ok ? __half2float(in_g[g]) : 0.f;
  }
  __syncthreads();
  int y = tid >> 3, x0 = (tid & 7) * 4;
  float a[4] = {0.f, 0.f, 0.f, 0.f};
  #pragma unroll
  for (int dt = 0; dt < 3; dt++){
    #pragma unroll
    for (int dy = 0; dy < 3; dy++){
      int rb = dt * 1156 + (y + dy) * 34 + x0;
      #pragma unroll
      for (int dx = 0; dx < 3; dx++){
        float wv = wmix[dt * 9 + dy * 3 + dx];
        #pragma unroll
        for (int p2 = 0; p2 < 4; p2++) a[p2] = fmaf(wv, sIn[rb + dx + p2], a[p2]);
      }
    }
  }
  size_t ob = (cbase + t) * HW_ + (size_t)y * 32 + x0;
  __half2 h01 = __halves2half2(__float2half(a[0]), __float2half(a[1]));
  __half2 h23 = __halves2half2(__float2half(a[2]), __float2half(a[3]));
  *reinterpret_cast<__half2*>(out + ob)     = h01;
  *reinterpret_cast<__half2*>(out + ob + 2) = h23;
}

// ---------------- axial attention body (MFMA), one 32x32 sequence per wave ----------------
// LDS (ushort idx, row stride 36 = 72B -> 2-way banks):
//   q[seq]: seq*2304 + i*36 + f ; k[seq]: +1152 ; v[seq]: 9216 + seq*1152 + d*36 + j
// O aliases q/k region after barrier (same formulas as r8).
template<int AXIS>
static __device__ __forceinline__ void attn_body(
    int id, unsigned short* smem,
    const unsigned short* __restrict__ qp, const unsigned short* __restrict__ kp,
    const unsigned short* __restrict__ vp, unsigned short* ctx,
    const float* __restrict__ cosT, const float* __restrict__ sinT)
{
  const int SS = (AXIS == 0) ? HW_ : (AXIS == 1) ? 32 : 1;
  const int GS = (AXIS == 2) ? 32 : 1;
  const int OS = (AXIS == 0) ? 32 : HW_;
  int ggrp = (id >> 3) & 7;
  int rest = ((id >> 6) << 3) | (id & 7);
  int outer = rest & 31;
  int head = (rest >> 5) & 7;
  int b = rest >> 8;
  const size_t base = ((size_t)(b * C_ + head * 32)) * THW_ + (size_t)outer * OS + (size_t)(ggrp * 4) * GS;
  const int tid = threadIdx.x;

  for (int idx2 = tid; idx2 < 512; idx2 += 256){
    if (AXIS != 2){
      int i = idx2 & 31, u = idx2 >> 5;
      size_t glo = base + (size_t)u * THW_ + (size_t)i * SS;
      size_t ghi = glo + (size_t)16 * THW_;
      ushort4 ql = *(const ushort4*)(qp + glo), qh = *(const ushort4*)(qp + ghi);
      ushort4 kl = *(const ushort4*)(kp + glo), kh = *(const ushort4*)(kp + ghi);
      float cv = cosT[i * 16 + u], sv = sinT[i * 16 + u];
      const unsigned short qla[4] = {ql.x, ql.y, ql.z, ql.w}, qha[4] = {qh.x, qh.y, qh.z, qh.w};
      const unsigned short kla[4] = {kl.x, kl.y, kl.z, kl.w}, kha[4] = {kh.x, kh.y, kh.z, kh.w};
      #pragma unroll
      for (int g = 0; g < 4; g++){
        int rb = g * 2304 + i * 36;
        float a = h2f_u(qla[g]), b2 = h2f_u(qha[g]);
        smem[rb + u]      = f2h_u(a * cv - b2 * sv);
        smem[rb + u + 16] = f2h_u(fmaf(b2, cv, a * sv));
        a = h2f_u(kla[g]); b2 = h2f_u(kha[g]);
        smem[rb + 1152 + u]      = f2h_u(a * cv - b2 * sv);
        smem[rb + 1152 + u + 16] = f2h_u(fmaf(b2, cv, a * sv));
      }
    } else {
      int ii = (idx2 & 7) * 4, g = (idx2 >> 3) & 3, u = idx2 >> 5;
      size_t glo = base + (size_t)u * THW_ + (size_t)g * GS + ii;
      size_t ghi = glo + (size_t)16 * THW_;
      ushort4 ql = *(const ushort4*)(qp + glo), qh = *(const ushort4*)(qp + ghi);
      ushort4 kl = *(const ushort4*)(kp + glo), kh = *(const ushort4*)(kp + ghi);
      const unsigned short qla[4] = {ql.x, ql.y, ql.z, ql.w}, qha[4] = {qh.x, qh.y, qh.z, qh.w};
      const unsigned short kla[4] = {kl.x, kl.y, kl.z, kl.w}, kha[4] = {kh.x, kh.y, kh.z, kh.w};
      #pragma unroll
      for (int p2 = 0; p2 < 4; p2++){
        int i = ii + p2;
        int rb = g * 2304 + i * 36;
        float cv = cosT[i * 16 + u], sv = sinT[i * 16 + u];
        float a = h2f_u(qla[p2]), b2 = h2f_u(qha[p2]);
        smem[rb + u]      = f2h_u(a * cv - b2 * sv);
        smem[rb + u + 16] = f2h_u(fmaf(b2, cv, a * sv));
        a = h2f_u(kla[p2]); b2 = h2f_u(kha[p2]);
        smem[rb + 1152 + u]      = f2h_u(a * cv - b2 * sv);
        smem[rb + 1152 + u + 16] = f2h_u(fmaf(b2, cv, a * sv));
      }
    }
  }
  for (int idx2 = tid; idx2 < 1024; idx2 += 256){
    if (AXIS != 2){
      int i = idx2 & 31, f = idx2 >> 5;
      size_t go = base + (size_t)f * THW_ + (size_t)i * SS;
      ushort4 vv = *(const ushort4*)(vp + go);
      const unsigned short va[4] = {vv.x, vv.y, vv.z, vv.w};
      #pragma unroll
      for (int g = 0; g < 4; g++) smem[9216 + g * 1152 + f * 36 + i] = va[g];
    } else {
      int ii = (idx2 & 7) * 4, g = (idx2 >> 3) & 3, f = idx2 >> 5;
      size_t go = base + (size_t)f * THW_ + (size_t)g * GS + ii;
      ushort4 vv = *(const ushort4*)(vp + go);
      const unsigned short va[4] = {vv.x, vv.y, vv.z, vv.w};
      #pragma unroll
      for (int p2 = 0; p2 < 4; p2++) smem[9216 + g * 1152 + f * 36 + ii + p2] = va[p2];
    }
  }
  __syncthreads();

  const int lane = tid & 63;
  const int seq = tid >> 6;
  const int m = lane & 15, kg = lane >> 4;
  const int sq = seq * 2304;

  h8_t aQ[2], bK[2], bV[2];
  #pragma unroll
  for (int t2 = 0; t2 < 2; t2++){
    union { ushort4 u4[2]; h8_t h; } uq, uk, uv;
    int rq = sq + (t2 * 16 + m) * 36 + kg * 8;
    uq.u4[0] = *(const ushort4*)&smem[rq];
    uq.u4[1] = *(const ushort4*)&smem[rq + 4];
    int rk = sq + 1152 + (t2 * 16 + m) * 36 + kg * 8;
    uk.u4[0] = *(const ushort4*)&smem[rk];
    uk.u4[1] = *(const ushort4*)&smem[rk + 4];
    int rv = 9216 + seq * 1152 + (t2 * 16 + m) * 36 + kg * 8;
    uv.u4[0] = *(const ushort4*)&smem[rv];
    uv.u4[1] = *(const ushort4*)&smem[rv + 4];
    aQ[t2] = uq.h; bK[t2] = uk.h; bV[t2] = uv.h;
  }

  f4_t st[2][2];
  #pragma unroll
  for (int tk = 0; tk < 2; tk++)
    #pragma unroll
    for (int tq = 0; tq < 2; tq++){
      st[tk][tq] = (f4_t)0.f;
      st[tk][tq] = __builtin_amdgcn_mfma_f32_16x16x32_f16(bK[tk], aQ[tq], st[tk][tq], 0, 0, 0);
    }

  u32 pkk[2][2][2];             // [tq][tk][pair]
  #pragma unroll
  for (int tq = 0; tq < 2; tq++){
    const int i = tq * 16 + m;
    float e[2][4];
    float mx = -3.0e38f;
    #pragma unroll
    for (int tk = 0; tk < 2; tk++)
      #pragma unroll
      for (int r = 0; r < 4; r++){
        float s = st[tk][tq][r] * 0.17677669529663687f;
        if (AXIS == 0 && (tk * 16 + kg * 4 + r) > i) s = -1e30f;
        e[tk][r] = s;
        mx = fmaxf(mx, s);
      }
    mx = fmaxf(mx, __shfl_xor(mx, 16));
    mx = fmaxf(mx, __shfl_xor(mx, 32));
    float sum = 0.f;
    #pragma unroll
    for (int tk = 0; tk < 2; tk++)
      #pragma unroll
      for (int r = 0; r < 4; r++){
        e[tk][r] = __expf(e[tk][r] - mx);
        sum += e[tk][r];
      }
    sum += __shfl_xor(sum, 16);
    sum += __shfl_xor(sum, 32);
    float rinv = 1.f / sum;
    #pragma unroll
    for (int tk = 0; tk < 2; tk++){
      pkk[tq][tk][0] = pkrtz(e[tk][0] * rinv, e[tk][1] * rinv);
      pkk[tq][tk][1] = pkrtz(e[tk][2] * rinv, e[tk][3] * rinv);
    }
  }

  h8_t aP[2];
  #pragma unroll
  for (int tq = 0; tq < 2; tq++){
    union { u32 w[4]; h8_t h; } uu;
    #pragma unroll
    for (int w = 0; w < 4; w++){
      int srcLane = ((kg & 1) * 2 + (w >> 1)) * 16 + m;
      u32 v0 = __shfl(pkk[tq][0][w & 1], srcLane);
      u32 v1 = __shfl(pkk[tq][1][w & 1], srcLane);
      uu.w[w] = (kg >= 2) ? v1 : v0;
    }
    aP[tq] = uu.h;
  }

  f4_t o_[2][2];
  #pragma unroll
  for (int tq = 0; tq < 2; tq++)
    #pragma unroll
    for (int td = 0; td < 2; td++){
      o_[tq][td] = (f4_t)0.f;
      o_[tq][td] = __builtin_amdgcn_mfma_f32_16x16x32_f16(aP[tq], bV[td], o_[tq][td], 0, 0, 0);
    }

  __syncthreads();   // all waves done reading q/k before O overwrites it

  #pragma unroll
  for (int tq = 0; tq < 2; tq++)
    #pragma unroll
    for (int td = 0; td < 2; td++)
      #pragma unroll
      for (int r = 0; r < 4; r++){
        int i = tq * 16 + kg * 4 + r, d = td * 16 + m;
        if (AXIS != 2){
          int a4 = (((i * 32 + d) << 2) ^ (kg << 2)) + seq;
          smem[a4] = f2h_u(o_[tq][td][r]);
        } else {
          smem[seq * 1152 + d * 36 + (i ^ ((d & 3) << 2))] = f2h_u(o_[tq][td][r]);
        }
      }
  __syncthreads();

  for (int idx2 = tid; idx2 < 1024; idx2 += 256){
    if (AXIS != 2){
      int i2 = idx2 & 31, f = idx2 >> 5;
      int a4 = ((i2 * 32 + f) << 2) ^ ((((i2 >> 2) & 3)) << 2);
      ushort4 ov = *(const ushort4*)&smem[a4];
      size_t go = base + (size_t)f * THW_ + (size_t)i2 * SS;
      *(ushort4*)(ctx + go) = ov;
    } else {
      int ii = (idx2 & 7) * 4, g2 = (idx2 >> 3) & 3, f = idx2 >> 5;
      ushort4 ov = *(const ushort4*)&smem[g2 * 1152 + f * 36 + (ii ^ ((f & 3) << 2))];
      size_t go = base + (size_t)f * THW_ + (size_t)g2 * GS + ii;
      *(ushort4*)(ctx + go) = ov;
    }
  }
}

// ---------------- fused attention dispatcher: all 3 axes in one grid (12288 blocks) --------
__global__ __launch_bounds__(256) void k_attn_all(
    const __half* __restrict__ qg_, const __half* __restrict__ kg_,
    const __half* __restrict__ vg_,
    __half* __restrict__ ctx_t, __half* __restrict__ ctx_h, __half* __restrict__ ctx_w,
    const float* __restrict__ cosT, const float* __restrict__ sinT)
{
  __shared__ __align__(16) unsigned short smem[13824];   // 27.6 KB
  int ax = blockIdx.x >> 12;
  int id = blockIdx.x & 4095;
  const unsigned short* qp = (const unsigned short*)qg_;
  const unsigned short* kp = (const unsigned short*)kg_;
  const unsigned short* vp = (const unsigned short*)vg_;
  if (ax == 0)      attn_body<0>(id, smem, qp, kp, vp, (unsigned short*)ctx_t, cosT, sinT);
  else if (ax == 1) attn_body<1>(id, smem, qp, kp, vp, (unsigned short*)ctx_h, cosT, sinT);
  else              attn_body<2>(id, smem, qp, kp, vp, (unsigned short*)ctx_w, cosT, sinT);
}

extern "C" void kernel_launch(void* const* d_in, const int* in_sizes, int n_in,
                              void* d_out, int out_size, void* d_ws, size_t ws_size,
                              hipStream_t stream)
{
  (void)in_sizes; (void)n_in; (void)out_size; (void)ws_size;
  const float* x       = (const float*)d_in[0];
  const float* w_qkv   = (const float*)d_in[1];
  const float* wk_bank = (const float*)d_in[2];
  const float* wv_bank = (const float*)d_in[3];
  const float* pre_w   = (const float*)d_in[4];
  const float* pre_b   = (const float*)d_in[5];
  const float* cw      = (const float*)d_in[6];
  const float* cb      = (const float*)d_in[7];
  const float* gate_w  = (const float*)d_in[8];
  const float* gate_b  = (const float*)d_in[9];
  const float* proj_w  = (const float*)d_in[10];

  const size_t SZ = (size_t)B_ * C_ * THW_;           // 16,777,216 elems
  __half* hb = (__half*)d_ws;                         // 32MB slots
  unsigned short* xT  = (unsigned short*)(hb + 0 * SZ);  // bf16, alive to gate
  __half* qH   = hb + 1 * SZ;                         // q
  __half* kH   = hb + 2 * SZ;                         // k -> ctx_t
  __half* vH   = hb + 3 * SZ;                         // v -> ctx_h
  __half* koH  = hb + 4 * SZ;                         // k_out -> yT(bf16)
  __half* voH  = hb + 5 * SZ;                         // v_out (stays valid)
  __half* ctxtH = kH;
  __half* ctxhH = vH;
  __half* ctxwH = (__half*)d_out;                     // ctx_w in d_out (dead until proj)
  unsigned short* yT = (unsigned short*)koH;          // over dead k_out
  float* sm    = (float*)(hb + 6 * SZ);               // smalls
  float* qg    = sm;                                  // 16384
  float* hbuf  = qg + 16384;                          // 16384
  float* alpha = hbuf + 16384;                        // 192
  float* cosT  = alpha + 192;                         // 512
  float* sinT  = cosT + 512;                          // 512
  unsigned short* wB = (unsigned short*)(sinT + 512); // 1792*256 bf16 (896 KB)
  unsigned short* wBq = wB;                           // [768][256]
  unsigned short* wBg = wB + 768 * 256;               // [768][256]
  unsigned short* wBp = wB + 1536 * 256;              // [256][256]

  k_rope_table<<<1, 512, 0, stream>>>(cosT, sinT);
  k_wcvt<<<1792, 256, 0, stream>>>(w_qkv, gate_w, proj_w, wB);
  k_transpose_cvt<float><<<dim3(512, 4, 2), 256, 0, stream>>>(x, xT);

  k_mfma_qkv<<<dim3(6, 256, 2), 256, 0, stream>>>(wBq, xT, qH, kH, vH);

  k_mean_hw<<<16384, 256, 0, stream>>>(qH, qg);
  k_mix_pre<<<64, 256, 0, stream>>>(pre_w, pre_b, qg, hbuf);
  k_mix_alpha<<<64, 256, 0, stream>>>(cw, cb, hbuf, alpha);

  k_conv_both<<<32768, 256, 0, stream>>>(kH, vH, wk_bank, wv_bank, alpha, koH, voH);

  k_attn_all<<<12288, 256, 0, stream>>>(qH, koH, voH, ctxtH, ctxhH, ctxwH, cosT, sinT);

  k_mfma_gate2<<<dim3(4, 512, 2), 256, 0, stream>>>(wBg, xT, gate_b,
                                                    ctxtH, ctxhH, ctxwH, yT); // yT over dead k_out
  k_mfma_proj<<<dim3(2, 256, 2), 256, 0, stream>>>(wBp, yT, (float*)d_out);
}

// Round 11
// 461.057 us; speedup vs baseline: 4.7010x; 1.0026x over previous
//
#include <hip/hip_runtime.h>
#include <hip/hip_fp16.h>
#include <math.h>

#define B_   2
#define C_   256
#define T_   32
#define HW_  1024
#define THW_ 32768

using u32 = unsigned int;
typedef __attribute__((ext_vector_type(8))) short bf8_t;   // 8 bf16 in 4 VGPRs
typedef __attribute__((ext_vector_type(8))) unsigned short us8_t;
typedef __attribute__((ext_vector_type(8))) _Float16 h8_t; // 8 f16 in 4 VGPRs
typedef __attribute__((ext_vector_type(2))) __fp16 fp16v2; // builtin cvt_pkrtz return type
typedef __attribute__((ext_vector_type(4))) float f4_t;

static __device__ __forceinline__ unsigned short f2bf(float x){
  u32 u = __float_as_uint(x);
  u32 r = (u + 0x7FFF + ((u >> 16) & 1)) >> 16;   // RNE
  return (unsigned short)r;
}
static __device__ __forceinline__ float h2f_u(unsigned short u){
  union { __half h; unsigned short us; } cv; cv.us = u; return __half2float(cv.h);
}
static __device__ __forceinline__ unsigned short f2h_u(float f){
  union { __half h; unsigned short us; } cv; cv.h = __float2half(f); return cv.us;
}
static __device__ __forceinline__ u32 pkrtz(float a, float b){
  union { fp16v2 h; u32 w; } cv; cv.h = __builtin_amdgcn_cvt_pkrtz(a, b); return cv.w;
}
static __device__ __forceinline__ float ldf(const float* p){ return *p; }
static __device__ __forceinline__ float ldf(const __half* p){ return __half2float(*p); }

// ---------------- rope table ----------------
__global__ void k_rope_table(float* __restrict__ cosT, float* __restrict__ sinT){
  int tid = threadIdx.x;            // 512 threads, tid = i*16+u
  int i = tid >> 4, u = tid & 15;
  float invf = powf(10000.f, -(2.f * (float)u) / 32.f);
  float s, c;
  sincosf((float)i * invf, &s, &c);
  cosT[tid] = c;
  sinT[tid] = s;
}

// ---------------- weight cvt: stack w_qkv(768), gate_w(768), proj_w(256) as bf16 [1792][256] --
__global__ void k_wcvt(const float* __restrict__ w_qkv, const float* __restrict__ gate_w,
                       const float* __restrict__ proj_w, unsigned short* __restrict__ out){
  int row = blockIdx.x, c = threadIdx.x;
  const float* src = (row < 768) ? w_qkv + (size_t)row * 256
                   : (row < 1536) ? gate_w + (size_t)(row - 768) * 256
                                  : proj_w + (size_t)(row - 1536) * 256;
  out[(size_t)row * 256 + c] = f2bf(src[c]);
}

// ---------------- transpose+cvt: [b][256][THW] f32 -> bf16 [b][THW][256] ----------------
template<typename InT>
__global__ __launch_bounds__(256) void k_transpose_cvt(
    const InT* __restrict__ in, unsigned short* __restrict__ outT)
{
  __shared__ float tile[64][65];
  int s0 = blockIdx.x * 64;     // 512
  int c0 = blockIdx.y * 64;     // 4
  int b  = blockIdx.z;
  int tid = threadIdx.x;
  for (int idx = tid; idx < 4096; idx += 256){
    int c = idx >> 6, s = idx & 63;
    tile[c][s] = ldf(&in[((size_t)(b * C_ + c0 + c)) * THW_ + s0 + s]);
  }
  __syncthreads();
  for (int idx = tid; idx < 4096; idx += 256){
    int s = idx >> 6, c = idx & 63;
    outT[((size_t)b * THW_ + s0 + s) * 256 + c0 + c] = f2bf(tile[c][s]);
  }
}

// ---------------- MFMA GEMM core (bf16 A bank): 128xBN tile, K=256 ----------------
template<int BN>
static __device__ __forceinline__ void gemm_core_b(
    const unsigned short* __restrict__ A, int o0,
    const unsigned short* __restrict__ BT,   // pre-offset: + (b*THW + s0)*256
    unsigned short* As, unsigned short* Bs, f4_t acc[4][BN / 32])
{
  const int tid = threadIdx.x;
  const int lane = tid & 63, wv = tid >> 6;
  const int wm = wv >> 1, wn = wv & 1;
  const int m = lane & 15, kg = lane >> 4;
  const int arow = tid >> 1, aseg = (tid & 1) * 64;     // A: 128 rows, 2 thr/row, 64B each
  const int brow = (BN == 128) ? (tid >> 1) : (tid >> 2);
  const int bseg = (BN == 128) ? (tid & 1) * 64 : (tid & 3) * 32;
  for (int ks = 0; ks < 4; ks++){
    __syncthreads();                                    // protect prior reads
    {
      const unsigned short* ga = A + (size_t)(o0 + arow) * 256 + ks * 64 + aseg / 2;
      #pragma unroll
      for (int q2 = 0; q2 < 4; q2++){
        us8_t v = *(const us8_t*)(ga + q2 * 8);
        *(us8_t*)((char*)As + arow * 128 + ((aseg + q2 * 16) ^ ((arow & 7) << 4))) = v;
      }
      const unsigned short* gb = BT + (size_t)brow * 256 + ks * 64 + bseg / 2;
      #pragma unroll
      for (int q2 = 0; q2 < (BN == 128 ? 4 : 2); q2++){
        us8_t v = *(const us8_t*)(gb + q2 * 8);
        *(us8_t*)((char*)Bs + brow * 128 + ((bseg + q2 * 16) ^ ((brow & 7) << 4))) = v;
      }
    }
    __syncthreads();
    #pragma unroll
    for (int kk = 0; kk < 2; kk++){
      bf8_t af[4], bfr[BN / 32];
      #pragma unroll
      for (int mi = 0; mi < 4; mi++){
        int row = wm * 64 + mi * 16 + m;
        af[mi] = *(const bf8_t*)((const char*)As + row * 128 + ((kk * 64 + kg * 16) ^ ((row & 7) << 4)));
      }
      #pragma unroll
      for (int ni = 0; ni < BN / 32; ni++){
        int row = wn * (BN / 2) + ni * 16 + m;
        bfr[ni] = *(const bf8_t*)((const char*)Bs + row * 128 + ((kk * 64 + kg * 16) ^ ((row & 7) << 4)));
      }
      #pragma unroll
      for (int mi = 0; mi < 4; mi++)
        #pragma unroll
        for (int ni = 0; ni < BN / 32; ni++)
          acc[mi][ni] = __builtin_amdgcn_mfma_f32_16x16x32_bf16(af[mi], bfr[ni], acc[mi][ni], 0, 0, 0);
    }
  }
}

// ---------------- qkv GEMM: Wq(bf16)[768][256] @ x -> q,k,v (f16) ----------------
__global__ __launch_bounds__(256) void k_mfma_qkv(
    const unsigned short* __restrict__ Wb, const unsigned short* __restrict__ xT,
    __half* __restrict__ q, __half* __restrict__ k, __half* __restrict__ v)
{
  __shared__ unsigned short As[8192], Bs[8192];
  const int bo = blockIdx.x;                  // 0..5
  const int s0 = blockIdx.y * 128;            // 256
  const int b  = blockIdx.z;
  f4_t acc[4][4];
  #pragma unroll
  for (int mi = 0; mi < 4; mi++)
    #pragma unroll
    for (int ni = 0; ni < 4; ni++) acc[mi][ni] = (f4_t)0.f;
  gemm_core_b<128>(Wb, bo * 128, xT + ((size_t)b * THW_ + s0) * 256, As, Bs, acc);
  __half* outp = (bo < 2) ? q : (bo < 4) ? k : v;
  const int ro = (bo & 1) * 128;
  const int lane = threadIdx.x & 63, wv = threadIdx.x >> 6;
  const int wm = wv >> 1, wn = wv & 1;
  size_t obase = (size_t)(b * C_) * THW_;
  #pragma unroll
  for (int mi = 0; mi < 4; mi++)
    #pragma unroll
    for (int ni = 0; ni < 4; ni++)
      #pragma unroll
      for (int r = 0; r < 4; r++){
        int o = ro + wm * 64 + mi * 16 + (lane >> 4) * 4 + r;
        int s = s0 + wn * 64 + ni * 16 + (lane & 15);
        outp[obase + (size_t)o * THW_ + s] = __float2half(acc[mi][ni][r]);
      }
}

// ---------------- gate GEMM + sigmoid + combine, 3 slices interleaved, yT(bf16) direct ------
__global__ __launch_bounds__(256) void k_mfma_gate2(
    const unsigned short* __restrict__ Wb,   // bf16 gate bank [768][256]
    const unsigned short* __restrict__ xT,
    const float* __restrict__ gb,
    const __half* __restrict__ ctx_t, const __half* __restrict__ ctx_h,
    const __half* __restrict__ ctx_w,
    unsigned short* __restrict__ yT)         // bf16 [b][THW][256]
{
  __shared__ unsigned short As3[12288];
  __shared__ unsigned short Bs[4096];
  const int bo = blockIdx.x;                  // 0..3
  const int s0 = blockIdx.y * 64;
  const int b  = blockIdx.z;
  const int tid = threadIdx.x;
  const int lane = tid & 63, wv = tid >> 6;
  const int wm = wv >> 1, wn = wv & 1;
  const int m = lane & 15, kg = lane >> 4;
  const unsigned short* xbase = xT + ((size_t)b * THW_ + s0) * 256;

  f4_t acc[3][2][2];
  #pragma unroll
  for (int sl = 0; sl < 3; sl++)
    #pragma unroll
    for (int mi = 0; mi < 2; mi++)
      #pragma unroll
      for (int ni = 0; ni < 2; ni++) acc[sl][mi][ni] = (f4_t)0.f;

  for (int ks = 0; ks < 4; ks++){
    __syncthreads();
    #pragma unroll
    for (int rep = 0; rep < 2; rep++){
      int idx = rep * 256 + tid;              // 0..511
      int row = idx >> 3, seg = idx & 7;
      us8_t v = *(const us8_t*)(xbase + (size_t)row * 256 + ks * 64 + seg * 8);
      *(us8_t*)((char*)Bs + row * 128 + ((seg * 16) ^ ((row & 7) << 4))) = v;
    }
    #pragma unroll
    for (int sl = 0; sl < 3; sl++){
      #pragma unroll
      for (int rep = 0; rep < 2; rep++){
        int idx = rep * 256 + tid;
        int row = idx >> 3, seg = idx & 7;
        us8_t v = *(const us8_t*)(Wb + (size_t)(sl * 256 + bo * 64 + row) * 256 + ks * 64 + seg * 8);
        *(us8_t*)((char*)As3 + sl * 8192 + row * 128 + ((seg * 16) ^ ((row & 7) << 4))) = v;
      }
    }
    __syncthreads();
    #pragma unroll
    for (int kk = 0; kk < 2; kk++){
      bf8_t bfr[2], af[3][2];
      #pragma unroll
      for (int ni = 0; ni < 2; ni++){
        int row = wn * 32 + ni * 16 + m;
        bfr[ni] = *(const bf8_t*)((const char*)Bs + row * 128 + ((kk * 64 + kg * 16) ^ ((row & 7) << 4)));
      }
      #pragma unroll
      for (int sl = 0; sl < 3; sl++)
        #pragma unroll
        for (int mi = 0; mi < 2; mi++){
          int row = wm * 32 + mi * 16 + m;
          af[sl][mi] = *(const bf8_t*)((const char*)As3 + sl * 8192 + row * 128 + ((kk * 64 + kg * 16) ^ ((row & 7) << 4)));
        }
      #pragma unroll
      for (int sl = 0; sl < 3; sl++)
        #pragma unroll
        for (int mi = 0; mi < 2; mi++)
          #pragma unroll
          for (int ni = 0; ni < 2; ni++)
            acc[sl][mi][ni] = __builtin_amdgcn_mfma_f32_16x16x32_bf16(af[sl][mi], bfr[ni], acc[sl][mi][ni], 0, 0, 0);
    }
  }

  const size_t obase = (size_t)(b * C_) * THW_;
  f4_t yacc[2][2];
  #pragma unroll
  for (int mi = 0; mi < 2; mi++)
    #pragma unroll
    for (int ni = 0; ni < 2; ni++) yacc[mi][ni] = (f4_t)0.f;
  #pragma unroll
  for (int sl = 0; sl < 3; sl++){
    const __half* ctx = (sl == 0) ? ctx_t : (sl == 1) ? ctx_h : ctx_w;
    #pragma unroll
    for (int mi = 0; mi < 2; mi++)
      #pragma unroll
      for (int ni = 0; ni < 2; ni++)
        #pragma unroll
        for (int r = 0; r < 4; r++){
          int ol = wm * 32 + mi * 16 + kg * 4 + r;
          int s  = s0 + wn * 32 + ni * 16 + m;
          float lg = acc[sl][mi][ni][r] + gb[sl * 256 + bo * 64 + ol];
          float g = __builtin_amdgcn_rcpf(1.f + __expf(-lg));
          yacc[mi][ni][r] += g * __half2float(ctx[obase + (size_t)(bo * 64 + ol) * THW_ + s]);
        }
  }

  __syncthreads();
  unsigned short* tile = As3;
  #pragma unroll
  for (int mi = 0; mi < 2; mi++)
    #pragma unroll
    for (int ni = 0; ni < 2; ni++){
      int ol = wm * 32 + mi * 16 + kg * 4;
      int sl2 = wn * 32 + ni * 16 + m;
      ushort4 w4;
      w4.x = f2bf(yacc[mi][ni][0]);
      w4.y = f2bf(yacc[mi][ni][1]);
      w4.z = f2bf(yacc[mi][ni][2]);
      w4.w = f2bf(yacc[mi][ni][3]);
      *(ushort4*)&tile[sl2 * 72 + ol] = w4;
    }
  __syncthreads();
  {
    int sr = tid >> 2, oc = (tid & 3) * 16;
    us8_t v0 = *(const us8_t*)&tile[sr * 72 + oc];
    us8_t v1 = *(const us8_t*)&tile[sr * 72 + oc + 8];
    unsigned short* dst = yT + ((size_t)b * THW_ + s0 + sr) * 256 + bo * 64 + oc;
    *(us8_t*)dst = v0;
    *(us8_t*)(dst + 8) = v1;
  }
}

// ---------------- proj GEMM -> d_out (f32) ----------------
__global__ __launch_bounds__(256) void k_mfma_proj(
    const unsigned short* __restrict__ Wb, const unsigned short* __restrict__ yT,
    float* __restrict__ out)
{
  __shared__ unsigned short As[8192], Bs[8192];
  const int bo = blockIdx.x;                  // 0..1
  const int s0 = blockIdx.y * 128;
  const int b  = blockIdx.z;
  f4_t acc[4][4];
  #pragma unroll
  for (int mi = 0; mi < 4; mi++)
    #pragma unroll
    for (int ni = 0; ni < 4; ni++) acc[mi][ni] = (f4_t)0.f;
  gemm_core_b<128>(Wb, bo * 128, yT + ((size_t)b * THW_ + s0) * 256, As, Bs, acc);
  const int lane = threadIdx.x & 63, wv = threadIdx.x >> 6;
  const int wm = wv >> 1, wn = wv & 1;
  size_t obase = (size_t)(b * C_) * THW_;
  #pragma unroll
  for (int mi = 0; mi < 4; mi++)
    #pragma unroll
    for (int ni = 0; ni < 4; ni++)
      #pragma unroll
      for (int r = 0; r < 4; r++){
        int o = bo * 128 + wm * 64 + mi * 16 + (lane >> 4) * 4 + r;
        int s = s0 + wn * 64 + ni * 16 + (lane & 15);
        out[obase + (size_t)o * THW_ + s] = acc[mi][ni][r];
      }
}

// ---------------- mean over (H,W): qg[b,c,t] (q is f16) ----------------
__global__ __launch_bounds__(256) void k_mean_hw(const __half* __restrict__ q, float* __restrict__ qg){
  int bct = blockIdx.x;
  const __half2* p = (const __half2*)(q + (size_t)bct * HW_);
  __half2 v0 = p[threadIdx.x * 2], v1 = p[threadIdx.x * 2 + 1];
  float sum = __low2float(v0) + __high2float(v0) + __low2float(v1) + __high2float(v1);
  #pragma unroll
  for (int off = 32; off; off >>= 1) sum += __shfl_down(sum, off);
  __shared__ float red[4];
  int lane = threadIdx.x & 63, w = threadIdx.x >> 6;
  if (lane == 0) red[w] = sum;
  __syncthreads();
  if (threadIdx.x == 0) qg[bct] = (red[0] + red[1] + red[2] + red[3]) * (1.f / 1024.f);
}

// ---------------- mix pre: h = gelu(pre_w @ qg + pre_b) ----------------
__global__ __launch_bounds__(256) void k_mix_pre(const float* __restrict__ preW, const float* __restrict__ preB,
    const float* __restrict__ qg, float* __restrict__ hbuf){
  int b = blockIdx.x >> 5, t = blockIdx.x & 31;
  int o = threadIdx.x;
  __shared__ float qgl[256];
  qgl[o] = qg[((size_t)(b * C_ + o)) * T_ + t];
  __syncthreads();
  float a = preB[o];
  for (int c = 0; c < C_; c++) a = fmaf(preW[o * C_ + c], qgl[c], a);
  float g = 0.5f * a * (1.f + erff(a * 0.70710678118f));
  hbuf[((size_t)(b * C_ + o)) * T_ + t] = g;
}

// ---------------- mix logits + softmax over m ----------------
__global__ __launch_bounds__(256) void k_mix_alpha(const float* __restrict__ cw, const float* __restrict__ cb,
    const float* __restrict__ hbuf, float* __restrict__ alpha){
  int b = blockIdx.x >> 5, t = blockIdx.x & 31;
  int c = threadIdx.x;
  float hv[3];
  #pragma unroll
  for (int j = 0; j < 3; j++){
    int tt = t - 2 + j;
    hv[j] = (tt >= 0) ? hbuf[((size_t)(b * C_ + c)) * T_ + tt] : 0.f;
  }
  float p[3];
  #pragma unroll
  for (int m = 0; m < 3; m++){
    const float* w = cw + ((size_t)m * C_ + c) * 3;
    p[m] = w[0] * hv[0] + w[1] * hv[1] + w[2] * hv[2];
  }
  #pragma unroll
  for (int m = 0; m < 3; m++){
    #pragma unroll
    for (int off = 32; off; off >>= 1) p[m] += __shfl_down(p[m], off);
  }
  __shared__ float red[3][4];
  int lane = threadIdx.x & 63, w = threadIdx.x >> 6;
  if (lane == 0){ red[0][w] = p[0]; red[1][w] = p[1]; red[2][w] = p[2]; }
  __syncthreads();
  if (threadIdx.x == 0){
    float lg[3];
    #pragma unroll
    for (int m = 0; m < 3; m++) lg[m] = red[m][0] + red[m][1] + red[m][2] + red[m][3] + cb[m];
    float mx = fmaxf(lg[0], fmaxf(lg[1], lg[2]));
    float e0 = __expf(lg[0] - mx), e1 = __expf(lg[1] - mx), e2 = __expf(lg[2] - mx);
    float r = 1.f / (e0 + e1 + e2);
    alpha[((size_t)(b * 3 + 0)) * T_ + t] = e0 * r;
    alpha[((size_t)(b * 3 + 1)) * T_ + t] = e1 * r;
    alpha[((size_t)(b * 3 + 2)) * T_ + t] = e2 * r;
  }
}

// ---------------- alpha-mixed causal depthwise conv 3x3x3, k AND v in one grid ----------------
__global__ __launch_bounds__(256) void k_conv_both(
    const __half* __restrict__ kin, const __half* __restrict__ vin,
    const float* __restrict__ wkb, const float* __restrict__ wvb,
    const float* __restrict__ alpha,
    __half* __restrict__ kout, __half* __restrict__ vout)
{
  int bi = blockIdx.x;
  int which = bi >> 14;
  int rest = bi & 16383;
  int c = rest & 255, t = (rest >> 8) & 31, b = (rest >> 13) & 1;
  const __half* in_g = which ? vin : kin;
  const float* bank  = which ? wvb : wkb;
  __half* out        = which ? vout : kout;
  __shared__ float sIn[3 * 34 * 34];
  __shared__ float wmix[27];
  int tid = threadIdx.x;
  if (tid < 27){
    float sum = 0.f;
    #pragma unroll
    for (int m = 0; m < 3; m++)
      sum += alpha[((size_t)(b * 3 + m)) * T_ + t] * bank[((size_t)m * C_ + c) * 27 + tid];
    wmix[tid] = sum;
  }
  size_t cbase = ((size_t)(b * C_ + c)) * T_;
  for (int idx = tid; idx < 3 * 34 * 34; idx += 256){
    int tp = idx / 1156, rem = idx % 1156;
    int yy = rem / 34, xx = rem % 34;
    int tin = t - 2 + tp, y = yy - 1, x = xx - 1;
    bool ok = (tin >= 0) && (y >= 0) && (y < 32) && (x >= 0) && (x < 32);
    size_t g = ok ? ((cbase + tin) * HW_ + (size_t)y * 32 + x) : 0;
    sIn[idx] = ok ? __half2float(in_g[g]) : 0.f;
  }
  __syncthreads();
  int y = tid >> 3, x0 = (tid & 7) * 4;
  float a[4] = {0.f, 0.f, 0.f, 0.f};
  #pragma unroll
  for (int dt = 0; dt < 3; dt++){
    #pragma unroll
    for (int dy = 0; dy < 3; dy++){
      int rb = dt * 1156 + (y + dy) * 34 + x0;
      #pragma unroll
      for (int dx = 0; dx < 3; dx++){
        float wv = wmix[dt * 9 + dy * 3 + dx];
        #pragma unroll
        for (int p2 = 0; p2 < 4; p2++) a[p2] = fmaf(wv, sIn[rb + dx + p2], a[p2]);
      }
    }
  }
  size_t ob = (cbase + t) * HW_ + (size_t)y * 32 + x0;
  __half2 h01 = __halves2half2(__float2half(a[0]), __float2half(a[1]));
  __half2 h23 = __halves2half2(__float2half(a[2]), __float2half(a[3]));
  *reinterpret_cast<__half2*>(out + ob)     = h01;
  *reinterpret_cast<__half2*>(out + ob + 2) = h23;
}

// ---------------- axial attention body (MFMA), one 32x32 sequence per wave ----------------
// LDS (ushort idx):
//   q[seq]: seq*2304 + i*36 + col' ; k[seq]: +1152      (col' = 2u | half: RoPE pair packed
//   as one u32 -> 2-way banks; k-dim permutation identical for Q and K => QK^T invariant)
//   v[seq]: 9216 + seq*1152 + d*36 + j                   (unchanged, unpermuted)
//   O (all axes): seq*1160 + d*36 + i  over dead q/k     (ushort4 vector writes, ~2-way)
template<int AXIS>
static __device__ __forceinline__ void attn_body(
    int id, unsigned short* smem,
    const unsigned short* __restrict__ qp, const unsigned short* __restrict__ kp,
    const unsigned short* __restrict__ vp, unsigned short* ctx,
    const float* __restrict__ cosT, const float* __restrict__ sinT)
{
  const int SS = (AXIS == 0) ? HW_ : (AXIS == 1) ? 32 : 1;
  const int GS = (AXIS == 2) ? 32 : 1;
  const int OS = (AXIS == 0) ? 32 : HW_;
  int ggrp = (id >> 3) & 7;
  int rest = ((id >> 6) << 3) | (id & 7);
  int outer = rest & 31;
  int head = (rest >> 5) & 7;
  int b = rest >> 8;
  const size_t base = ((size_t)(b * C_ + head * 32)) * THW_ + (size_t)outer * OS + (size_t)(ggrp * 4) * GS;
  const int tid = threadIdx.x;

  // ---- staged load q,k with RoPE folded; (f,f+16) packed into one u32 store ----
  for (int idx2 = tid; idx2 < 512; idx2 += 256){
    if (AXIS != 2){
      int i = idx2 & 31, u = idx2 >> 5;
      size_t glo = base + (size_t)u * THW_ + (size_t)i * SS;
      size_t ghi = glo + (size_t)16 * THW_;
      ushort4 ql = *(const ushort4*)(qp + glo), qh = *(const ushort4*)(qp + ghi);
      ushort4 kl = *(const ushort4*)(kp + glo), kh = *(const ushort4*)(kp + ghi);
      float cv = cosT[i * 16 + u], sv = sinT[i * 16 + u];
      const unsigned short qla[4] = {ql.x, ql.y, ql.z, ql.w}, qha[4] = {qh.x, qh.y, qh.z, qh.w};
      const unsigned short kla[4] = {kl.x, kl.y, kl.z, kl.w}, kha[4] = {kh.x, kh.y, kh.z, kh.w};
      #pragma unroll
      for (int g = 0; g < 4; g++){
        int rb = g * 2304 + i * 36 + 2 * u;
        float a = h2f_u(qla[g]), b2 = h2f_u(qha[g]);
        *(u32*)&smem[rb] = pkrtz(a * cv - b2 * sv, fmaf(b2, cv, a * sv));
        a = h2f_u(kla[g]); b2 = h2f_u(kha[g]);
        *(u32*)&smem[rb + 1152] = pkrtz(a * cv - b2 * sv, fmaf(b2, cv, a * sv));
      }
    } else {
      int ii = (idx2 & 7) * 4, g = (idx2 >> 3) & 3, u = idx2 >> 5;
      size_t glo = base + (size_t)u * THW_ + (size_t)g * GS + ii;
      size_t ghi = glo + (size_t)16 * THW_;
      ushort4 ql = *(const ushort4*)(qp + glo), qh = *(const ushort4*)(qp + ghi);
      ushort4 kl = *(const ushort4*)(kp + glo), kh = *(const ushort4*)(kp + ghi);
      const unsigned short qla[4] = {ql.x, ql.y, ql.z, ql.w}, qha[4] = {qh.x, qh.y, qh.z, qh.w};
      const unsigned short kla[4] = {kl.x, kl.y, kl.z, kl.w}, kha[4] = {kh.x, kh.y, kh.z, kh.w};
      #pragma unroll
      for (int p2 = 0; p2 < 4; p2++){
        int i = ii + p2;
        int rb = g * 2304 + i * 36 + 2 * u;
        float cv = cosT[i * 16 + u], sv = sinT[i * 16 + u];
        float a = h2f_u(qla[p2]), b2 = h2f_u(qha[p2]);
        *(u32*)&smem[rb] = pkrtz(a * cv - b2 * sv, fmaf(b2, cv, a * sv));
        a = h2f_u(kla[p2]); b2 = h2f_u(kha[p2]);
        *(u32*)&smem[rb + 1152] = pkrtz(a * cv - b2 * sv, fmaf(b2, cv, a * sv));
      }
    }
  }
  // ---- staged load v -> transposed [d][j] ----
  for (int idx2 = tid; idx2 < 1024; idx2 += 256){
    if (AXIS != 2){
      int i = idx2 & 31, f = idx2 >> 5;
      size_t go = base + (size_t)f * THW_ + (size_t)i * SS;
      ushort4 vv = *(const ushort4*)(vp + go);
      const unsigned short va[4] = {vv.x, vv.y, vv.z, vv.w};
      #pragma unroll
      for (int g = 0; g < 4; g++) smem[9216 + g * 1152 + f * 36 + i] = va[g];
    } else {
      int ii = (idx2 & 7) * 4, g = (idx2 >> 3) & 3, f = idx2 >> 5;
      size_t go = base + (size_t)f * THW_ + (size_t)g * GS + ii;
      ushort4 vv = *(const ushort4*)(vp + go);
      const unsigned short va[4] = {vv.x, vv.y, vv.z, vv.w};
      #pragma unroll
      for (int p2 = 0; p2 < 4; p2++) smem[9216 + g * 1152 + f * 36 + ii + p2] = va[p2];
    }
  }
  __syncthreads();

  const int lane = tid & 63;
  const int seq = tid >> 6;
  const int m = lane & 15, kg = lane >> 4;
  const int sq = seq * 2304;

  h8_t aQ[2], bK[2], bV[2];
  #pragma unroll
  for (int t2 = 0; t2 < 2; t2++){
    union { ushort4 u4[2]; h8_t h; } uq, uk, uv;
    int rq = sq + (t2 * 16 + m) * 36 + kg * 8;
    uq.u4[0] = *(const ushort4*)&smem[rq];
    uq.u4[1] = *(const ushort4*)&smem[rq + 4];
    int rk = sq + 1152 + (t2 * 16 + m) * 36 + kg * 8;
    uk.u4[0] = *(const ushort4*)&smem[rk];
    uk.u4[1] = *(const ushort4*)&smem[rk + 4];
    int rv = 9216 + seq * 1152 + (t2 * 16 + m) * 36 + kg * 8;
    uv.u4[0] = *(const ushort4*)&smem[rv];
    uv.u4[1] = *(const ushort4*)&smem[rv + 4];
    aQ[t2] = uq.h; bK[t2] = uk.h; bV[t2] = uv.h;
  }

  f4_t st[2][2];
  #pragma unroll
  for (int tk = 0; tk < 2; tk++)
    #pragma unroll
    for (int tq = 0; tq < 2; tq++){
      st[tk][tq] = (f4_t)0.f;
      st[tk][tq] = __builtin_amdgcn_mfma_f32_16x16x32_f16(bK[tk], aQ[tq], st[tk][tq], 0, 0, 0);
    }

  u32 pkk[2][2][2];             // [tq][tk][pair]
  #pragma unroll
  for (int tq = 0; tq < 2; tq++){
    const int i = tq * 16 + m;
    float e[2][4];
    float mx = -3.0e38f;
    #pragma unroll
    for (int tk = 0; tk < 2; tk++)
      #pragma unroll
      for (int r = 0; r < 4; r++){
        float s = st[tk][tq][r] * 0.17677669529663687f;
        if (AXIS == 0 && (tk * 16 + kg * 4 + r) > i) s = -1e30f;
        e[tk][r] = s;
        mx = fmaxf(mx, s);
      }
    mx = fmaxf(mx, __shfl_xor(mx, 16));
    mx = fmaxf(mx, __shfl_xor(mx, 32));
    float sum = 0.f;
    #pragma unroll
    for (int tk = 0; tk < 2; tk++)
      #pragma unroll
      for (int r = 0; r < 4; r++){
        e[tk][r] = __expf(e[tk][r] - mx);
        sum += e[tk][r];
      }
    sum += __shfl_xor(sum, 16);
    sum += __shfl_xor(sum, 32);
    float rinv = 1.f / sum;
    #pragma unroll
    for (int tk = 0; tk < 2; tk++){
      pkk[tq][tk][0] = pkrtz(e[tk][0] * rinv, e[tk][1] * rinv);
      pkk[tq][tk][1] = pkrtz(e[tk][2] * rinv, e[tk][3] * rinv);
    }
  }

  h8_t aP[2];
  #pragma unroll
  for (int tq = 0; tq < 2; tq++){
    union { u32 w[4]; h8_t h; } uu;
    #pragma unroll
    for (int w = 0; w < 4; w++){
      int srcLane = ((kg & 1) * 2 + (w >> 1)) * 16 + m;
      u32 v0 = __shfl(pkk[tq][0][w & 1], srcLane);
      u32 v1 = __shfl(pkk[tq][1][w & 1], srcLane);
      uu.w[w] = (kg >= 2) ? v1 : v0;
    }
    aP[tq] = uu.h;
  }

  f4_t o_[2][2];
  #pragma unroll
  for (int tq = 0; tq < 2; tq++)
    #pragma unroll
    for (int td = 0; td < 2; td++){
      o_[tq][td] = (f4_t)0.f;
      o_[tq][td] = __builtin_amdgcn_mfma_f32_16x16x32_f16(aP[tq], bV[td], o_[tq][td], 0, 0, 0);
    }

  __syncthreads();   // all waves done reading q/k before O overwrites it

  // ---- O -> LDS, unified layout [seq][d][i], vector ushort4 writes over r ----
  #pragma unroll
  for (int tq = 0; tq < 2; tq++)
    #pragma unroll
    for (int td = 0; td < 2; td++){
      int i0 = tq * 16 + kg * 4, d = td * 16 + m;
      union { u32 w[2]; ushort4 v; } pk2;
      pk2.w[0] = pkrtz(o_[tq][td][0], o_[tq][td][1]);
      pk2.w[1] = pkrtz(o_[tq][td][2], o_[tq][td][3]);
      *(ushort4*)&smem[seq * 1160 + d * 36 + i0] = pk2.v;
    }
  __syncthreads();

  // ---- staged store ----
  for (int idx2 = tid; idx2 < 1024; idx2 += 256){
    if (AXIS != 2){
      int i2 = idx2 & 31, f = idx2 >> 5;
      ushort4 ov;
      ov.x = smem[0 * 1160 + f * 36 + i2];
      ov.y = smem[1 * 1160 + f * 36 + i2];
      ov.z = smem[2 * 1160 + f * 36 + i2];
      ov.w = smem[3 * 1160 + f * 36 + i2];
      size_t go = base + (size_t)f * THW_ + (size_t)i2 * SS;
      *(ushort4*)(ctx + go) = ov;
    } else {
      int ii = (idx2 & 7) * 4, g2 = (idx2 >> 3) & 3, f = idx2 >> 5;
      ushort4 ov = *(const ushort4*)&smem[g2 * 1160 + f * 36 + ii];
      size_t go = base + (size_t)f * THW_ + (size_t)g2 * GS + ii;
      *(ushort4*)(ctx + go) = ov;
    }
  }
}

// ---------------- fused attention dispatcher: all 3 axes in one grid (12288 blocks) --------
__global__ __launch_bounds__(256) void k_attn_all(
    const __half* __restrict__ qg_, const __half* __restrict__ kg_,
    const __half* __restrict__ vg_,
    __half* __restrict__ ctx_t, __half* __restrict__ ctx_h, __half* __restrict__ ctx_w,
    const float* __restrict__ cosT, const float* __restrict__ sinT)
{
  __shared__ __align__(16) unsigned short smem[13824];   // 27.6 KB
  int ax = blockIdx.x >> 12;
  int id = blockIdx.x & 4095;
  const unsigned short* qp = (const unsigned short*)qg_;
  const unsigned short* kp = (const unsigned short*)kg_;
  const unsigned short* vp = (const unsigned short*)vg_;
  if (ax == 0)      attn_body<0>(id, smem, qp, kp, vp, (unsigned short*)ctx_t, cosT, sinT);
  else if (ax == 1) attn_body<1>(id, smem, qp, kp, vp, (unsigned short*)ctx_h, cosT, sinT);
  else              attn_body<2>(id, smem, qp, kp, vp, (unsigned short*)ctx_w, cosT, sinT);
}

extern "C" void kernel_launch(void* const* d_in, const int* in_sizes, int n_in,
                              void* d_out, int out_size, void* d_ws, size_t ws_size,
                              hipStream_t stream)
{
  (void)in_sizes; (void)n_in; (void)out_size; (void)ws_size;
  const float* x       = (const float*)d_in[0];
  const float* w_qkv   = (const float*)d_in[1];
  const float* wk_bank = (const float*)d_in[2];
  const float* wv_bank = (const float*)d_in[3];
  const float* pre_w   = (const float*)d_in[4];
  const float* pre_b   = (const float*)d_in[5];
  const float* cw      = (const float*)d_in[6];
  const float* cb      = (const float*)d_in[7];
  const float* gate_w  = (const float*)d_in[8];
  const float* gate_b  = (const float*)d_in[9];
  const float* proj_w  = (const float*)d_in[10];

  const size_t SZ = (size_t)B_ * C_ * THW_;           // 16,777,216 elems
  __half* hb = (__half*)d_ws;                         // 32MB slots
  unsigned short* xT  = (unsigned short*)(hb + 0 * SZ);  // bf16, alive to gate
  __half* qH   = hb + 1 * SZ;                         // q
  __half* kH   = hb + 2 * SZ;                         // k -> ctx_t
  __half* vH   = hb + 3 * SZ;                         // v -> ctx_h
  __half* koH  = hb + 4 * SZ;                         // k_out -> yT(bf16)
  __half* voH  = hb + 5 * SZ;                         // v_out (stays valid)
  __half* ctxtH = kH;
  __half* ctxhH = vH;
  __half* ctxwH = (__half*)d_out;                     // ctx_w in d_out (dead until proj)
  unsigned short* yT = (unsigned short*)koH;          // over dead k_out
  float* sm    = (float*)(hb + 6 * SZ);               // smalls
  float* qg    = sm;                                  // 16384
  float* hbuf  = qg + 16384;                          // 16384
  float* alpha = hbuf + 16384;                        // 192
  float* cosT  = alpha + 192;                         // 512
  float* sinT  = cosT + 512;                          // 512
  unsigned short* wB = (unsigned short*)(sinT + 512); // 1792*256 bf16 (896 KB)
  unsigned short* wBq = wB;                           // [768][256]
  unsigned short* wBg = wB + 768 * 256;               // [768][256]
  unsigned short* wBp = wB + 1536 * 256;              // [256][256]

  k_rope_table<<<1, 512, 0, stream>>>(cosT, sinT);
  k_wcvt<<<1792, 256, 0, stream>>>(w_qkv, gate_w, proj_w, wB);
  k_transpose_cvt<float><<<dim3(512, 4, 2), 256, 0, stream>>>(x, xT);

  k_mfma_qkv<<<dim3(6, 256, 2), 256, 0, stream>>>(wBq, xT, qH, kH, vH);

  k_mean_hw<<<16384, 256, 0, stream>>>(qH, qg);
  k_mix_pre<<<64, 256, 0, stream>>>(pre_w, pre_b, qg, hbuf);
  k_mix_alpha<<<64, 256, 0, stream>>>(cw, cb, hbuf, alpha);

  k_conv_both<<<32768, 256, 0, stream>>>(kH, vH, wk_bank, wv_bank, alpha, koH, voH);

  k_attn_all<<<12288, 256, 0, stream>>>(qH, koH, voH, ctxtH, ctxhH, ctxwH, cosT, sinT);

  k_mfma_gate2<<<dim3(4, 512, 2), 256, 0, stream>>>(wBg, xT, gate_b,
                                                    ctxtH, ctxhH, ctxwH, yT); // yT over dead k_out
  k_mfma_proj<<<dim3(2, 256, 2), 256, 0, stream>>>(wBp, yT, (float*)d_out);
}

// Round 12
// 417.237 us; speedup vs baseline: 5.1947x; 1.1050x over previous
//
#include <hip/hip_runtime.h>
#include <hip/hip_fp16.h>
#include <math.h>

#define B_   2
#define C_   256
#define T_   32
#define HW_  1024
#define THW_ 32768

using u32 = unsigned int;
typedef __attribute__((ext_vector_type(8))) short bf8_t;   // 8 bf16 in 4 VGPRs
typedef __attribute__((ext_vector_type(8))) unsigned short us8_t;
typedef __attribute__((ext_vector_type(8))) _Float16 h8_t; // 8 f16 in 4 VGPRs
typedef __attribute__((ext_vector_type(2))) __fp16 fp16v2; // builtin cvt_pkrtz return type
typedef __attribute__((ext_vector_type(4))) float f4_t;

static __device__ __forceinline__ unsigned short f2bf(float x){
  u32 u = __float_as_uint(x);
  u32 r = (u + 0x7FFF + ((u >> 16) & 1)) >> 16;   // RNE
  return (unsigned short)r;
}
static __device__ __forceinline__ float h2f_u(unsigned short u){
  union { __half h; unsigned short us; } cv; cv.us = u; return __half2float(cv.h);
}
static __device__ __forceinline__ unsigned short f2h_u(float f){
  union { __half h; unsigned short us; } cv; cv.h = __float2half(f); return cv.us;
}
static __device__ __forceinline__ u32 pkrtz(float a, float b){
  union { fp16v2 h; u32 w; } cv; cv.h = __builtin_amdgcn_cvt_pkrtz(a, b); return cv.w;
}
static __device__ __forceinline__ float ldf(const float* p){ return *p; }
static __device__ __forceinline__ float ldf(const __half* p){ return __half2float(*p); }

// ---------------- rope table ----------------
__global__ void k_rope_table(float* __restrict__ cosT, float* __restrict__ sinT){
  int tid = threadIdx.x;            // 512 threads, tid = i*16+u
  int i = tid >> 4, u = tid & 15;
  float invf = powf(10000.f, -(2.f * (float)u) / 32.f);
  float s, c;
  sincosf((float)i * invf, &s, &c);
  cosT[tid] = c;
  sinT[tid] = s;
}

// ---------------- weight cvt: stack w_qkv(768), gate_w(768), proj_w(256) as bf16 [1792][256] --
__global__ void k_wcvt(const float* __restrict__ w_qkv, const float* __restrict__ gate_w,
                       const float* __restrict__ proj_w, unsigned short* __restrict__ out){
  int row = blockIdx.x, c = threadIdx.x;
  const float* src = (row < 768) ? w_qkv + (size_t)row * 256
                   : (row < 1536) ? gate_w + (size_t)(row - 768) * 256
                                  : proj_w + (size_t)(row - 1536) * 256;
  out[(size_t)row * 256 + c] = f2bf(src[c]);
}

// ---------------- transpose+cvt: [b][256][THW] f32 -> bf16 [b][THW][256] ----------------
template<typename InT>
__global__ __launch_bounds__(256) void k_transpose_cvt(
    const InT* __restrict__ in, unsigned short* __restrict__ outT)
{
  __shared__ float tile[64][65];
  int s0 = blockIdx.x * 64;     // 512
  int c0 = blockIdx.y * 64;     // 4
  int b  = blockIdx.z;
  int tid = threadIdx.x;
  for (int idx = tid; idx < 4096; idx += 256){
    int c = idx >> 6, s = idx & 63;
    tile[c][s] = ldf(&in[((size_t)(b * C_ + c0 + c)) * THW_ + s0 + s]);
  }
  __syncthreads();
  for (int idx = tid; idx < 4096; idx += 256){
    int s = idx >> 6, c = idx & 63;
    outT[((size_t)b * THW_ + s0 + s) * 256 + c0 + c] = f2bf(tile[c][s]);
  }
}

// ---------------- MFMA GEMM core (bf16 A bank): 128xBN tile, K=256 ----------------
template<int BN>
static __device__ __forceinline__ void gemm_core_b(
    const unsigned short* __restrict__ A, int o0,
    const unsigned short* __restrict__ BT,   // pre-offset: + (b*THW + s0)*256
    unsigned short* As, unsigned short* Bs, f4_t acc[4][BN / 32])
{
  const int tid = threadIdx.x;
  const int lane = tid & 63, wv = tid >> 6;
  const int wm = wv >> 1, wn = wv & 1;
  const int m = lane & 15, kg = lane >> 4;
  const int arow = tid >> 1, aseg = (tid & 1) * 64;     // A: 128 rows, 2 thr/row, 64B each
  const int brow = (BN == 128) ? (tid >> 1) : (tid >> 2);
  const int bseg = (BN == 128) ? (tid & 1) * 64 : (tid & 3) * 32;
  for (int ks = 0; ks < 4; ks++){
    __syncthreads();                                    // protect prior reads
    {
      const unsigned short* ga = A + (size_t)(o0 + arow) * 256 + ks * 64 + aseg / 2;
      #pragma unroll
      for (int q2 = 0; q2 < 4; q2++){
        us8_t v = *(const us8_t*)(ga + q2 * 8);
        *(us8_t*)((char*)As + arow * 128 + ((aseg + q2 * 16) ^ ((arow & 7) << 4))) = v;
      }
      const unsigned short* gb = BT + (size_t)brow * 256 + ks * 64 + bseg / 2;
      #pragma unroll
      for (int q2 = 0; q2 < (BN == 128 ? 4 : 2); q2++){
        us8_t v = *(const us8_t*)(gb + q2 * 8);
        *(us8_t*)((char*)Bs + brow * 128 + ((bseg + q2 * 16) ^ ((brow & 7) << 4))) = v;
      }
    }
    __syncthreads();
    #pragma unroll
    for (int kk = 0; kk < 2; kk++){
      bf8_t af[4], bfr[BN / 32];
      #pragma unroll
      for (int mi = 0; mi < 4; mi++){
        int row = wm * 64 + mi * 16 + m;
        af[mi] = *(const bf8_t*)((const char*)As + row * 128 + ((kk * 64 + kg * 16) ^ ((row & 7) << 4)));
      }
      #pragma unroll
      for (int ni = 0; ni < BN / 32; ni++){
        int row = wn * (BN / 2) + ni * 16 + m;
        bfr[ni] = *(const bf8_t*)((const char*)Bs + row * 128 + ((kk * 64 + kg * 16) ^ ((row & 7) << 4)));
      }
      #pragma unroll
      for (int mi = 0; mi < 4; mi++)
        #pragma unroll
        for (int ni = 0; ni < BN / 32; ni++)
          acc[mi][ni] = __builtin_amdgcn_mfma_f32_16x16x32_bf16(af[mi], bfr[ni], acc[mi][ni], 0, 0, 0);
    }
  }
}

// ---------------- qkv GEMM: Wq(bf16)[768][256] @ x -> q,k,v (f16) ----------------
__global__ __launch_bounds__(256) void k_mfma_qkv(
    const unsigned short* __restrict__ Wb, const unsigned short* __restrict__ xT,
    __half* __restrict__ q, __half* __restrict__ k, __half* __restrict__ v)
{
  __shared__ unsigned short As[8192], Bs[8192];
  const int bo = blockIdx.x;                  // 0..5
  const int s0 = blockIdx.y * 128;            // 256
  const int b  = blockIdx.z;
  f4_t acc[4][4];
  #pragma unroll
  for (int mi = 0; mi < 4; mi++)
    #pragma unroll
    for (int ni = 0; ni < 4; ni++) acc[mi][ni] = (f4_t)0.f;
  gemm_core_b<128>(Wb, bo * 128, xT + ((size_t)b * THW_ + s0) * 256, As, Bs, acc);
  __half* outp = (bo < 2) ? q : (bo < 4) ? k : v;
  const int ro = (bo & 1) * 128;
  const int lane = threadIdx.x & 63, wv = threadIdx.x >> 6;
  const int wm = wv >> 1, wn = wv & 1;
  size_t obase = (size_t)(b * C_) * THW_;
  #pragma unroll
  for (int mi = 0; mi < 4; mi++)
    #pragma unroll
    for (int ni = 0; ni < 4; ni++)
      #pragma unroll
      for (int r = 0; r < 4; r++){
        int o = ro + wm * 64 + mi * 16 + (lane >> 4) * 4 + r;
        int s = s0 + wn * 64 + ni * 16 + (lane & 15);
        outp[obase + (size_t)o * THW_ + s] = __float2half(acc[mi][ni][r]);
      }
}

// ---------------- gate GEMM + sigmoid + combine, 3 slices interleaved, yT(bf16) direct ------
__global__ __launch_bounds__(256) void k_mfma_gate2(
    const unsigned short* __restrict__ Wb,   // bf16 gate bank [768][256]
    const unsigned short* __restrict__ xT,
    const float* __restrict__ gb,
    const __half* __restrict__ ctx_t, const __half* __restrict__ ctx_h,
    const __half* __restrict__ ctx_w,
    unsigned short* __restrict__ yT)         // bf16 [b][THW][256]
{
  __shared__ unsigned short As3[12288];
  __shared__ unsigned short Bs[4096];
  const int bo = blockIdx.x;                  // 0..3
  const int s0 = blockIdx.y * 64;
  const int b  = blockIdx.z;
  const int tid = threadIdx.x;
  const int lane = tid & 63, wv = tid >> 6;
  const int wm = wv >> 1, wn = wv & 1;
  const int m = lane & 15, kg = lane >> 4;
  const unsigned short* xbase = xT + ((size_t)b * THW_ + s0) * 256;

  f4_t acc[3][2][2];
  #pragma unroll
  for (int sl = 0; sl < 3; sl++)
    #pragma unroll
    for (int mi = 0; mi < 2; mi++)
      #pragma unroll
      for (int ni = 0; ni < 2; ni++) acc[sl][mi][ni] = (f4_t)0.f;

  for (int ks = 0; ks < 4; ks++){
    __syncthreads();
    #pragma unroll
    for (int rep = 0; rep < 2; rep++){
      int idx = rep * 256 + tid;              // 0..511
      int row = idx >> 3, seg = idx & 7;
      us8_t v = *(const us8_t*)(xbase + (size_t)row * 256 + ks * 64 + seg * 8);
      *(us8_t*)((char*)Bs + row * 128 + ((seg * 16) ^ ((row & 7) << 4))) = v;
    }
    #pragma unroll
    for (int sl = 0; sl < 3; sl++){
      #pragma unroll
      for (int rep = 0; rep < 2; rep++){
        int idx = rep * 256 + tid;
        int row = idx >> 3, seg = idx & 7;
        us8_t v = *(const us8_t*)(Wb + (size_t)(sl * 256 + bo * 64 + row) * 256 + ks * 64 + seg * 8);
        *(us8_t*)((char*)As3 + sl * 8192 + row * 128 + ((seg * 16) ^ ((row & 7) << 4))) = v;
      }
    }
    __syncthreads();
    #pragma unroll
    for (int kk = 0; kk < 2; kk++){
      bf8_t bfr[2], af[3][2];
      #pragma unroll
      for (int ni = 0; ni < 2; ni++){
        int row = wn * 32 + ni * 16 + m;
        bfr[ni] = *(const bf8_t*)((const char*)Bs + row * 128 + ((kk * 64 + kg * 16) ^ ((row & 7) << 4)));
      }
      #pragma unroll
      for (int sl = 0; sl < 3; sl++)
        #pragma unroll
        for (int mi = 0; mi < 2; mi++){
          int row = wm * 32 + mi * 16 + m;
          af[sl][mi] = *(const bf8_t*)((const char*)As3 + sl * 8192 + row * 128 + ((kk * 64 + kg * 16) ^ ((row & 7) << 4)));
        }
      #pragma unroll
      for (int sl = 0; sl < 3; sl++)
        #pragma unroll
        for (int mi = 0; mi < 2; mi++)
          #pragma unroll
          for (int ni = 0; ni < 2; ni++)
            acc[sl][mi][ni] = __builtin_amdgcn_mfma_f32_16x16x32_bf16(af[sl][mi], bfr[ni], acc[sl][mi][ni], 0, 0, 0);
    }
  }

  const size_t obase = (size_t)(b * C_) * THW_;
  f4_t yacc[2][2];
  #pragma unroll
  for (int mi = 0; mi < 2; mi++)
    #pragma unroll
    for (int ni = 0; ni < 2; ni++) yacc[mi][ni] = (f4_t)0.f;
  #pragma unroll
  for (int sl = 0; sl < 3; sl++){
    const __half* ctx = (sl == 0) ? ctx_t : (sl == 1) ? ctx_h : ctx_w;
    #pragma unroll
    for (int mi = 0; mi < 2; mi++)
      #pragma unroll
      for (int ni = 0; ni < 2; ni++)
        #pragma unroll
        for (int r = 0; r < 4; r++){
          int ol = wm * 32 + mi * 16 + kg * 4 + r;
          int s  = s0 + wn * 32 + ni * 16 + m;
          float lg = acc[sl][mi][ni][r] + gb[sl * 256 + bo * 64 + ol];
          float g = __builtin_amdgcn_rcpf(1.f + __expf(-lg));
          yacc[mi][ni][r] += g * __half2float(ctx[obase + (size_t)(bo * 64 + ol) * THW_ + s]);
        }
  }

  __syncthreads();
  unsigned short* tile = As3;
  #pragma unroll
  for (int mi = 0; mi < 2; mi++)
    #pragma unroll
    for (int ni = 0; ni < 2; ni++){
      int ol = wm * 32 + mi * 16 + kg * 4;
      int sl2 = wn * 32 + ni * 16 + m;
      ushort4 w4;
      w4.x = f2bf(yacc[mi][ni][0]);
      w4.y = f2bf(yacc[mi][ni][1]);
      w4.z = f2bf(yacc[mi][ni][2]);
      w4.w = f2bf(yacc[mi][ni][3]);
      *(ushort4*)&tile[sl2 * 72 + ol] = w4;
    }
  __syncthreads();
  {
    int sr = tid >> 2, oc = (tid & 3) * 16;
    us8_t v0 = *(const us8_t*)&tile[sr * 72 + oc];
    us8_t v1 = *(const us8_t*)&tile[sr * 72 + oc + 8];
    unsigned short* dst = yT + ((size_t)b * THW_ + s0 + sr) * 256 + bo * 64 + oc;
    *(us8_t*)dst = v0;
    *(us8_t*)(dst + 8) = v1;
  }
}

// ---------------- proj GEMM -> d_out (f32) ----------------
__global__ __launch_bounds__(256) void k_mfma_proj(
    const unsigned short* __restrict__ Wb, const unsigned short* __restrict__ yT,
    float* __restrict__ out)
{
  __shared__ unsigned short As[8192], Bs[8192];
  const int bo = blockIdx.x;                  // 0..1
  const int s0 = blockIdx.y * 128;
  const int b  = blockIdx.z;
  f4_t acc[4][4];
  #pragma unroll
  for (int mi = 0; mi < 4; mi++)
    #pragma unroll
    for (int ni = 0; ni < 4; ni++) acc[mi][ni] = (f4_t)0.f;
  gemm_core_b<128>(Wb, bo * 128, yT + ((size_t)b * THW_ + s0) * 256, As, Bs, acc);
  const int lane = threadIdx.x & 63, wv = threadIdx.x >> 6;
  const int wm = wv >> 1, wn = wv & 1;
  size_t obase = (size_t)(b * C_) * THW_;
  #pragma unroll
  for (int mi = 0; mi < 4; mi++)
    #pragma unroll
    for (int ni = 0; ni < 4; ni++)
      #pragma unroll
      for (int r = 0; r < 4; r++){
        int o = bo * 128 + wm * 64 + mi * 16 + (lane >> 4) * 4 + r;
        int s = s0 + wn * 64 + ni * 16 + (lane & 15);
        out[obase + (size_t)o * THW_ + s] = acc[mi][ni][r];
      }
}

// ---------------- mean over (H,W): qg[b,c,t] (q is f16) ----------------
__global__ __launch_bounds__(256) void k_mean_hw(const __half* __restrict__ q, float* __restrict__ qg){
  int bct = blockIdx.x;
  const __half2* p = (const __half2*)(q + (size_t)bct * HW_);
  __half2 v0 = p[threadIdx.x * 2], v1 = p[threadIdx.x * 2 + 1];
  float sum = __low2float(v0) + __high2float(v0) + __low2float(v1) + __high2float(v1);
  #pragma unroll
  for (int off = 32; off; off >>= 1) sum += __shfl_down(sum, off);
  __shared__ float red[4];
  int lane = threadIdx.x & 63, w = threadIdx.x >> 6;
  if (lane == 0) red[w] = sum;
  __syncthreads();
  if (threadIdx.x == 0) qg[bct] = (red[0] + red[1] + red[2] + red[3]) * (1.f / 1024.f);
}

// ---------------- mix pre: h = gelu(pre_w @ qg + pre_b) ----------------
__global__ __launch_bounds__(256) void k_mix_pre(const float* __restrict__ preW, const float* __restrict__ preB,
    const float* __restrict__ qg, float* __restrict__ hbuf){
  int b = blockIdx.x >> 5, t = blockIdx.x & 31;
  int o = threadIdx.x;
  __shared__ float qgl[256];
  qgl[o] = qg[((size_t)(b * C_ + o)) * T_ + t];
  __syncthreads();
  float a = preB[o];
  for (int c = 0; c < C_; c++) a = fmaf(preW[o * C_ + c], qgl[c], a);
  float g = 0.5f * a * (1.f + erff(a * 0.70710678118f));
  hbuf[((size_t)(b * C_ + o)) * T_ + t] = g;
}

// ---------------- mix logits + softmax over m ----------------
__global__ __launch_bounds__(256) void k_mix_alpha(const float* __restrict__ cw, const float* __restrict__ cb,
    const float* __restrict__ hbuf, float* __restrict__ alpha){
  int b = blockIdx.x >> 5, t = blockIdx.x & 31;
  int c = threadIdx.x;
  float hv[3];
  #pragma unroll
  for (int j = 0; j < 3; j++){
    int tt = t - 2 + j;
    hv[j] = (tt >= 0) ? hbuf[((size_t)(b * C_ + c)) * T_ + tt] : 0.f;
  }
  float p[3];
  #pragma unroll
  for (int m = 0; m < 3; m++){
    const float* w = cw + ((size_t)m * C_ + c) * 3;
    p[m] = w[0] * hv[0] + w[1] * hv[1] + w[2] * hv[2];
  }
  #pragma unroll
  for (int m = 0; m < 3; m++){
    #pragma unroll
    for (int off = 32; off; off >>= 1) p[m] += __shfl_down(p[m], off);
  }
  __shared__ float red[3][4];
  int lane = threadIdx.x & 63, w = threadIdx.x >> 6;
  if (lane == 0){ red[0][w] = p[0]; red[1][w] = p[1]; red[2][w] = p[2]; }
  __syncthreads();
  if (threadIdx.x == 0){
    float lg[3];
    #pragma unroll
    for (int m = 0; m < 3; m++) lg[m] = red[m][0] + red[m][1] + red[m][2] + red[m][3] + cb[m];
    float mx = fmaxf(lg[0], fmaxf(lg[1], lg[2]));
    float e0 = __expf(lg[0] - mx), e1 = __expf(lg[1] - mx), e2 = __expf(lg[2] - mx);
    float r = 1.f / (e0 + e1 + e2);
    alpha[((size_t)(b * 3 + 0)) * T_ + t] = e0 * r;
    alpha[((size_t)(b * 3 + 1)) * T_ + t] = e1 * r;
    alpha[((size_t)(b * 3 + 2)) * T_ + t] = e2 * r;
  }
}

// ---------------- alpha-mixed causal depthwise conv 3x3x3, k AND v in one grid ----------------
__global__ __launch_bounds__(256) void k_conv_both(
    const __half* __restrict__ kin, const __half* __restrict__ vin,
    const float* __restrict__ wkb, const float* __restrict__ wvb,
    const float* __restrict__ alpha,
    __half* __restrict__ kout, __half* __restrict__ vout)
{
  int bi = blockIdx.x;
  int which = bi >> 14;
  int rest = bi & 16383;
  int c = rest & 255, t = (rest >> 8) & 31, b = (rest >> 13) & 1;
  const __half* in_g = which ? vin : kin;
  const float* bank  = which ? wvb : wkb;
  __half* out        = which ? vout : kout;
  __shared__ float sIn[3 * 34 * 34];
  __shared__ float wmix[27];
  int tid = threadIdx.x;
  if (tid < 27){
    float sum = 0.f;
    #pragma unroll
    for (int m = 0; m < 3; m++)
      sum += alpha[((size_t)(b * 3 + m)) * T_ + t] * bank[((size_t)m * C_ + c) * 27 + tid];
    wmix[tid] = sum;
  }
  size_t cbase = ((size_t)(b * C_ + c)) * T_;
  for (int idx = tid; idx < 3 * 34 * 34; idx += 256){
    int tp = idx / 1156, rem = idx % 1156;
    int yy = rem / 34, xx = rem % 34;
    int tin = t - 2 + tp, y = yy - 1, x = xx - 1;
    bool ok = (tin >= 0) && (y >= 0) && (y < 32) && (x >= 0) && (x < 32);
    size_t g = ok ? ((cbase + tin) * HW_ + (size_t)y * 32 + x) : 0;
    sIn[idx] = ok ? __half2float(in_g[g]) : 0.f;
  }
  __syncthreads();
  int y = tid >> 3, x0 = (tid & 7) * 4;
  float a[4] = {0.f, 0.f, 0.f, 0.f};
  #pragma unroll
  for (int dt = 0; dt < 3; dt++){
    #pragma unroll
    for (int dy = 0; dy < 3; dy++){
      int rb = dt * 1156 + (y + dy) * 34 + x0;
      #pragma unroll
      for (int dx = 0; dx < 3; dx++){
        float wv = wmix[dt * 9 + dy * 3 + dx];
        #pragma unroll
        for (int p2 = 0; p2 < 4; p2++) a[p2] = fmaf(wv, sIn[rb + dx + p2], a[p2]);
      }
    }
  }
  size_t ob = (cbase + t) * HW_ + (size_t)y * 32 + x0;
  __half2 h01 = __halves2half2(__float2half(a[0]), __float2half(a[1]));
  __half2 h23 = __halves2half2(__float2half(a[2]), __float2half(a[3]));
  *reinterpret_cast<__half2*>(out + ob)     = h01;
  *reinterpret_cast<__half2*>(out + ob + 2) = h23;
}

// ---------------- axial attention body (MFMA), 8 waves/block, one seq per wave ----------------
// Block covers 8 consecutive g (ggrp*8..+7) -> all q/k/v loads and ctx stores are ushort8 (16B).
// LDS (ushort idx, row stride 36):
//   Q[seq]: seq*1152 + i*36 + col'        (col' = 2u|half, RoPE-pair packed as u32)
//   K[seq]: 9216 + seq*1152 + i*36 + col'
//   V[seq]: 18432 + seq*1152 + d*36 + j   -> O overwrites V[seq] (wave-local, no barrier)
template<int AXIS>
static __device__ __forceinline__ void attn_body(
    int id, unsigned short* smem,
    const unsigned short* __restrict__ qp, const unsigned short* __restrict__ kp,
    const unsigned short* __restrict__ vp, unsigned short* ctx,
    const float* __restrict__ cosT, const float* __restrict__ sinT)
{
  const int SS = (AXIS == 0) ? HW_ : (AXIS == 1) ? 32 : 1;
  const int GS = (AXIS == 2) ? 32 : 1;
  const int OS = (AXIS == 0) ? 32 : HW_;
  int ggrp = (id >> 3) & 3;                       // 4 sibling blocks share 64B lines
  int rest = ((id >> 5) << 3) | (id & 7);         // 0..511
  int outer = rest & 31;
  int head = (rest >> 5) & 7;
  int b = rest >> 8;
  const size_t base = ((size_t)(b * C_ + head * 32)) * THW_ + (size_t)outer * OS + (size_t)(ggrp * 8) * GS;
  const int tid = threadIdx.x;                    // 0..511

  // ---- staged load q,k with RoPE folded; ushort8 = 8 g (axis 0/1) or 8 i (axis 2) ----
  if (AXIS != 2){
    int i = tid & 31, u = tid >> 5;               // u 0..15
    size_t glo = base + (size_t)u * THW_ + (size_t)i * SS;
    size_t ghi = glo + (size_t)16 * THW_;
    us8_t ql = *(const us8_t*)(qp + glo), qh = *(const us8_t*)(qp + ghi);
    us8_t kl = *(const us8_t*)(kp + glo), kh = *(const us8_t*)(kp + ghi);
    float cv = cosT[i * 16 + u], sv = sinT[i * 16 + u];
    #pragma unroll
    for (int g = 0; g < 8; g++){
      int rb = g * 1152 + i * 36 + 2 * u;
      float a = h2f_u(ql[g]), b2 = h2f_u(qh[g]);
      *(u32*)&smem[rb] = pkrtz(a * cv - b2 * sv, fmaf(b2, cv, a * sv));
      a = h2f_u(kl[g]); b2 = h2f_u(kh[g]);
      *(u32*)&smem[9216 + rb] = pkrtz(a * cv - b2 * sv, fmaf(b2, cv, a * sv));
    }
  } else {
    int i8 = (tid & 3) * 8, g = (tid >> 2) & 7, u = tid >> 5;
    size_t glo = base + (size_t)u * THW_ + (size_t)g * GS + i8;
    size_t ghi = glo + (size_t)16 * THW_;
    us8_t ql = *(const us8_t*)(qp + glo), qh = *(const us8_t*)(qp + ghi);
    us8_t kl = *(const us8_t*)(kp + glo), kh = *(const us8_t*)(kp + ghi);
    #pragma unroll
    for (int p2 = 0; p2 < 8; p2++){
      int i = i8 + p2;
      int rb = g * 1152 + i * 36 + 2 * u;
      float cv = cosT[i * 16 + u], sv = sinT[i * 16 + u];
      float a = h2f_u(ql[p2]), b2 = h2f_u(qh[p2]);
      *(u32*)&smem[rb] = pkrtz(a * cv - b2 * sv, fmaf(b2, cv, a * sv));
      a = h2f_u(kl[p2]); b2 = h2f_u(kh[p2]);
      *(u32*)&smem[9216 + rb] = pkrtz(a * cv - b2 * sv, fmaf(b2, cv, a * sv));
    }
  }
  // ---- staged load v -> transposed [d][j], ushort8 loads ----
  #pragma unroll
  for (int rep = 0; rep < 2; rep++){
    int idx2 = rep * 512 + tid;                   // 0..1023
    if (AXIS != 2){
      int i = idx2 & 31, f = idx2 >> 5;           // f 0..31
      size_t go = base + (size_t)f * THW_ + (size_t)i * SS;
      us8_t vv = *(const us8_t*)(vp + go);
      #pragma unroll
      for (int g = 0; g < 8; g++) smem[18432 + g * 1152 + f * 36 + i] = vv[g];
    } else {
      int i8 = (idx2 & 3) * 8, g = (idx2 >> 2) & 7, f = idx2 >> 5;
      size_t go = base + (size_t)f * THW_ + (size_t)g * GS + i8;
      us8_t vv = *(const us8_t*)(vp + go);
      int rb = 18432 + g * 1152 + f * 36 + i8;
      ushort4 lo, hi;
      lo.x = vv[0]; lo.y = vv[1]; lo.z = vv[2]; lo.w = vv[3];
      hi.x = vv[4]; hi.y = vv[5]; hi.z = vv[6]; hi.w = vv[7];
      *(ushort4*)&smem[rb] = lo;
      *(ushort4*)&smem[rb + 4] = hi;
    }
  }
  __syncthreads();

  const int lane = tid & 63;
  const int seq = tid >> 6;                       // 0..7
  const int m = lane & 15, kg = lane >> 4;

  h8_t aQ[2], bK[2], bV[2];
  #pragma unroll
  for (int t2 = 0; t2 < 2; t2++){
    union { ushort4 u4[2]; h8_t h; } uq, uk, uv;
    int rq = seq * 1152 + (t2 * 16 + m) * 36 + kg * 8;
    uq.u4[0] = *(const ushort4*)&smem[rq];
    uq.u4[1] = *(const ushort4*)&smem[rq + 4];
    uk.u4[0] = *(const ushort4*)&smem[9216 + rq];
    uk.u4[1] = *(const ushort4*)&smem[9216 + rq + 4];
    uv.u4[0] = *(const ushort4*)&smem[18432 + rq];
    uv.u4[1] = *(const ushort4*)&smem[18432 + rq + 4];
    aQ[t2] = uq.h; bK[t2] = uk.h; bV[t2] = uv.h;
  }

  f4_t st[2][2];
  #pragma unroll
  for (int tk = 0; tk < 2; tk++)
    #pragma unroll
    for (int tq = 0; tq < 2; tq++){
      st[tk][tq] = (f4_t)0.f;
      st[tk][tq] = __builtin_amdgcn_mfma_f32_16x16x32_f16(bK[tk], aQ[tq], st[tk][tq], 0, 0, 0);
    }

  u32 pkk[2][2][2];             // [tq][tk][pair]
  #pragma unroll
  for (int tq = 0; tq < 2; tq++){
    const int i = tq * 16 + m;
    float e[2][4];
    float mx = -3.0e38f;
    #pragma unroll
    for (int tk = 0; tk < 2; tk++)
      #pragma unroll
      for (int r = 0; r < 4; r++){
        float s = st[tk][tq][r] * 0.17677669529663687f;
        if (AXIS == 0 && (tk * 16 + kg * 4 + r) > i) s = -1e30f;
        e[tk][r] = s;
        mx = fmaxf(mx, s);
      }
    mx = fmaxf(mx, __shfl_xor(mx, 16));
    mx = fmaxf(mx, __shfl_xor(mx, 32));
    float sum = 0.f;
    #pragma unroll
    for (int tk = 0; tk < 2; tk++)
      #pragma unroll
      for (int r = 0; r < 4; r++){
        e[tk][r] = __expf(e[tk][r] - mx);
        sum += e[tk][r];
      }
    sum += __shfl_xor(sum, 16);
    sum += __shfl_xor(sum, 32);
    float rinv = 1.f / sum;
    #pragma unroll
    for (int tk = 0; tk < 2; tk++){
      pkk[tq][tk][0] = pkrtz(e[tk][0] * rinv, e[tk][1] * rinv);
      pkk[tq][tk][1] = pkrtz(e[tk][2] * rinv, e[tk][3] * rinv);
    }
  }

  h8_t aP[2];
  #pragma unroll
  for (int tq = 0; tq < 2; tq++){
    union { u32 w[4]; h8_t h; } uu;
    #pragma unroll
    for (int w = 0; w < 4; w++){
      int srcLane = ((kg & 1) * 2 + (w >> 1)) * 16 + m;
      u32 v0 = __shfl(pkk[tq][0][w & 1], srcLane);
      u32 v1 = __shfl(pkk[tq][1][w & 1], srcLane);
      uu.w[w] = (kg >= 2) ? v1 : v0;
    }
    aP[tq] = uu.h;
  }

  f4_t o_[2][2];
  #pragma unroll
  for (int tq = 0; tq < 2; tq++)
    #pragma unroll
    for (int td = 0; td < 2; td++){
      o_[tq][td] = (f4_t)0.f;
      o_[tq][td] = __builtin_amdgcn_mfma_f32_16x16x32_f16(aP[tq], bV[td], o_[tq][td], 0, 0, 0);
    }

  // ---- O over own-seq V region [d][i] (wave-local; bV already in registers) ----
  #pragma unroll
  for (int tq = 0; tq < 2; tq++)
    #pragma unroll
    for (int td = 0; td < 2; td++){
      int i0 = tq * 16 + kg * 4, d = td * 16 + m;
      union { u32 w[2]; ushort4 v; } pk2;
      pk2.w[0] = pkrtz(o_[tq][td][0], o_[tq][td][1]);
      pk2.w[1] = pkrtz(o_[tq][td][2], o_[tq][td][3]);
      *(ushort4*)&smem[18432 + seq * 1152 + d * 36 + i0] = pk2.v;
    }
  __syncthreads();

  // ---- staged store, ushort8 ----
  #pragma unroll
  for (int rep = 0; rep < 2; rep++){
    int idx2 = rep * 512 + tid;                   // 0..1023
    if (AXIS != 2){
      int i2 = idx2 & 31, f = idx2 >> 5;          // f 0..31
      us8_t ov;
      #pragma unroll
      for (int g = 0; g < 8; g++) ov[g] = smem[18432 + g * 1152 + f * 36 + i2];
      size_t go = base + (size_t)f * THW_ + (size_t)i2 * SS;
      *(us8_t*)(ctx + go) = ov;
    } else {
      int i8 = (idx2 & 3) * 8, g2 = (idx2 >> 2) & 7, f = idx2 >> 5;
      int rb = 18432 + g2 * 1152 + f * 36 + i8;
      ushort4 lo = *(const ushort4*)&smem[rb];
      ushort4 hi = *(const ushort4*)&smem[rb + 4];
      us8_t ov;
      ov[0] = lo.x; ov[1] = lo.y; ov[2] = lo.z; ov[3] = lo.w;
      ov[4] = hi.x; ov[5] = hi.y; ov[6] = hi.z; ov[7] = hi.w;
      size_t go = base + (size_t)f * THW_ + (size_t)g2 * GS + i8;
      *(us8_t*)(ctx + go) = ov;
    }
  }
}

// ---------------- fused attention dispatcher: all 3 axes, 6144 blocks x 512 threads ---------
__global__ __launch_bounds__(512) void k_attn_all(
    const __half* __restrict__ qg_, const __half* __restrict__ kg_,
    const __half* __restrict__ vg_,
    __half* __restrict__ ctx_t, __half* __restrict__ ctx_h, __half* __restrict__ ctx_w,
    const float* __restrict__ cosT, const float* __restrict__ sinT)
{
  __shared__ __align__(16) unsigned short smem[27648];   // 55.3 KB
  int ax = blockIdx.x >> 11;
  int id = blockIdx.x & 2047;
  const unsigned short* qp = (const unsigned short*)qg_;
  const unsigned short* kp = (const unsigned short*)kg_;
  const unsigned short* vp = (const unsigned short*)vg_;
  if (ax == 0)      attn_body<0>(id, smem, qp, kp, vp, (unsigned short*)ctx_t, cosT, sinT);
  else if (ax == 1) attn_body<1>(id, smem, qp, kp, vp, (unsigned short*)ctx_h, cosT, sinT);
  else              attn_body<2>(id, smem, qp, kp, vp, (unsigned short*)ctx_w, cosT, sinT);
}

extern "C" void kernel_launch(void* const* d_in, const int* in_sizes, int n_in,
                              void* d_out, int out_size, void* d_ws, size_t ws_size,
                              hipStream_t stream)
{
  (void)in_sizes; (void)n_in; (void)out_size; (void)ws_size;
  const float* x       = (const float*)d_in[0];
  const float* w_qkv   = (const float*)d_in[1];
  const float* wk_bank = (const float*)d_in[2];
  const float* wv_bank = (const float*)d_in[3];
  const float* pre_w   = (const float*)d_in[4];
  const float* pre_b   = (const float*)d_in[5];
  const float* cw      = (const float*)d_in[6];
  const float* cb      = (const float*)d_in[7];
  const float* gate_w  = (const float*)d_in[8];
  const float* gate_b  = (const float*)d_in[9];
  const float* proj_w  = (const float*)d_in[10];

  const size_t SZ = (size_t)B_ * C_ * THW_;           // 16,777,216 elems
  __half* hb = (__half*)d_ws;                         // 32MB slots
  unsigned short* xT  = (unsigned short*)(hb + 0 * SZ);  // bf16, alive to gate
  __half* qH   = hb + 1 * SZ;                         // q
  __half* kH   = hb + 2 * SZ;                         // k -> ctx_t
  __half* vH   = hb + 3 * SZ;                         // v -> ctx_h
  __half* koH  = hb + 4 * SZ;                         // k_out -> yT(bf16)
  __half* voH  = hb + 5 * SZ;                         // v_out (stays valid)
  __half* ctxtH = kH;
  __half* ctxhH = vH;
  __half* ctxwH = (__half*)d_out;                     // ctx_w in d_out (dead until proj)
  unsigned short* yT = (unsigned short*)koH;          // over dead k_out
  float* sm    = (float*)(hb + 6 * SZ);               // smalls
  float* qg    = sm;                                  // 16384
  float* hbuf  = qg + 16384;                          // 16384
  float* alpha = hbuf + 16384;                        // 192
  float* cosT  = alpha + 192;                         // 512
  float* sinT  = cosT + 512;                          // 512
  unsigned short* wB = (unsigned short*)(sinT + 512); // 1792*256 bf16 (896 KB)
  unsigned short* wBq = wB;                           // [768][256]
  unsigned short* wBg = wB + 768 * 256;               // [768][256]
  unsigned short* wBp = wB + 1536 * 256;              // [256][256]

  k_rope_table<<<1, 512, 0, stream>>>(cosT, sinT);
  k_wcvt<<<1792, 256, 0, stream>>>(w_qkv, gate_w, proj_w, wB);
  k_transpose_cvt<float><<<dim3(512, 4, 2), 256, 0, stream>>>(x, xT);

  k_mfma_qkv<<<dim3(6, 256, 2), 256, 0, stream>>>(wBq, xT, qH, kH, vH);

  k_mean_hw<<<16384, 256, 0, stream>>>(qH, qg);
  k_mix_pre<<<64, 256, 0, stream>>>(pre_w, pre_b, qg, hbuf);
  k_mix_alpha<<<64, 256, 0, stream>>>(cw, cb, hbuf, alpha);

  k_conv_both<<<32768, 256, 0, stream>>>(kH, vH, wk_bank, wv_bank, alpha, koH, voH);

  k_attn_all<<<6144, 512, 0, stream>>>(qH, koH, voH, ctxtH, ctxhH, ctxwH, cosT, sinT);

  k_mfma_gate2<<<dim3(4, 512, 2), 256, 0, stream>>>(wBg, xT, gate_b,
                                                    ctxtH, ctxhH, ctxwH, yT); // yT over dead k_out
  k_mfma_proj<<<dim3(2, 256, 2), 256, 0, stream>>>(wBp, yT, (float*)d_out);
}

// Round 13
// 366.356 us; speedup vs baseline: 5.9161x; 1.1389x over previous
//
#include <hip/hip_runtime.h>
#include <hip/hip_fp16.h>
#include <math.h>

#define B_   2
#define C_   256
#define T_   32
#define HW_  1024
#define THW_ 32768

using u32 = unsigned int;
typedef __attribute__((ext_vector_type(8))) short bf8_t;   // 8 bf16 in 4 VGPRs
typedef __attribute__((ext_vector_type(8))) unsigned short us8_t;
typedef __attribute__((ext_vector_type(8))) _Float16 h8_t; // 8 f16 in 4 VGPRs
typedef __attribute__((ext_vector_type(2))) __fp16 fp16v2; // builtin cvt_pkrtz return type
typedef __attribute__((ext_vector_type(4))) float f4_t;

static __device__ __forceinline__ unsigned short f2bf(float x){
  u32 u = __float_as_uint(x);
  u32 r = (u + 0x7FFF + ((u >> 16) & 1)) >> 16;   // RNE
  return (unsigned short)r;
}
static __device__ __forceinline__ float h2f_u(unsigned short u){
  union { __half h; unsigned short us; } cv; cv.us = u; return __half2float(cv.h);
}
static __device__ __forceinline__ unsigned short f2h_u(float f){
  union { __half h; unsigned short us; } cv; cv.h = __float2half(f); return cv.us;
}
static __device__ __forceinline__ u32 pkrtz(float a, float b){
  union { fp16v2 h; u32 w; } cv; cv.h = __builtin_amdgcn_cvt_pkrtz(a, b); return cv.w;
}
static __device__ __forceinline__ float ldf(const float* p){ return *p; }
static __device__ __forceinline__ float ldf(const __half* p){ return __half2float(*p); }

// ---------------- rope table ----------------
__global__ void k_rope_table(float* __restrict__ cosT, float* __restrict__ sinT){
  int tid = threadIdx.x;            // 512 threads, tid = i*16+u
  int i = tid >> 4, u = tid & 15;
  float invf = powf(10000.f, -(2.f * (float)u) / 32.f);
  float s, c;
  sincosf((float)i * invf, &s, &c);
  cosT[tid] = c;
  sinT[tid] = s;
}

// ---------------- weight cvt: stack w_qkv(768), gate_w(768), proj_w(256) as bf16 [1792][256] --
__global__ void k_wcvt(const float* __restrict__ w_qkv, const float* __restrict__ gate_w,
                       const float* __restrict__ proj_w, unsigned short* __restrict__ out){
  int row = blockIdx.x, c = threadIdx.x;
  const float* src = (row < 768) ? w_qkv + (size_t)row * 256
                   : (row < 1536) ? gate_w + (size_t)(row - 768) * 256
                                  : proj_w + (size_t)(row - 1536) * 256;
  out[(size_t)row * 256 + c] = f2bf(src[c]);
}

// ---------------- transpose+cvt: [b][256][THW] f32 -> bf16 [b][THW][256] ----------------
template<typename InT>
__global__ __launch_bounds__(256) void k_transpose_cvt(
    const InT* __restrict__ in, unsigned short* __restrict__ outT)
{
  __shared__ float tile[64][65];
  int s0 = blockIdx.x * 64;     // 512
  int c0 = blockIdx.y * 64;     // 4
  int b  = blockIdx.z;
  int tid = threadIdx.x;
  for (int idx = tid; idx < 4096; idx += 256){
    int c = idx >> 6, s = idx & 63;
    tile[c][s] = ldf(&in[((size_t)(b * C_ + c0 + c)) * THW_ + s0 + s]);
  }
  __syncthreads();
  for (int idx = tid; idx < 4096; idx += 256){
    int s = idx >> 6, c = idx & 63;
    outT[((size_t)b * THW_ + s0 + s) * 256 + c0 + c] = f2bf(tile[c][s]);
  }
}

// ---------------- MFMA GEMM core (bf16 A bank): 128xBN tile, K=256 ----------------
template<int BN>
static __device__ __forceinline__ void gemm_core_b(
    const unsigned short* __restrict__ A, int o0,
    const unsigned short* __restrict__ BT,   // pre-offset: + (b*THW + s0)*256
    unsigned short* As, unsigned short* Bs, f4_t acc[4][BN / 32])
{
  const int tid = threadIdx.x;
  const int lane = tid & 63, wv = tid >> 6;
  const int wm = wv >> 1, wn = wv & 1;
  const int m = lane & 15, kg = lane >> 4;
  const int arow = tid >> 1, aseg = (tid & 1) * 64;     // A: 128 rows, 2 thr/row, 64B each
  const int brow = (BN == 128) ? (tid >> 1) : (tid >> 2);
  const int bseg = (BN == 128) ? (tid & 1) * 64 : (tid & 3) * 32;
  for (int ks = 0; ks < 4; ks++){
    __syncthreads();                                    // protect prior reads
    {
      const unsigned short* ga = A + (size_t)(o0 + arow) * 256 + ks * 64 + aseg / 2;
      #pragma unroll
      for (int q2 = 0; q2 < 4; q2++){
        us8_t v = *(const us8_t*)(ga + q2 * 8);
        *(us8_t*)((char*)As + arow * 128 + ((aseg + q2 * 16) ^ ((arow & 7) << 4))) = v;
      }
      const unsigned short* gb = BT + (size_t)brow * 256 + ks * 64 + bseg / 2;
      #pragma unroll
      for (int q2 = 0; q2 < (BN == 128 ? 4 : 2); q2++){
        us8_t v = *(const us8_t*)(gb + q2 * 8);
        *(us8_t*)((char*)Bs + brow * 128 + ((bseg + q2 * 16) ^ ((brow & 7) << 4))) = v;
      }
    }
    __syncthreads();
    #pragma unroll
    for (int kk = 0; kk < 2; kk++){
      bf8_t af[4], bfr[BN / 32];
      #pragma unroll
      for (int mi = 0; mi < 4; mi++){
        int row = wm * 64 + mi * 16 + m;
        af[mi] = *(const bf8_t*)((const char*)As + row * 128 + ((kk * 64 + kg * 16) ^ ((row & 7) << 4)));
      }
      #pragma unroll
      for (int ni = 0; ni < BN / 32; ni++){
        int row = wn * (BN / 2) + ni * 16 + m;
        bfr[ni] = *(const bf8_t*)((const char*)Bs + row * 128 + ((kk * 64 + kg * 16) ^ ((row & 7) << 4)));
      }
      #pragma unroll
      for (int mi = 0; mi < 4; mi++)
        #pragma unroll
        for (int ni = 0; ni < BN / 32; ni++)
          acc[mi][ni] = __builtin_amdgcn_mfma_f32_16x16x32_bf16(af[mi], bfr[ni], acc[mi][ni], 0, 0, 0);
    }
  }
}

// ---------------- qkv GEMM: Wq(bf16)[768][256] @ x -> q,k,v (f16) ----------------
__global__ __launch_bounds__(256) void k_mfma_qkv(
    const unsigned short* __restrict__ Wb, const unsigned short* __restrict__ xT,
    __half* __restrict__ q, __half* __restrict__ k, __half* __restrict__ v)
{
  __shared__ unsigned short As[8192], Bs[8192];
  const int bo = blockIdx.x;                  // 0..5
  const int s0 = blockIdx.y * 128;            // 256
  const int b  = blockIdx.z;
  f4_t acc[4][4];
  #pragma unroll
  for (int mi = 0; mi < 4; mi++)
    #pragma unroll
    for (int ni = 0; ni < 4; ni++) acc[mi][ni] = (f4_t)0.f;
  gemm_core_b<128>(Wb, bo * 128, xT + ((size_t)b * THW_ + s0) * 256, As, Bs, acc);
  __half* outp = (bo < 2) ? q : (bo < 4) ? k : v;
  const int ro = (bo & 1) * 128;
  const int lane = threadIdx.x & 63, wv = threadIdx.x >> 6;
  const int wm = wv >> 1, wn = wv & 1;
  size_t obase = (size_t)(b * C_) * THW_;
  #pragma unroll
  for (int mi = 0; mi < 4; mi++)
    #pragma unroll
    for (int ni = 0; ni < 4; ni++)
      #pragma unroll
      for (int r = 0; r < 4; r++){
        int o = ro + wm * 64 + mi * 16 + (lane >> 4) * 4 + r;
        int s = s0 + wn * 64 + ni * 16 + (lane & 15);
        outp[obase + (size_t)o * THW_ + s] = __float2half(acc[mi][ni][r]);
      }
}

// ---------------- gate GEMM + sigmoid + combine, 3 slices interleaved, yT(bf16) direct ------
__global__ __launch_bounds__(256) void k_mfma_gate2(
    const unsigned short* __restrict__ Wb,   // bf16 gate bank [768][256]
    const unsigned short* __restrict__ xT,
    const float* __restrict__ gb,
    const __half* __restrict__ ctx_t, const __half* __restrict__ ctx_h,
    const __half* __restrict__ ctx_w,
    unsigned short* __restrict__ yT)         // bf16 [b][THW][256]
{
  __shared__ unsigned short As3[12288];
  __shared__ unsigned short Bs[4096];
  const int bo = blockIdx.x;                  // 0..3
  const int s0 = blockIdx.y * 64;
  const int b  = blockIdx.z;
  const int tid = threadIdx.x;
  const int lane = tid & 63, wv = tid >> 6;
  const int wm = wv >> 1, wn = wv & 1;
  const int m = lane & 15, kg = lane >> 4;
  const unsigned short* xbase = xT + ((size_t)b * THW_ + s0) * 256;

  f4_t acc[3][2][2];
  #pragma unroll
  for (int sl = 0; sl < 3; sl++)
    #pragma unroll
    for (int mi = 0; mi < 2; mi++)
      #pragma unroll
      for (int ni = 0; ni < 2; ni++) acc[sl][mi][ni] = (f4_t)0.f;

  for (int ks = 0; ks < 4; ks++){
    __syncthreads();
    #pragma unroll
    for (int rep = 0; rep < 2; rep++){
      int idx = rep * 256 + tid;              // 0..511
      int row = idx >> 3, seg = idx & 7;
      us8_t v = *(const us8_t*)(xbase + (size_t)row * 256 + ks * 64 + seg * 8);
      *(us8_t*)((char*)Bs + row * 128 + ((seg * 16) ^ ((row & 7) << 4))) = v;
    }
    #pragma unroll
    for (int sl = 0; sl < 3; sl++){
      #pragma unroll
      for (int rep = 0; rep < 2; rep++){
        int idx = rep * 256 + tid;
        int row = idx >> 3, seg = idx & 7;
        us8_t v = *(const us8_t*)(Wb + (size_t)(sl * 256 + bo * 64 + row) * 256 + ks * 64 + seg * 8);
        *(us8_t*)((char*)As3 + sl * 8192 + row * 128 + ((seg * 16) ^ ((row & 7) << 4))) = v;
      }
    }
    __syncthreads();
    #pragma unroll
    for (int kk = 0; kk < 2; kk++){
      bf8_t bfr[2], af[3][2];
      #pragma unroll
      for (int ni = 0; ni < 2; ni++){
        int row = wn * 32 + ni * 16 + m;
        bfr[ni] = *(const bf8_t*)((const char*)Bs + row * 128 + ((kk * 64 + kg * 16) ^ ((row & 7) << 4)));
      }
      #pragma unroll
      for (int sl = 0; sl < 3; sl++)
        #pragma unroll
        for (int mi = 0; mi < 2; mi++){
          int row = wm * 32 + mi * 16 + m;
          af[sl][mi] = *(const bf8_t*)((const char*)As3 + sl * 8192 + row * 128 + ((kk * 64 + kg * 16) ^ ((row & 7) << 4)));
        }
      #pragma unroll
      for (int sl = 0; sl < 3; sl++)
        #pragma unroll
        for (int mi = 0; mi < 2; mi++)
          #pragma unroll
          for (int ni = 0; ni < 2; ni++)
            acc[sl][mi][ni] = __builtin_amdgcn_mfma_f32_16x16x32_bf16(af[sl][mi], bfr[ni], acc[sl][mi][ni], 0, 0, 0);
    }
  }

  const size_t obase = (size_t)(b * C_) * THW_;
  f4_t yacc[2][2];
  #pragma unroll
  for (int mi = 0; mi < 2; mi++)
    #pragma unroll
    for (int ni = 0; ni < 2; ni++) yacc[mi][ni] = (f4_t)0.f;
  #pragma unroll
  for (int sl = 0; sl < 3; sl++){
    const __half* ctx = (sl == 0) ? ctx_t : (sl == 1) ? ctx_h : ctx_w;
    #pragma unroll
    for (int mi = 0; mi < 2; mi++)
      #pragma unroll
      for (int ni = 0; ni < 2; ni++)
        #pragma unroll
        for (int r = 0; r < 4; r++){
          int ol = wm * 32 + mi * 16 + kg * 4 + r;
          int s  = s0 + wn * 32 + ni * 16 + m;
          float lg = acc[sl][mi][ni][r] + gb[sl * 256 + bo * 64 + ol];
          float g = __builtin_amdgcn_rcpf(1.f + __expf(-lg));
          yacc[mi][ni][r] += g * __half2float(ctx[obase + (size_t)(bo * 64 + ol) * THW_ + s]);
        }
  }

  __syncthreads();
  unsigned short* tile = As3;
  #pragma unroll
  for (int mi = 0; mi < 2; mi++)
    #pragma unroll
    for (int ni = 0; ni < 2; ni++){
      int ol = wm * 32 + mi * 16 + kg * 4;
      int sl2 = wn * 32 + ni * 16 + m;
      ushort4 w4;
      w4.x = f2bf(yacc[mi][ni][0]);
      w4.y = f2bf(yacc[mi][ni][1]);
      w4.z = f2bf(yacc[mi][ni][2]);
      w4.w = f2bf(yacc[mi][ni][3]);
      *(ushort4*)&tile[sl2 * 72 + ol] = w4;
    }
  __syncthreads();
  {
    int sr = tid >> 2, oc = (tid & 3) * 16;
    us8_t v0 = *(const us8_t*)&tile[sr * 72 + oc];
    us8_t v1 = *(const us8_t*)&tile[sr * 72 + oc + 8];
    unsigned short* dst = yT + ((size_t)b * THW_ + s0 + sr) * 256 + bo * 64 + oc;
    *(us8_t*)dst = v0;
    *(us8_t*)(dst + 8) = v1;
  }
}

// ---------------- proj GEMM -> d_out (f32) ----------------
__global__ __launch_bounds__(256) void k_mfma_proj(
    const unsigned short* __restrict__ Wb, const unsigned short* __restrict__ yT,
    float* __restrict__ out)
{
  __shared__ unsigned short As[8192], Bs[8192];
  const int bo = blockIdx.x;                  // 0..1
  const int s0 = blockIdx.y * 128;
  const int b  = blockIdx.z;
  f4_t acc[4][4];
  #pragma unroll
  for (int mi = 0; mi < 4; mi++)
    #pragma unroll
    for (int ni = 0; ni < 4; ni++) acc[mi][ni] = (f4_t)0.f;
  gemm_core_b<128>(Wb, bo * 128, yT + ((size_t)b * THW_ + s0) * 256, As, Bs, acc);
  const int lane = threadIdx.x & 63, wv = threadIdx.x >> 6;
  const int wm = wv >> 1, wn = wv & 1;
  size_t obase = (size_t)(b * C_) * THW_;
  #pragma unroll
  for (int mi = 0; mi < 4; mi++)
    #pragma unroll
    for (int ni = 0; ni < 4; ni++)
      #pragma unroll
      for (int r = 0; r < 4; r++){
        int o = bo * 128 + wm * 64 + mi * 16 + (lane >> 4) * 4 + r;
        int s = s0 + wn * 64 + ni * 16 + (lane & 15);
        out[obase + (size_t)o * THW_ + s] = acc[mi][ni][r];
      }
}

// ---------------- mean over (H,W): qg[b,c,t] (q is f16) ----------------
__global__ __launch_bounds__(256) void k_mean_hw(const __half* __restrict__ q, float* __restrict__ qg){
  int bct = blockIdx.x;
  const __half2* p = (const __half2*)(q + (size_t)bct * HW_);
  __half2 v0 = p[threadIdx.x * 2], v1 = p[threadIdx.x * 2 + 1];
  float sum = __low2float(v0) + __high2float(v0) + __low2float(v1) + __high2float(v1);
  #pragma unroll
  for (int off = 32; off; off >>= 1) sum += __shfl_down(sum, off);
  __shared__ float red[4];
  int lane = threadIdx.x & 63, w = threadIdx.x >> 6;
  if (lane == 0) red[w] = sum;
  __syncthreads();
  if (threadIdx.x == 0) qg[bct] = (red[0] + red[1] + red[2] + red[3]) * (1.f / 1024.f);
}

// ---------------- mix pre: h = gelu(pre_w @ qg + pre_b) ----------------
__global__ __launch_bounds__(256) void k_mix_pre(const float* __restrict__ preW, const float* __restrict__ preB,
    const float* __restrict__ qg, float* __restrict__ hbuf){
  int b = blockIdx.x >> 5, t = blockIdx.x & 31;
  int o = threadIdx.x;
  __shared__ float qgl[256];
  qgl[o] = qg[((size_t)(b * C_ + o)) * T_ + t];
  __syncthreads();
  float a = preB[o];
  for (int c = 0; c < C_; c++) a = fmaf(preW[o * C_ + c], qgl[c], a);
  float g = 0.5f * a * (1.f + erff(a * 0.70710678118f));
  hbuf[((size_t)(b * C_ + o)) * T_ + t] = g;
}

// ---------------- mix logits + softmax over m ----------------
__global__ __launch_bounds__(256) void k_mix_alpha(const float* __restrict__ cw, const float* __restrict__ cb,
    const float* __restrict__ hbuf, float* __restrict__ alpha){
  int b = blockIdx.x >> 5, t = blockIdx.x & 31;
  int c = threadIdx.x;
  float hv[3];
  #pragma unroll
  for (int j = 0; j < 3; j++){
    int tt = t - 2 + j;
    hv[j] = (tt >= 0) ? hbuf[((size_t)(b * C_ + c)) * T_ + tt] : 0.f;
  }
  float p[3];
  #pragma unroll
  for (int m = 0; m < 3; m++){
    const float* w = cw + ((size_t)m * C_ + c) * 3;
    p[m] = w[0] * hv[0] + w[1] * hv[1] + w[2] * hv[2];
  }
  #pragma unroll
  for (int m = 0; m < 3; m++){
    #pragma unroll
    for (int off = 32; off; off >>= 1) p[m] += __shfl_down(p[m], off);
  }
  __shared__ float red[3][4];
  int lane = threadIdx.x & 63, w = threadIdx.x >> 6;
  if (lane == 0){ red[0][w] = p[0]; red[1][w] = p[1]; red[2][w] = p[2]; }
  __syncthreads();
  if (threadIdx.x == 0){
    float lg[3];
    #pragma unroll
    for (int m = 0; m < 3; m++) lg[m] = red[m][0] + red[m][1] + red[m][2] + red[m][3] + cb[m];
    float mx = fmaxf(lg[0], fmaxf(lg[1], lg[2]));
    float e0 = __expf(lg[0] - mx), e1 = __expf(lg[1] - mx), e2 = __expf(lg[2] - mx);
    float r = 1.f / (e0 + e1 + e2);
    alpha[((size_t)(b * 3 + 0)) * T_ + t] = e0 * r;
    alpha[((size_t)(b * 3 + 1)) * T_ + t] = e1 * r;
    alpha[((size_t)(b * 3 + 2)) * T_ + t] = e2 * r;
  }
}

// ---------------- alpha-mixed causal depthwise conv 3x3x3, k AND v fused in one block --------
// grid 16384 (c + 256*t + 8192*b), block 256. LDS: 2 tensors x [3][34] rows x 35 f32 (stride 35,
// odd -> conflict-light). Row-wise vectorized staging (ushort8 x2 = 16B loads), zero div/mod.
__global__ __launch_bounds__(256) void k_conv_mix2(
    const __half* __restrict__ kin, const __half* __restrict__ vin,
    const float* __restrict__ wkb, const float* __restrict__ wvb,
    const float* __restrict__ alpha,
    __half* __restrict__ kout, __half* __restrict__ vout)
{
  int bi = blockIdx.x;
  int c = bi & 255, t = (bi >> 8) & 31, b = bi >> 13;
  __shared__ float sK[3 * 34 * 35];    // 3570 f32
  __shared__ float sV[3 * 34 * 35];
  __shared__ float wmix[2][27];
  const int tid = threadIdx.x;
  if (tid < 54){
    int which = (tid >= 27) ? 1 : 0;
    int tap = tid - 27 * which;
    const float* bank = which ? wvb : wkb;
    float sum = 0.f;
    #pragma unroll
    for (int m = 0; m < 3; m++)
      sum += alpha[((size_t)(b * 3 + m)) * T_ + t] * bank[((size_t)m * C_ + c) * 27 + tap];
    wmix[which][tap] = sum;
  }
  const size_t cbase = ((size_t)(b * C_ + c)) * T_;

  // staging: 408 jobs = 2 tensors x 102 rows x 2 halves
  #pragma unroll
  for (int rep = 0; rep < 2; rep++){
    int job = rep * 256 + tid;
    if (job < 408){
      int half = job & 1;
      int rr = job >> 1;                    // 0..203
      int which = (rr >= 102) ? 1 : 0;
      int r = rr - 102 * which;             // 0..101
      int tp = (r >= 68) ? 2 : (r >= 34) ? 1 : 0;
      int yy = r - 34 * tp;                 // 0..33
      int tin = t - 2 + tp;
      float* dst = (which ? sV : sK) + tp * 1190 + yy * 35 + 1 + half * 16;
      bool ok = (tin >= 0) && (yy >= 1) && (yy <= 32);
      if (ok){
        const unsigned short* src = (const unsigned short*)((which ? vin : kin)
                                  + (cbase + tin) * HW_ + (size_t)(yy - 1) * 32 + half * 16);
        us8_t v0 = *(const us8_t*)src;
        us8_t v1 = *(const us8_t*)(src + 8);
        #pragma unroll
        for (int j = 0; j < 8; j++) dst[j] = h2f_u(v0[j]);
        #pragma unroll
        for (int j = 0; j < 8; j++) dst[j + 8] = h2f_u(v1[j]);
      } else {
        #pragma unroll
        for (int j = 0; j < 16; j++) dst[j] = 0.f;
      }
      if (half == 0) dst[-1] = 0.f;         // col 0  (x = -1 pad)
      else           dst[16] = 0.f;         // col 33 (x = 32 pad)
    }
  }
  __syncthreads();

  const int y = tid >> 3, x0 = (tid & 7) * 4;
  #pragma unroll
  for (int which = 0; which < 2; which++){
    const float* buf = which ? sV : sK;
    const float* wm = wmix[which];
    float a[4] = {0.f, 0.f, 0.f, 0.f};
    #pragma unroll
    for (int dt = 0; dt < 3; dt++){
      #pragma unroll
      for (int dy = 0; dy < 3; dy++){
        const float* row = buf + dt * 1190 + (y + dy) * 35 + x0;  // col x0 == x index x0-1
        float w0 = wm[dt * 9 + dy * 3 + 0];
        float w1 = wm[dt * 9 + dy * 3 + 1];
        float w2 = wm[dt * 9 + dy * 3 + 2];
        float c0 = row[0], c1 = row[1], c2 = row[2];
        float c3 = row[3], c4 = row[4], c5 = row[5];
        a[0] = fmaf(w0, c0, fmaf(w1, c1, fmaf(w2, c2, a[0])));
        a[1] = fmaf(w0, c1, fmaf(w1, c2, fmaf(w2, c3, a[1])));
        a[2] = fmaf(w0, c2, fmaf(w1, c3, fmaf(w2, c4, a[2])));
        a[3] = fmaf(w0, c3, fmaf(w1, c4, fmaf(w2, c5, a[3])));
      }
    }
    size_t ob = (cbase + t) * HW_ + (size_t)y * 32 + x0;
    ushort4 o4;
    o4.x = f2h_u(a[0]); o4.y = f2h_u(a[1]);
    o4.z = f2h_u(a[2]); o4.w = f2h_u(a[3]);
    *(ushort4*)((unsigned short*)(which ? vout : kout) + ob) = o4;
  }
}

// ---------------- axial attention body (MFMA), 8 waves/block, one seq per wave ----------------
template<int AXIS>
static __device__ __forceinline__ void attn_body(
    int id, unsigned short* smem,
    const unsigned short* __restrict__ qp, const unsigned short* __restrict__ kp,
    const unsigned short* __restrict__ vp, unsigned short* ctx,
    const float* __restrict__ cosT, const float* __restrict__ sinT)
{
  const int SS = (AXIS == 0) ? HW_ : (AXIS == 1) ? 32 : 1;
  const int GS = (AXIS == 2) ? 32 : 1;
  const int OS = (AXIS == 0) ? 32 : HW_;
  int ggrp = (id >> 3) & 3;
  int rest = ((id >> 5) << 3) | (id & 7);
  int outer = rest & 31;
  int head = (rest >> 5) & 7;
  int b = rest >> 8;
  const size_t base = ((size_t)(b * C_ + head * 32)) * THW_ + (size_t)outer * OS + (size_t)(ggrp * 8) * GS;
  const int tid = threadIdx.x;                    // 0..511

  if (AXIS != 2){
    int i = tid & 31, u = tid >> 5;
    size_t glo = base + (size_t)u * THW_ + (size_t)i * SS;
    size_t ghi = glo + (size_t)16 * THW_;
    us8_t ql = *(const us8_t*)(qp + glo), qh = *(const us8_t*)(qp + ghi);
    us8_t kl = *(const us8_t*)(kp + glo), kh = *(const us8_t*)(kp + ghi);
    float cv = cosT[i * 16 + u], sv = sinT[i * 16 + u];
    #pragma unroll
    for (int g = 0; g < 8; g++){
      int rb = g * 1152 + i * 36 + 2 * u;
      float a = h2f_u(ql[g]), b2 = h2f_u(qh[g]);
      *(u32*)&smem[rb] = pkrtz(a * cv - b2 * sv, fmaf(b2, cv, a * sv));
      a = h2f_u(kl[g]); b2 = h2f_u(kh[g]);
      *(u32*)&smem[9216 + rb] = pkrtz(a * cv - b2 * sv, fmaf(b2, cv, a * sv));
    }
  } else {
    int i8 = (tid & 3) * 8, g = (tid >> 2) & 7, u = tid >> 5;
    size_t glo = base + (size_t)u * THW_ + (size_t)g * GS + i8;
    size_t ghi = glo + (size_t)16 * THW_;
    us8_t ql = *(const us8_t*)(qp + glo), qh = *(const us8_t*)(qp + ghi);
    us8_t kl = *(const us8_t*)(kp + glo), kh = *(const us8_t*)(kp + ghi);
    #pragma unroll
    for (int p2 = 0; p2 < 8; p2++){
      int i = i8 + p2;
      int rb = g * 1152 + i * 36 + 2 * u;
      float cv = cosT[i * 16 + u], sv = sinT[i * 16 + u];
      float a = h2f_u(ql[p2]), b2 = h2f_u(qh[p2]);
      *(u32*)&smem[rb] = pkrtz(a * cv - b2 * sv, fmaf(b2, cv, a * sv));
      a = h2f_u(kl[p2]); b2 = h2f_u(kh[p2]);
      *(u32*)&smem[9216 + rb] = pkrtz(a * cv - b2 * sv, fmaf(b2, cv, a * sv));
    }
  }
  #pragma unroll
  for (int rep = 0; rep < 2; rep++){
    int idx2 = rep * 512 + tid;
    if (AXIS != 2){
      int i = idx2 & 31, f = idx2 >> 5;
      size_t go = base + (size_t)f * THW_ + (size_t)i * SS;
      us8_t vv = *(const us8_t*)(vp + go);
      #pragma unroll
      for (int g = 0; g < 8; g++) smem[18432 + g * 1152 + f * 36 + i] = vv[g];
    } else {
      int i8 = (idx2 & 3) * 8, g = (idx2 >> 2) & 7, f = idx2 >> 5;
      size_t go = base + (size_t)f * THW_ + (size_t)g * GS + i8;
      us8_t vv = *(const us8_t*)(vp + go);
      int rb = 18432 + g * 1152 + f * 36 + i8;
      ushort4 lo, hi;
      lo.x = vv[0]; lo.y = vv[1]; lo.z = vv[2]; lo.w = vv[3];
      hi.x = vv[4]; hi.y = vv[5]; hi.z = vv[6]; hi.w = vv[7];
      *(ushort4*)&smem[rb] = lo;
      *(ushort4*)&smem[rb + 4] = hi;
    }
  }
  __syncthreads();

  const int lane = tid & 63;
  const int seq = tid >> 6;
  const int m = lane & 15, kg = lane >> 4;

  h8_t aQ[2], bK[2], bV[2];
  #pragma unroll
  for (int t2 = 0; t2 < 2; t2++){
    union { ushort4 u4[2]; h8_t h; } uq, uk, uv;
    int rq = seq * 1152 + (t2 * 16 + m) * 36 + kg * 8;
    uq.u4[0] = *(const ushort4*)&smem[rq];
    uq.u4[1] = *(const ushort4*)&smem[rq + 4];
    uk.u4[0] = *(const ushort4*)&smem[9216 + rq];
    uk.u4[1] = *(const ushort4*)&smem[9216 + rq + 4];
    uv.u4[0] = *(const ushort4*)&smem[18432 + rq];
    uv.u4[1] = *(const ushort4*)&smem[18432 + rq + 4];
    aQ[t2] = uq.h; bK[t2] = uk.h; bV[t2] = uv.h;
  }

  f4_t st[2][2];
  #pragma unroll
  for (int tk = 0; tk < 2; tk++)
    #pragma unroll
    for (int tq = 0; tq < 2; tq++){
      st[tk][tq] = (f4_t)0.f;
      st[tk][tq] = __builtin_amdgcn_mfma_f32_16x16x32_f16(bK[tk], aQ[tq], st[tk][tq], 0, 0, 0);
    }

  u32 pkk[2][2][2];             // [tq][tk][pair]
  #pragma unroll
  for (int tq = 0; tq < 2; tq++){
    const int i = tq * 16 + m;
    float e[2][4];
    float mx = -3.0e38f;
    #pragma unroll
    for (int tk = 0; tk < 2; tk++)
      #pragma unroll
      for (int r = 0; r < 4; r++){
        float s = st[tk][tq][r] * 0.17677669529663687f;
        if (AXIS == 0 && (tk * 16 + kg * 4 + r) > i) s = -1e30f;
        e[tk][r] = s;
        mx = fmaxf(mx, s);
      }
    mx = fmaxf(mx, __shfl_xor(mx, 16));
    mx = fmaxf(mx, __shfl_xor(mx, 32));
    float sum = 0.f;
    #pragma unroll
    for (int tk = 0; tk < 2; tk++)
      #pragma unroll
      for (int r = 0; r < 4; r++){
        e[tk][r] = __expf(e[tk][r] - mx);
        sum += e[tk][r];
      }
    sum += __shfl_xor(sum, 16);
    sum += __shfl_xor(sum, 32);
    float rinv = 1.f / sum;
    #pragma unroll
    for (int tk = 0; tk < 2; tk++){
      pkk[tq][tk][0] = pkrtz(e[tk][0] * rinv, e[tk][1] * rinv);
      pkk[tq][tk][1] = pkrtz(e[tk][2] * rinv, e[tk][3] * rinv);
    }
  }

  h8_t aP[2];
  #pragma unroll
  for (int tq = 0; tq < 2; tq++){
    union { u32 w[4]; h8_t h; } uu;
    #pragma unroll
    for (int w = 0; w < 4; w++){
      int srcLane = ((kg & 1) * 2 + (w >> 1)) * 16 + m;
      u32 v0 = __shfl(pkk[tq][0][w & 1], srcLane);
      u32 v1 = __shfl(pkk[tq][1][w & 1], srcLane);
      uu.w[w] = (kg >= 2) ? v1 : v0;
    }
    aP[tq] = uu.h;
  }

  f4_t o_[2][2];
  #pragma unroll
  for (int tq = 0; tq < 2; tq++)
    #pragma unroll
    for (int td = 0; td < 2; td++){
      o_[tq][td] = (f4_t)0.f;
      o_[tq][td] = __builtin_amdgcn_mfma_f32_16x16x32_f16(aP[tq], bV[td], o_[tq][td], 0, 0, 0);
    }

  #pragma unroll
  for (int tq = 0; tq < 2; tq++)
    #pragma unroll
    for (int td = 0; td < 2; td++){
      int i0 = tq * 16 + kg * 4, d = td * 16 + m;
      union { u32 w[2]; ushort4 v; } pk2;
      pk2.w[0] = pkrtz(o_[tq][td][0], o_[tq][td][1]);
      pk2.w[1] = pkrtz(o_[tq][td][2], o_[tq][td][3]);
      *(ushort4*)&smem[18432 + seq * 1152 + d * 36 + i0] = pk2.v;
    }
  __syncthreads();

  #pragma unroll
  for (int rep = 0; rep < 2; rep++){
    int idx2 = rep * 512 + tid;
    if (AXIS != 2){
      int i2 = idx2 & 31, f = idx2 >> 5;
      us8_t ov;
      #pragma unroll
      for (int g = 0; g < 8; g++) ov[g] = smem[18432 + g * 1152 + f * 36 + i2];
      size_t go = base + (size_t)f * THW_ + (size_t)i2 * SS;
      *(us8_t*)(ctx + go) = ov;
    } else {
      int i8 = (idx2 & 3) * 8, g2 = (idx2 >> 2) & 7, f = idx2 >> 5;
      int rb = 18432 + g2 * 1152 + f * 36 + i8;
      ushort4 lo = *(const ushort4*)&smem[rb];
      ushort4 hi = *(const ushort4*)&smem[rb + 4];
      us8_t ov;
      ov[0] = lo.x; ov[1] = lo.y; ov[2] = lo.z; ov[3] = lo.w;
      ov[4] = hi.x; ov[5] = hi.y; ov[6] = hi.z; ov[7] = hi.w;
      size_t go = base + (size_t)f * THW_ + (size_t)g2 * GS + i8;
      *(us8_t*)(ctx + go) = ov;
    }
  }
}

// ---------------- fused attention dispatcher: all 3 axes, 6144 blocks x 512 threads ---------
__global__ __launch_bounds__(512) void k_attn_all(
    const __half* __restrict__ qg_, const __half* __restrict__ kg_,
    const __half* __restrict__ vg_,
    __half* __restrict__ ctx_t, __half* __restrict__ ctx_h, __half* __restrict__ ctx_w,
    const float* __restrict__ cosT, const float* __restrict__ sinT)
{
  __shared__ __align__(16) unsigned short smem[27648];   // 55.3 KB
  int ax = blockIdx.x >> 11;
  int id = blockIdx.x & 2047;
  const unsigned short* qp = (const unsigned short*)qg_;
  const unsigned short* kp = (const unsigned short*)kg_;
  const unsigned short* vp = (const unsigned short*)vg_;
  if (ax == 0)      attn_body<0>(id, smem, qp, kp, vp, (unsigned short*)ctx_t, cosT, sinT);
  else if (ax == 1) attn_body<1>(id, smem, qp, kp, vp, (unsigned short*)ctx_h, cosT, sinT);
  else              attn_body<2>(id, smem, qp, kp, vp, (unsigned short*)ctx_w, cosT, sinT);
}

extern "C" void kernel_launch(void* const* d_in, const int* in_sizes, int n_in,
                              void* d_out, int out_size, void* d_ws, size_t ws_size,
                              hipStream_t stream)
{
  (void)in_sizes; (void)n_in; (void)out_size; (void)ws_size;
  const float* x       = (const float*)d_in[0];
  const float* w_qkv   = (const float*)d_in[1];
  const float* wk_bank = (const float*)d_in[2];
  const float* wv_bank = (const float*)d_in[3];
  const float* pre_w   = (const float*)d_in[4];
  const float* pre_b   = (const float*)d_in[5];
  const float* cw      = (const float*)d_in[6];
  const float* cb      = (const float*)d_in[7];
  const float* gate_w  = (const float*)d_in[8];
  const float* gate_b  = (const float*)d_in[9];
  const float* proj_w  = (const float*)d_in[10];

  const size_t SZ = (size_t)B_ * C_ * THW_;           // 16,777,216 elems
  __half* hb = (__half*)d_ws;                         // 32MB slots
  unsigned short* xT  = (unsigned short*)(hb + 0 * SZ);  // bf16, alive to gate
  __half* qH   = hb + 1 * SZ;                         // q
  __half* kH   = hb + 2 * SZ;                         // k -> ctx_t
  __half* vH   = hb + 3 * SZ;                         // v -> ctx_h
  __half* koH  = hb + 4 * SZ;                         // k_out -> yT(bf16)
  __half* voH  = hb + 5 * SZ;                         // v_out (stays valid)
  __half* ctxtH = kH;
  __half* ctxhH = vH;
  __half* ctxwH = (__half*)d_out;                     // ctx_w in d_out (dead until proj)
  unsigned short* yT = (unsigned short*)koH;          // over dead k_out
  float* sm    = (float*)(hb + 6 * SZ);               // smalls
  float* qg    = sm;                                  // 16384
  float* hbuf  = qg + 16384;                          // 16384
  float* alpha = hbuf + 16384;                        // 192
  float* cosT  = alpha + 192;                         // 512
  float* sinT  = cosT + 512;                          // 512
  unsigned short* wB = (unsigned short*)(sinT + 512); // 1792*256 bf16 (896 KB)
  unsigned short* wBq = wB;                           // [768][256]
  unsigned short* wBg = wB + 768 * 256;               // [768][256]
  unsigned short* wBp = wB + 1536 * 256;              // [256][256]

  k_rope_table<<<1, 512, 0, stream>>>(cosT, sinT);
  k_wcvt<<<1792, 256, 0, stream>>>(w_qkv, gate_w, proj_w, wB);
  k_transpose_cvt<float><<<dim3(512, 4, 2), 256, 0, stream>>>(x, xT);

  k_mfma_qkv<<<dim3(6, 256, 2), 256, 0, stream>>>(wBq, xT, qH, kH, vH);

  k_mean_hw<<<16384, 256, 0, stream>>>(qH, qg);
  k_mix_pre<<<64, 256, 0, stream>>>(pre_w, pre_b, qg, hbuf);
  k_mix_alpha<<<64, 256, 0, stream>>>(cw, cb, hbuf, alpha);

  k_conv_mix2<<<16384, 256, 0, stream>>>(kH, vH, wk_bank, wv_bank, alpha, koH, voH);

  k_attn_all<<<6144, 512, 0, stream>>>(qH, koH, voH, ctxtH, ctxhH, ctxwH, cosT, sinT);

  k_mfma_gate2<<<dim3(4, 512, 2), 256, 0, stream>>>(wBg, xT, gate_b,
                                                    ctxtH, ctxhH, ctxwH, yT); // yT over dead k_out
  k_mfma_proj<<<dim3(2, 256, 2), 256, 0, stream>>>(wBp, yT, (float*)d_out);
}